// Round 4
// baseline (1097.884 us; speedup 1.0000x reference)
//
#include <hip/hip_runtime.h>
#include <hip/hip_bf16.h>
#include <stdint.h>

#define NN 100000
#define EE 1600000
#define NT 98          // ceil(NN/1024)
#define NB 782         // ceil(NN/128) buckets for CSR fill
#define BPH 32         // MHA blocks per head

// fma of scalar xi with float4 vv into acc[base..base+3]
// (param name must NOT be 'x'/'y'/'z'/'w' — member tokens get macro-substituted!)
#define FMA4(xi, vv, a, base)                      \
  a[(base)+0] = fmaf((xi), (vv).x, a[(base)+0]);   \
  a[(base)+1] = fmaf((xi), (vv).y, a[(base)+1]);   \
  a[(base)+2] = fmaf((xi), (vv).z, a[(base)+2]);   \
  a[(base)+3] = fmaf((xi), (vv).w, a[(base)+3]);

__device__ inline unsigned pack_bf2(float a, float b) {
  __hip_bfloat162 t;
  t.x = __float2bfloat16(a);
  t.y = __float2bfloat16(b);
  return *reinterpret_cast<unsigned*>(&t);
}

// ---------------- degree count ----------------
__global__ void k_deg(const int* __restrict__ ei, int* __restrict__ counts) {
  int e = blockIdx.x * 256 + threadIdx.x;
  if (e < EE) atomicAdd(&counts[ei[EE + e]], 1);
}

// ---------------- block-level scan ----------------
__global__ void k_scan_block(const int* __restrict__ counts, int* __restrict__ offsets,
                             int* __restrict__ tile_sums, float* __restrict__ dinv) {
  __shared__ int sm[1024];
  int t = threadIdx.x;
  int i = blockIdx.x * 1024 + t;
  int v = (i < NN) ? counts[i] : 0;
  if (i < NN) dinv[i] = rsqrtf((float)(v + 1));  // deg includes self loop
  sm[t] = v;
  __syncthreads();
  for (int off = 1; off < 1024; off <<= 1) {
    int x = (t >= off) ? sm[t - off] : 0;
    __syncthreads();
    sm[t] += x;
    __syncthreads();
  }
  if (i < NN) offsets[i] = sm[t] - v;
  if (t == 1023) tile_sums[blockIdx.x] = sm[1023];
}

__global__ void k_scan_tiles(int* __restrict__ tile_sums) {
  if (blockIdx.x == 0 && threadIdx.x == 0) {
    int run = 0;
    for (int b = 0; b < NT; b++) { int v = tile_sums[b]; tile_sums[b] = run; run += v; }
  }
}

__global__ void k_scan_add(int* __restrict__ offsets, const int* __restrict__ tile_sums) {
  int i = blockIdx.x * 256 + threadIdx.x;
  if (i < NN) offsets[i] += tile_sums[i >> 10];
  if (i == 0) offsets[NN] = EE;
}

// ---------------- CSR fill pass B: bucket scatter (packed 4B records) ----------------
// bucket = dst>>7 (128 nodes/bucket). 782 L2-hot write frontiers -> no 16x
// write amplification (vs direct scatter: 107 MB writeback for a 6.4 MB array).
__global__ void k_fill_b(const int* __restrict__ ei, const int* __restrict__ offsets,
                         int* __restrict__ bcur, unsigned* __restrict__ brec) {
  int e = blockIdx.x * 256 + threadIdx.x;
  if (e < EE) {
    int s = ei[e], d = ei[EE + e];
    int b = d >> 7;
    int p = atomicAdd(&bcur[b], 1) + offsets[b << 7];
    brec[p] = (unsigned)s | ((unsigned)(d & 127) << 17);  // NN < 2^17
  }
}

// ---------------- CSR fill pass C: one WG per bucket, LDS cursors ----------------
__launch_bounds__(256)
__global__ void k_fill_c(const unsigned* __restrict__ brec, const int* __restrict__ offsets,
                         int* __restrict__ csr) {
  __shared__ int lcnt[128];
  __shared__ int loff[129];
  int b = blockIdx.x;
  int nb0 = b << 7;
  int nn = NN - nb0; if (nn > 128) nn = 128;
  if ((int)threadIdx.x < nn) lcnt[threadIdx.x] = 0;
  if ((int)threadIdx.x <= nn) loff[threadIdx.x] = offsets[nb0 + threadIdx.x];
  __syncthreads();
  int e0 = loff[0], e1 = loff[nn];
  for (int j = e0 + threadIdx.x; j < e1; j += 256) {
    unsigned r = brec[j];
    int s = r & 0x1FFFF;
    int dl = (r >> 17) & 127;
    int p = atomicAdd(&lcnt[dl], 1);
    csr[loff[dl] + p] = s;  // writes confined to this bucket's ~8KB window
  }
}

// ---------------- x~ = bf16(x * dinv[row]) ----------------
__global__ void k_prep(const float* __restrict__ x, const float* __restrict__ dinv,
                       unsigned* __restrict__ xbf2) {
  int i = blockIdx.x * 256 + threadIdx.x;  // pair index
  if (i >= NN * 32) return;
  float dv = dinv[i >> 5];
  float2 v = ((const float2*)x)[i];
  xbf2[i] = pack_bf2(v.x * dv, v.y * dv);
}

// ---------------- ax = A_norm @ x (wave per node, half-wave per edge parity) ----------------
__launch_bounds__(256)
__global__ void k_agg_x(const unsigned* __restrict__ xbf2, const int* __restrict__ offsets,
                        const int* __restrict__ csr, const float* __restrict__ dinv,
                        float* __restrict__ ax) {
  int gid = blockIdx.x * 256 + threadIdx.x;
  int n = gid >> 6;
  if (n >= NN) return;
  int lane = gid & 63, l = lane & 31, half = lane >> 5;
  int e0 = offsets[n], e1 = offsets[n + 1];
  float dv = dinv[n];
  float a0 = 0.f, a1 = 0.f;
  {  // self loop (half 0 only): x~[n] already contains x[n]*dv
    unsigned u = xbf2[(size_t)n * 32 + l];
    __hip_bfloat162 v = *reinterpret_cast<__hip_bfloat162*>(&u);
    if (!half) { a0 = __bfloat162float(v.x); a1 = __bfloat162float(v.y); }
  }
  for (int j = e0 + half; j < e1; j += 2) {
    int s = csr[j];
    unsigned u = xbf2[(size_t)s * 32 + l];
    __hip_bfloat162 v = *reinterpret_cast<__hip_bfloat162*>(&u);
    a0 += __bfloat162float(v.x);
    a1 += __bfloat162float(v.y);
  }
  a0 += __shfl_xor(a0, 32);
  a1 += __shfl_xor(a1, 32);
  if (!half) ((float2*)ax)[(size_t)n * 32 + l] = make_float2(a0 * dv, a1 * dv);
}

// ---------------- xK = ax@WK+bK, xV = ax@WV+bV ----------------
__launch_bounds__(256)
__global__ void k_gemm_kv(const float* __restrict__ ax, const float* __restrict__ WK,
                          const float* __restrict__ WV, const float* __restrict__ bK,
                          const float* __restrict__ bV, float* __restrict__ xK,
                          float* __restrict__ xV) {
  __shared__ float sK[4096], sV[4096], sbK[64], sbV[64];
  for (int i = threadIdx.x; i < 4096; i += 256) { sK[i] = WK[i]; sV[i] = WV[i]; }
  for (int i = threadIdx.x; i < 64; i += 256) { sbK[i] = bK[i]; sbV[i] = bV[i]; }
  __syncthreads();
  int row = blockIdx.x * 256 + threadIdx.x;
  if (row >= NN) return;
  const float4* xr = (const float4*)(ax + (size_t)row * 64);
  const float4* K4 = (const float4*)sK;
  const float4* V4 = (const float4*)sV;
  float aK[64], aV[64];
#pragma unroll
  for (int j = 0; j < 64; j++) { aK[j] = 0.f; aV[j] = 0.f; }
  for (int i4 = 0; i4 < 16; i4++) {
    float4 xv = xr[i4];
    float xs[4] = {xv.x, xv.y, xv.z, xv.w};
#pragma unroll
    for (int ii = 0; ii < 4; ii++) {
      int i = i4 * 4 + ii;
      float xi = xs[ii];
#pragma unroll
      for (int j4 = 0; j4 < 16; j4++) {
        float4 wk = K4[i * 16 + j4];
        float4 wv = V4[i * 16 + j4];
        FMA4(xi, wk, aK, 4 * j4);
        FMA4(xi, wv, aV, 4 * j4);
      }
    }
  }
  float4* oK = (float4*)(xK + (size_t)row * 64);
  float4* oV = (float4*)(xV + (size_t)row * 64);
#pragma unroll
  for (int j4 = 0; j4 < 16; j4++) {
    oK[j4] = make_float4(aK[4 * j4] + sbK[4 * j4], aK[4 * j4 + 1] + sbK[4 * j4 + 1],
                         aK[4 * j4 + 2] + sbK[4 * j4 + 2], aK[4 * j4 + 3] + sbK[4 * j4 + 3]);
    oV[j4] = make_float4(aV[4 * j4] + sbV[4 * j4], aV[4 * j4 + 1] + sbV[4 * j4 + 1],
                         aV[4 * j4 + 2] + sbV[4 * j4 + 2], aV[4 * j4 + 3] + sbV[4 * j4 + 3]);
  }
}

// ---------------- qh = (super_Q @ Wq^T + bq) * scale ----------------
__global__ void k_qh(const float* __restrict__ sQ, const float* __restrict__ in_w,
                     const float* __restrict__ in_b, float* __restrict__ qh) {
  int t = blockIdx.x * 256 + threadIdx.x;
  if (t >= 640) return;
  int l = t >> 6, c = t & 63;
  float acc = 0.f;
  for (int i = 0; i < 64; i++) acc = fmaf(sQ[l * 64 + i], in_w[c * 64 + i], acc);
  qh[t] = (acc + in_b[c]) * 0.35355339059327373f;  // 1/sqrt(8)
}

// ---------------- Kh/Vh (head-blocked), hGb (bf16), s_dst ----------------
__launch_bounds__(256)
__global__ void k_gemm2(const float* __restrict__ xK, const float* __restrict__ xV,
                        const float* __restrict__ in_w, const float* __restrict__ in_b,
                        const float* __restrict__ gatW, const float* __restrict__ a_dst,
                        float* __restrict__ Kh, float* __restrict__ Vh,
                        unsigned* __restrict__ hGb, float* __restrict__ s_dst) {
  __shared__ float sWk[4096], sWv[4096], sGW[4096];
  __shared__ float sBk[64], sBv[64], sAd[64];
  for (int t = threadIdx.x; t < 4096; t += 256) {
    int c = t & 63, i = t >> 6;
    sWk[i * 64 + c] = in_w[(64 + c) * 64 + i];   // transposed: [i][c]
    sWv[i * 64 + c] = in_w[(128 + c) * 64 + i];
    sGW[t] = gatW[t];                            // natural [i][j]
  }
  for (int t = threadIdx.x; t < 64; t += 256) {
    sBk[t] = in_b[64 + t]; sBv[t] = in_b[128 + t]; sAd[t] = a_dst[t];
  }
  __syncthreads();
  int row = blockIdx.x * 256 + threadIdx.x;
  if (row >= NN) return;
  // phase 1: K projection
  {
    const float4* xr = (const float4*)(xK + (size_t)row * 64);
    const float4* W4 = (const float4*)sWk;
    float a[64];
#pragma unroll
    for (int c = 0; c < 64; c++) a[c] = 0.f;
    for (int i4 = 0; i4 < 16; i4++) {
      float4 xv4 = xr[i4];
      float xs[4] = {xv4.x, xv4.y, xv4.z, xv4.w};
#pragma unroll
      for (int ii = 0; ii < 4; ii++) {
        float xi = xs[ii];
        int i = i4 * 4 + ii;
#pragma unroll
        for (int c4 = 0; c4 < 16; c4++) {
          float4 wk = W4[i * 16 + c4];
          FMA4(xi, wk, a, 4 * c4);
        }
      }
    }
#pragma unroll
    for (int h = 0; h < 8; h++) {
      float4* dst = (float4*)(Kh + (size_t)h * NN * 8 + (size_t)row * 8);
      dst[0] = make_float4(a[h * 8 + 0] + sBk[h * 8 + 0], a[h * 8 + 1] + sBk[h * 8 + 1],
                           a[h * 8 + 2] + sBk[h * 8 + 2], a[h * 8 + 3] + sBk[h * 8 + 3]);
      dst[1] = make_float4(a[h * 8 + 4] + sBk[h * 8 + 4], a[h * 8 + 5] + sBk[h * 8 + 5],
                           a[h * 8 + 6] + sBk[h * 8 + 6], a[h * 8 + 7] + sBk[h * 8 + 7]);
    }
  }
  // phase 2: V projection + GAT features + s_dst
  {
    const float4* xr = (const float4*)(xV + (size_t)row * 64);
    const float4* Wv4 = (const float4*)sWv;
    const float4* G4 = (const float4*)sGW;
    float av[64], ag[64];
#pragma unroll
    for (int c = 0; c < 64; c++) { av[c] = 0.f; ag[c] = 0.f; }
    for (int i4 = 0; i4 < 16; i4++) {
      float4 xv4 = xr[i4];
      float xs[4] = {xv4.x, xv4.y, xv4.z, xv4.w};
#pragma unroll
      for (int ii = 0; ii < 4; ii++) {
        float xi = xs[ii];
        int i = i4 * 4 + ii;
#pragma unroll
        for (int c4 = 0; c4 < 16; c4++) {
          float4 wv = Wv4[i * 16 + c4];
          float4 wg = G4[i * 16 + c4];
          FMA4(xi, wv, av, 4 * c4);
          FMA4(xi, wg, ag, 4 * c4);
        }
      }
    }
#pragma unroll
    for (int h = 0; h < 8; h++) {
      float4* dst = (float4*)(Vh + (size_t)h * NN * 8 + (size_t)row * 8);
      dst[0] = make_float4(av[h * 8 + 0] + sBv[h * 8 + 0], av[h * 8 + 1] + sBv[h * 8 + 1],
                           av[h * 8 + 2] + sBv[h * 8 + 2], av[h * 8 + 3] + sBv[h * 8 + 3]);
      dst[1] = make_float4(av[h * 8 + 4] + sBv[h * 8 + 4], av[h * 8 + 5] + sBv[h * 8 + 5],
                           av[h * 8 + 6] + sBv[h * 8 + 6], av[h * 8 + 7] + sBv[h * 8 + 7]);
    }
    float sd = 0.f;
#pragma unroll
    for (int j = 0; j < 64; j++) sd = fmaf(ag[j], sAd[j], sd);
    s_dst[row] = sd;
    uint4* gb4 = (uint4*)(hGb + (size_t)row * 32);
#pragma unroll
    for (int q = 0; q < 8; q++) {
      uint4 u;
      u.x = pack_bf2(ag[8 * q + 0], ag[8 * q + 1]);
      u.y = pack_bf2(ag[8 * q + 2], ag[8 * q + 3]);
      u.z = pack_bf2(ag[8 * q + 4], ag[8 * q + 5]);
      u.w = pack_bf2(ag[8 * q + 6], ag[8 * q + 7]);
      gb4[q] = u;
    }
  }
}

// ---------------- MHA main ----------------
__launch_bounds__(256)
__global__ void k_mha(const float* __restrict__ Kh, const float* __restrict__ Vh,
                      const float* __restrict__ qh, float* __restrict__ acc) {
  int h = blockIdx.x / BPH, b = blockIdx.x % BPH;
  __shared__ float sq[80];
  if (threadIdx.x < 80) {
    int l = threadIdx.x >> 3, j = threadIdx.x & 7;
    sq[threadIdx.x] = qh[l * 64 + h * 8 + j];
  }
  __syncthreads();
  const float4* Kp = (const float4*)(Kh + (size_t)h * NN * 8);
  const float4* Vp = (const float4*)(Vh + (size_t)h * NN * 8);
  const float4* sq4 = (const float4*)sq;
  float s[10], o[80];
#pragma unroll
  for (int l = 0; l < 10; l++) s[l] = 0.f;
#pragma unroll
  for (int t = 0; t < 80; t++) o[t] = 0.f;
  for (int n = b * 256 + threadIdx.x; n < NN; n += BPH * 256) {
    float4 k0 = Kp[n * 2], k1 = Kp[n * 2 + 1];
    float4 v0 = Vp[n * 2], v1 = Vp[n * 2 + 1];
#pragma unroll
    for (int l = 0; l < 10; l++) {
      float4 q0 = sq4[l * 2], q1 = sq4[l * 2 + 1];
      float z = q0.x * k0.x + q0.y * k0.y + q0.z * k0.z + q0.w * k0.w +
                q1.x * k1.x + q1.y * k1.y + q1.z * k1.z + q1.w * k1.w;
      float w = __expf(z);
      s[l] += w;
      o[l * 8 + 0] = fmaf(w, v0.x, o[l * 8 + 0]);
      o[l * 8 + 1] = fmaf(w, v0.y, o[l * 8 + 1]);
      o[l * 8 + 2] = fmaf(w, v0.z, o[l * 8 + 2]);
      o[l * 8 + 3] = fmaf(w, v0.w, o[l * 8 + 3]);
      o[l * 8 + 4] = fmaf(w, v1.x, o[l * 8 + 4]);
      o[l * 8 + 5] = fmaf(w, v1.y, o[l * 8 + 5]);
      o[l * 8 + 6] = fmaf(w, v1.z, o[l * 8 + 6]);
      o[l * 8 + 7] = fmaf(w, v1.w, o[l * 8 + 7]);
    }
  }
  int lane = threadIdx.x & 63;
#pragma unroll
  for (int l = 0; l < 10; l++) {
    float v = s[l];
#pragma unroll
    for (int off = 32; off > 0; off >>= 1) v += __shfl_down(v, off);
    if (lane == 0) atomicAdd(&acc[h * 10 + l], v);
  }
#pragma unroll
  for (int t = 0; t < 80; t++) {
    float v = o[t];
#pragma unroll
    for (int off = 32; off > 0; off >>= 1) v += __shfl_down(v, off);
    if (lane == 0) atomicAdd(&acc[80 + h * 80 + t], v);
  }
}

// ---------------- softmax finalize -> cluster -> context -> a_eff ----------------
__global__ void k_context(const float* __restrict__ acc, const float* __restrict__ out_w,
                          const float* __restrict__ out_b, const float* __restrict__ a_src,
                          const float* __restrict__ gat_Wc, float* __restrict__ aeff) {
  __shared__ float po[640], cl[640], ctx[64];
  int t = threadIdx.x;  // blockDim = 640
  {
    int h = t / 80, r = t % 80, l = r >> 3, j = r & 7;
    po[l * 64 + h * 8 + j] = acc[80 + t] / acc[h * 10 + l];
  }
  __syncthreads();
  {
    int l = t >> 6, d = t & 63;
    float v = out_b[d];
    for (int c = 0; c < 64; c++) v = fmaf(po[l * 64 + c], out_w[d * 64 + c], v);
    cl[t] = v;
  }
  __syncthreads();
  if (t < 64) {
    float m = 0.f;
#pragma unroll
    for (int l = 0; l < 10; l++) m += cl[l * 64 + t];
    ctx[t] = m * 0.1f;
  }
  __syncthreads();
  if (t < 64) {
    float v = a_src[t];
    for (int i = 0; i < 64; i++) v = fmaf(ctx[i], gat_Wc[i * 64 + t], v);
    aeff[t] = v;
  }
}

// ---------------- s_src[n] = dot(hG[n], a_eff) ----------------
__launch_bounds__(256)
__global__ void k_ssrc(const unsigned* __restrict__ hGb, const float* __restrict__ aeff,
                       float* __restrict__ s_src) {
  int gid = blockIdx.x * 256 + threadIdx.x;
  int n = gid >> 6, lane = gid & 63;
  if (n >= NN) return;
  const __hip_bfloat16* hp = (const __hip_bfloat16*)hGb;
  float v = __bfloat162float(hp[(size_t)n * 64 + lane]) * aeff[lane];
#pragma unroll
  for (int off = 32; off > 0; off >>= 1) v += __shfl_xor(v, off);
  if (lane == 0) s_src[n] = v;
}

// ---------------- GAT: single-sweep segment softmax + bf16 weighted gather ----------------
__launch_bounds__(256)
__global__ void k_gat(const int* __restrict__ offsets, const int* __restrict__ csr,
                      const float* __restrict__ s_src, const float* __restrict__ s_dstv,
                      const unsigned* __restrict__ hGb, const float* __restrict__ gat_b,
                      float* __restrict__ g) {
  int gid = blockIdx.x * 256 + threadIdx.x;
  int n = gid >> 6;
  if (n >= NN) return;
  int lane = gid & 63, l = lane & 31, half = lane >> 5;
  int e0 = offsets[n], e1 = offsets[n + 1];
  float sd = s_dstv[n];
  float den = 0.f, a0 = 0.f, a1 = 0.f;
  for (int j = e0 + half; j < e1; j += 2) {
    int s = csr[j];
    float z = s_src[s] + sd;
    z = z > 0.f ? z : 0.2f * z;
    float ex = __expf(z);   // logits O(1): softmax is shift-invariant, skip segment-max
    den += ex;
    unsigned u = hGb[(size_t)s * 32 + l];
    __hip_bfloat162 v = *reinterpret_cast<__hip_bfloat162*>(&u);
    a0 = fmaf(ex, __bfloat162float(v.x), a0);
    a1 = fmaf(ex, __bfloat162float(v.y), a1);
  }
  den += __shfl_xor(den, 32);
  a0 += __shfl_xor(a0, 32);
  a1 += __shfl_xor(a1, 32);
  float inv = 1.f / (den + 1e-16f);
  if (!half)
    ((float2*)g)[(size_t)n * 32 + l] =
        make_float2(a0 * inv + gat_b[2 * l], a1 * inv + gat_b[2 * l + 1]);
}

// ---------------- fused MLP (in-place on d_out) ----------------
__launch_bounds__(256)
__global__ void k_mlp(float* __restrict__ io, const float* __restrict__ W1,
                      const float* __restrict__ b1, const float* __restrict__ W2,
                      const float* __restrict__ b2) {
  __shared__ float sW1[64 * 128];  // transposed: [j][i]
  __shared__ float sW2[128 * 64];  // natural [j][k]
  __shared__ float sb1[128], sb2[64];
  for (int t = threadIdx.x; t < 8192; t += 256) {
    int j = t >> 6, i = t & 63;
    sW1[j * 64 + i] = W1[i * 128 + j];
    sW2[t] = W2[t];
  }
  for (int t = threadIdx.x; t < 128; t += 256) sb1[t] = b1[t];
  for (int t = threadIdx.x; t < 64; t += 256) sb2[t] = b2[t];
  __syncthreads();
  int row = blockIdx.x * 256 + threadIdx.x;
  if (row >= NN) return;
  float4* iop = (float4*)(io + (size_t)row * 64);
  float gr[64];
#pragma unroll
  for (int i4 = 0; i4 < 16; i4++) {
    float4 v = iop[i4];
    gr[4 * i4] = v.x; gr[4 * i4 + 1] = v.y; gr[4 * i4 + 2] = v.z; gr[4 * i4 + 3] = v.w;
  }
  float out[64];
#pragma unroll
  for (int k = 0; k < 64; k++) out[k] = sb2[k];
  const float4* W1t4 = (const float4*)sW1;
  const float4* W24 = (const float4*)sW2;
  for (int j = 0; j < 128; j++) {
    float hv = sb1[j];
#pragma unroll
    for (int i4 = 0; i4 < 16; i4++) {
      float4 wr = W1t4[j * 16 + i4];
      hv = fmaf(gr[4 * i4], wr.x, hv);
      hv = fmaf(gr[4 * i4 + 1], wr.y, hv);
      hv = fmaf(gr[4 * i4 + 2], wr.z, hv);
      hv = fmaf(gr[4 * i4 + 3], wr.w, hv);
    }
    hv = fmaxf(hv, 0.f);
#pragma unroll
    for (int k4 = 0; k4 < 16; k4++) {
      float4 wr = W24[j * 16 + k4];
      FMA4(hv, wr, out, 4 * k4);
    }
  }
#pragma unroll
  for (int k4 = 0; k4 < 16; k4++)
    iop[k4] = make_float4(fmaxf(out[4 * k4], 0.f), fmaxf(out[4 * k4 + 1], 0.f),
                          fmaxf(out[4 * k4 + 2], 0.f), fmaxf(out[4 * k4 + 3], 0.f));
}

// ---------------- host ----------------
extern "C" void kernel_launch(void* const* d_in, const int* in_sizes, int n_in,
                              void* d_out, int out_size, void* d_ws, size_t ws_size,
                              hipStream_t stream) {
  (void)in_sizes; (void)n_in; (void)out_size; (void)ws_size;
  const float* x        = (const float*)d_in[0];
  const int*   ei       = (const int*)d_in[1];
  const float* gcnK_W   = (const float*)d_in[2];
  const float* gcnK_b   = (const float*)d_in[3];
  const float* gcnV_W   = (const float*)d_in[4];
  const float* gcnV_b   = (const float*)d_in[5];
  const float* super_Q  = (const float*)d_in[6];
  const float* mha_in_w = (const float*)d_in[7];
  const float* mha_in_b = (const float*)d_in[8];
  const float* mha_out_w= (const float*)d_in[9];
  const float* mha_out_b= (const float*)d_in[10];
  const float* gat_W    = (const float*)d_in[11];
  const float* gat_Wc   = (const float*)d_in[12];
  const float* gat_a_src= (const float*)d_in[13];
  const float* gat_a_dst= (const float*)d_in[14];
  const float* gat_b    = (const float*)d_in[15];
  const float* t1_W     = (const float*)d_in[16];
  const float* t1_b     = (const float*)d_in[17];
  const float* t2_W     = (const float*)d_in[18];
  const float* t2_b     = (const float*)d_in[19];

  char* ws = (char*)d_ws;
  size_t cur = 0;
  auto alloc = [&](size_t bytes) -> char* {
    char* p = ws + cur;
    cur = (cur + bytes + 255) & ~(size_t)255;
    return p;
  };
  // zero-initialized region (single memset): counts, bucket cursors, mha accumulators
  int*      counts = (int*)alloc((size_t)NN * 4);
  int*      bcur   = (int*)alloc((size_t)NB * 4);
  float*    macc   = (float*)alloc(720 * 4);
  size_t zero_bytes = cur;
  int*      offsets = (int*)alloc((size_t)(NN + 1) * 4);
  int*      tiles   = (int*)alloc((size_t)NT * 4);
  float*    dinv    = (float*)alloc((size_t)NN * 4);
  int*      csr     = (int*)alloc((size_t)EE * 4);
  unsigned* brec    = (unsigned*)alloc((size_t)EE * 4);
  float*    qh      = (float*)alloc(640 * 4);
  float*    aeff    = (float*)alloc(64 * 4);
  float*    s_src   = (float*)alloc((size_t)NN * 4);
  float*    s_dstv  = (float*)alloc((size_t)NN * 4);
  unsigned* xbf     = (unsigned*)alloc((size_t)NN * 128);   // bf16 x*dinv, 32 pairs/row
  float*    ax      = (float*)alloc((size_t)NN * 64 * 4);
  float*    xK      = (float*)alloc((size_t)NN * 64 * 4);
  float*    xV      = (float*)alloc((size_t)NN * 64 * 4);
  float*    Vh      = (float*)alloc((size_t)NN * 64 * 4);
  unsigned* hGb     = (unsigned*)alloc((size_t)NN * 128);   // bf16 GAT features
  float*    Kh      = ax;   // ax dead after k_gemm_kv; k_gemm2 writes Kh there
  float*    g       = (float*)d_out;

  (void)hipMemsetAsync(d_ws, 0, zero_bytes, stream);
  k_deg<<<(EE + 255) / 256, 256, 0, stream>>>(ei, counts);
  k_scan_block<<<NT, 1024, 0, stream>>>(counts, offsets, tiles, dinv);
  k_scan_tiles<<<1, 64, 0, stream>>>(tiles);
  k_scan_add<<<(NN + 255) / 256, 256, 0, stream>>>(offsets, tiles);
  k_fill_b<<<(EE + 255) / 256, 256, 0, stream>>>(ei, offsets, bcur, brec);
  k_fill_c<<<NB, 256, 0, stream>>>(brec, offsets, csr);
  k_prep<<<(NN * 32 + 255) / 256, 256, 0, stream>>>(x, dinv, xbf);
  k_agg_x<<<NN / 4, 256, 0, stream>>>(xbf, offsets, csr, dinv, ax);
  k_gemm_kv<<<(NN + 255) / 256, 256, 0, stream>>>(ax, gcnK_W, gcnV_W, gcnK_b, gcnV_b, xK, xV);
  k_qh<<<3, 256, 0, stream>>>(super_Q, mha_in_w, mha_in_b, qh);
  k_gemm2<<<(NN + 255) / 256, 256, 0, stream>>>(xK, xV, mha_in_w, mha_in_b, gat_W, gat_a_dst,
                                                Kh, Vh, hGb, s_dstv);
  k_mha<<<8 * BPH, 256, 0, stream>>>(Kh, Vh, qh, macc);
  k_context<<<1, 640, 0, stream>>>(macc, mha_out_w, mha_out_b, gat_a_src, gat_Wc, aeff);
  k_ssrc<<<NN / 4, 256, 0, stream>>>(hGb, aeff, s_src);
  k_gat<<<NN / 4, 256, 0, stream>>>(offsets, csr, s_src, s_dstv, hGb, gat_b, g);
  k_mlp<<<(NN + 255) / 256, 256, 0, stream>>>(g, t1_W, t1_b, t2_W, t2_b);
}

// Round 5
// 846.849 us; speedup vs baseline: 1.2964x; 1.2964x over previous
//
#include <hip/hip_runtime.h>
#include <hip/hip_bf16.h>
#include <stdint.h>

#define NN 100000
#define EE 1600000
#define NT 98          // ceil(NN/1024)
#define NB 782         // ceil(NN/128) buckets for CSR fill
#define BPH 32         // MHA blocks per head

// fma of scalar xi with float4 vv into acc[base..base+3]
// (param name must NOT be 'x'/'y'/'z'/'w' — member tokens get macro-substituted!)
#define FMA4(xi, vv, a, base)                      \
  a[(base)+0] = fmaf((xi), (vv).x, a[(base)+0]);   \
  a[(base)+1] = fmaf((xi), (vv).y, a[(base)+1]);   \
  a[(base)+2] = fmaf((xi), (vv).z, a[(base)+2]);   \
  a[(base)+3] = fmaf((xi), (vv).w, a[(base)+3]);

__device__ inline unsigned pack_bf2(float a, float b) {
  __hip_bfloat162 t;
  t.x = __float2bfloat16(a);
  t.y = __float2bfloat16(b);
  return *reinterpret_cast<unsigned*>(&t);
}

// ---------------- degree count + per-(bucket,partition) histogram ----------------
// partition = blockIdx.x & 7 (~XCD round-robin). pcnt counters padded to one
// 64B line each: round-4 showed 16 counters/line => 32K-RMW chains = 377 us.
__global__ void k_deg(const int* __restrict__ ei, int* __restrict__ counts,
                      int* __restrict__ pcnt) {
  int e = blockIdx.x * 256 + threadIdx.x;
  if (e < EE) {
    int d = ei[EE + e];
    atomicAdd(&counts[d], 1);
    atomicAdd(&pcnt[((d >> 7) * 8 + (blockIdx.x & 7)) * 16], 1);
  }
}

// ---------------- block-level scan ----------------
__global__ void k_scan_block(const int* __restrict__ counts, int* __restrict__ offsets,
                             int* __restrict__ tile_sums, float* __restrict__ dinv) {
  __shared__ int sm[1024];
  int t = threadIdx.x;
  int i = blockIdx.x * 1024 + t;
  int v = (i < NN) ? counts[i] : 0;
  if (i < NN) dinv[i] = rsqrtf((float)(v + 1));  // deg includes self loop
  sm[t] = v;
  __syncthreads();
  for (int off = 1; off < 1024; off <<= 1) {
    int x = (t >= off) ? sm[t - off] : 0;
    __syncthreads();
    sm[t] += x;
    __syncthreads();
  }
  if (i < NN) offsets[i] = sm[t] - v;
  if (t == 1023) tile_sums[blockIdx.x] = sm[1023];
}

__global__ void k_scan_tiles(int* __restrict__ tile_sums) {
  if (blockIdx.x == 0 && threadIdx.x == 0) {
    int run = 0;
    for (int b = 0; b < NT; b++) { int v = tile_sums[b]; tile_sums[b] = run; run += v; }
  }
}

__global__ void k_scan_add(int* __restrict__ offsets, const int* __restrict__ tile_sums) {
  int i = blockIdx.x * 256 + threadIdx.x;
  if (i < NN) offsets[i] += tile_sums[i >> 10];
  if (i == 0) offsets[NN] = EE;
}

// ---------------- per-(bucket,partition) sub-region start cursors ----------------
__global__ void k_boff(const int* __restrict__ offsets, const int* __restrict__ pcnt,
                       int* __restrict__ ppos) {
  int b = blockIdx.x * 256 + threadIdx.x;
  if (b >= NB) return;
  int run = offsets[b << 7];  // max index 781<<7 = 99968 <= NN, in bounds
#pragma unroll
  for (int p = 0; p < 8; p++) {
    ppos[(b * 8 + p) * 16] = run;
    run += pcnt[(b * 8 + p) * 16];
  }
}

// ---------------- CSR fill pass B: partitioned bucket scatter ----------------
// Same launch geometry as k_deg => identical edge->partition mapping.
// Each (bucket,partition) sub-region is written by ~one XCD's blocks =>
// frontier lines assemble in one L2 (no 8x write amplification), and each
// padded cursor's RMW chain is only ~256.
__global__ void k_fill_b(const int* __restrict__ ei, int* __restrict__ ppos,
                         unsigned* __restrict__ brec) {
  int e = blockIdx.x * 256 + threadIdx.x;
  if (e < EE) {
    int s = ei[e], d = ei[EE + e];
    int idx = ((d >> 7) * 8 + (blockIdx.x & 7)) * 16;
    int p = atomicAdd(&ppos[idx], 1);
    brec[p] = (unsigned)s | ((unsigned)(d & 127) << 17);  // NN < 2^17
  }
}

// ---------------- CSR fill pass C: one WG per bucket, LDS cursors ----------------
__launch_bounds__(256)
__global__ void k_fill_c(const unsigned* __restrict__ brec, const int* __restrict__ offsets,
                         int* __restrict__ csr) {
  __shared__ int lcnt[128];
  __shared__ int loff[129];
  int b = blockIdx.x;
  int nb0 = b << 7;
  int nn = NN - nb0; if (nn > 128) nn = 128;
  if ((int)threadIdx.x < nn) lcnt[threadIdx.x] = 0;
  if ((int)threadIdx.x <= nn) loff[threadIdx.x] = offsets[nb0 + threadIdx.x];
  __syncthreads();
  int e0 = loff[0], e1 = loff[nn];
  for (int j = e0 + threadIdx.x; j < e1; j += 256) {
    unsigned r = brec[j];
    int s = r & 0x1FFFF;
    int dl = (r >> 17) & 127;
    int p = atomicAdd(&lcnt[dl], 1);
    csr[loff[dl] + p] = s;  // writes confined to this bucket's ~8KB window
  }
}

// ---------------- x~ = bf16(x * dinv[row]) ----------------
__global__ void k_prep(const float* __restrict__ x, const float* __restrict__ dinv,
                       unsigned* __restrict__ xbf2) {
  int i = blockIdx.x * 256 + threadIdx.x;  // pair index
  if (i >= NN * 32) return;
  float dv = dinv[i >> 5];
  float2 v = ((const float2*)x)[i];
  xbf2[i] = pack_bf2(v.x * dv, v.y * dv);
}

// ---------------- ax = A_norm @ x (wave per node, half-wave per edge parity) ----------------
__launch_bounds__(256)
__global__ void k_agg_x(const unsigned* __restrict__ xbf2, const int* __restrict__ offsets,
                        const int* __restrict__ csr, const float* __restrict__ dinv,
                        float* __restrict__ ax) {
  int gid = blockIdx.x * 256 + threadIdx.x;
  int n = gid >> 6;
  if (n >= NN) return;
  int lane = gid & 63, l = lane & 31, half = lane >> 5;
  int e0 = offsets[n], e1 = offsets[n + 1];
  float dv = dinv[n];
  float a0 = 0.f, a1 = 0.f;
  {  // self loop (half 0 only): x~[n] already contains x[n]*dv
    unsigned u = xbf2[(size_t)n * 32 + l];
    __hip_bfloat162 v = *reinterpret_cast<__hip_bfloat162*>(&u);
    if (!half) { a0 = __bfloat162float(v.x); a1 = __bfloat162float(v.y); }
  }
  for (int j = e0 + half; j < e1; j += 2) {
    int s = csr[j];
    unsigned u = xbf2[(size_t)s * 32 + l];
    __hip_bfloat162 v = *reinterpret_cast<__hip_bfloat162*>(&u);
    a0 += __bfloat162float(v.x);
    a1 += __bfloat162float(v.y);
  }
  a0 += __shfl_xor(a0, 32);
  a1 += __shfl_xor(a1, 32);
  if (!half) ((float2*)ax)[(size_t)n * 32 + l] = make_float2(a0 * dv, a1 * dv);
}

// ---------------- xK = ax@WK+bK, xV = ax@WV+bV ----------------
__launch_bounds__(256)
__global__ void k_gemm_kv(const float* __restrict__ ax, const float* __restrict__ WK,
                          const float* __restrict__ WV, const float* __restrict__ bK,
                          const float* __restrict__ bV, float* __restrict__ xK,
                          float* __restrict__ xV) {
  __shared__ float sK[4096], sV[4096], sbK[64], sbV[64];
  for (int i = threadIdx.x; i < 4096; i += 256) { sK[i] = WK[i]; sV[i] = WV[i]; }
  for (int i = threadIdx.x; i < 64; i += 256) { sbK[i] = bK[i]; sbV[i] = bV[i]; }
  __syncthreads();
  int row = blockIdx.x * 256 + threadIdx.x;
  if (row >= NN) return;
  const float4* xr = (const float4*)(ax + (size_t)row * 64);
  const float4* K4 = (const float4*)sK;
  const float4* V4 = (const float4*)sV;
  float aK[64], aV[64];
#pragma unroll
  for (int j = 0; j < 64; j++) { aK[j] = 0.f; aV[j] = 0.f; }
  for (int i4 = 0; i4 < 16; i4++) {
    float4 xv = xr[i4];
    float xs[4] = {xv.x, xv.y, xv.z, xv.w};
#pragma unroll
    for (int ii = 0; ii < 4; ii++) {
      int i = i4 * 4 + ii;
      float xi = xs[ii];
#pragma unroll
      for (int j4 = 0; j4 < 16; j4++) {
        float4 wk = K4[i * 16 + j4];
        float4 wv = V4[i * 16 + j4];
        FMA4(xi, wk, aK, 4 * j4);
        FMA4(xi, wv, aV, 4 * j4);
      }
    }
  }
  float4* oK = (float4*)(xK + (size_t)row * 64);
  float4* oV = (float4*)(xV + (size_t)row * 64);
#pragma unroll
  for (int j4 = 0; j4 < 16; j4++) {
    oK[j4] = make_float4(aK[4 * j4] + sbK[4 * j4], aK[4 * j4 + 1] + sbK[4 * j4 + 1],
                         aK[4 * j4 + 2] + sbK[4 * j4 + 2], aK[4 * j4 + 3] + sbK[4 * j4 + 3]);
    oV[j4] = make_float4(aV[4 * j4] + sbV[4 * j4], aV[4 * j4 + 1] + sbV[4 * j4 + 1],
                         aV[4 * j4 + 2] + sbV[4 * j4 + 2], aV[4 * j4 + 3] + sbV[4 * j4 + 3]);
  }
}

// ---------------- qh = (super_Q @ Wq^T + bq) * scale ----------------
__global__ void k_qh(const float* __restrict__ sQ, const float* __restrict__ in_w,
                     const float* __restrict__ in_b, float* __restrict__ qh) {
  int t = blockIdx.x * 256 + threadIdx.x;
  if (t >= 640) return;
  int l = t >> 6, c = t & 63;
  float acc = 0.f;
  for (int i = 0; i < 64; i++) acc = fmaf(sQ[l * 64 + i], in_w[c * 64 + i], acc);
  qh[t] = (acc + in_b[c]) * 0.35355339059327373f;  // 1/sqrt(8)
}

// ---------------- Kh/Vh (head-blocked), hGb (bf16), s_dst ----------------
__launch_bounds__(256)
__global__ void k_gemm2(const float* __restrict__ xK, const float* __restrict__ xV,
                        const float* __restrict__ in_w, const float* __restrict__ in_b,
                        const float* __restrict__ gatW, const float* __restrict__ a_dst,
                        float* __restrict__ Kh, float* __restrict__ Vh,
                        unsigned* __restrict__ hGb, float* __restrict__ s_dst) {
  __shared__ float sWk[4096], sWv[4096], sGW[4096];
  __shared__ float sBk[64], sBv[64], sAd[64];
  for (int t = threadIdx.x; t < 4096; t += 256) {
    int c = t & 63, i = t >> 6;
    sWk[i * 64 + c] = in_w[(64 + c) * 64 + i];   // transposed: [i][c]
    sWv[i * 64 + c] = in_w[(128 + c) * 64 + i];
    sGW[t] = gatW[t];                            // natural [i][j]
  }
  for (int t = threadIdx.x; t < 64; t += 256) {
    sBk[t] = in_b[64 + t]; sBv[t] = in_b[128 + t]; sAd[t] = a_dst[t];
  }
  __syncthreads();
  int row = blockIdx.x * 256 + threadIdx.x;
  if (row >= NN) return;
  // phase 1: K projection
  {
    const float4* xr = (const float4*)(xK + (size_t)row * 64);
    const float4* W4 = (const float4*)sWk;
    float a[64];
#pragma unroll
    for (int c = 0; c < 64; c++) a[c] = 0.f;
    for (int i4 = 0; i4 < 16; i4++) {
      float4 xv4 = xr[i4];
      float xs[4] = {xv4.x, xv4.y, xv4.z, xv4.w};
#pragma unroll
      for (int ii = 0; ii < 4; ii++) {
        float xi = xs[ii];
        int i = i4 * 4 + ii;
#pragma unroll
        for (int c4 = 0; c4 < 16; c4++) {
          float4 wk = W4[i * 16 + c4];
          FMA4(xi, wk, a, 4 * c4);
        }
      }
    }
#pragma unroll
    for (int h = 0; h < 8; h++) {
      float4* dst = (float4*)(Kh + (size_t)h * NN * 8 + (size_t)row * 8);
      dst[0] = make_float4(a[h * 8 + 0] + sBk[h * 8 + 0], a[h * 8 + 1] + sBk[h * 8 + 1],
                           a[h * 8 + 2] + sBk[h * 8 + 2], a[h * 8 + 3] + sBk[h * 8 + 3]);
      dst[1] = make_float4(a[h * 8 + 4] + sBk[h * 8 + 4], a[h * 8 + 5] + sBk[h * 8 + 5],
                           a[h * 8 + 6] + sBk[h * 8 + 6], a[h * 8 + 7] + sBk[h * 8 + 7]);
    }
  }
  // phase 2: V projection + GAT features + s_dst
  {
    const float4* xr = (const float4*)(xV + (size_t)row * 64);
    const float4* Wv4 = (const float4*)sWv;
    const float4* G4 = (const float4*)sGW;
    float av[64], ag[64];
#pragma unroll
    for (int c = 0; c < 64; c++) { av[c] = 0.f; ag[c] = 0.f; }
    for (int i4 = 0; i4 < 16; i4++) {
      float4 xv4 = xr[i4];
      float xs[4] = {xv4.x, xv4.y, xv4.z, xv4.w};
#pragma unroll
      for (int ii = 0; ii < 4; ii++) {
        float xi = xs[ii];
        int i = i4 * 4 + ii;
#pragma unroll
        for (int c4 = 0; c4 < 16; c4++) {
          float4 wv = Wv4[i * 16 + c4];
          float4 wg = G4[i * 16 + c4];
          FMA4(xi, wv, av, 4 * c4);
          FMA4(xi, wg, ag, 4 * c4);
        }
      }
    }
#pragma unroll
    for (int h = 0; h < 8; h++) {
      float4* dst = (float4*)(Vh + (size_t)h * NN * 8 + (size_t)row * 8);
      dst[0] = make_float4(av[h * 8 + 0] + sBv[h * 8 + 0], av[h * 8 + 1] + sBv[h * 8 + 1],
                           av[h * 8 + 2] + sBv[h * 8 + 2], av[h * 8 + 3] + sBv[h * 8 + 3]);
      dst[1] = make_float4(av[h * 8 + 4] + sBv[h * 8 + 4], av[h * 8 + 5] + sBv[h * 8 + 5],
                           av[h * 8 + 6] + sBv[h * 8 + 6], av[h * 8 + 7] + sBv[h * 8 + 7]);
    }
    float sd = 0.f;
#pragma unroll
    for (int j = 0; j < 64; j++) sd = fmaf(ag[j], sAd[j], sd);
    s_dst[row] = sd;
    uint4* gb4 = (uint4*)(hGb + (size_t)row * 32);
#pragma unroll
    for (int q = 0; q < 8; q++) {
      uint4 u;
      u.x = pack_bf2(ag[8 * q + 0], ag[8 * q + 1]);
      u.y = pack_bf2(ag[8 * q + 2], ag[8 * q + 3]);
      u.z = pack_bf2(ag[8 * q + 4], ag[8 * q + 5]);
      u.w = pack_bf2(ag[8 * q + 6], ag[8 * q + 7]);
      gb4[q] = u;
    }
  }
}

// ---------------- MHA main ----------------
__launch_bounds__(256)
__global__ void k_mha(const float* __restrict__ Kh, const float* __restrict__ Vh,
                      const float* __restrict__ qh, float* __restrict__ acc) {
  int h = blockIdx.x / BPH, b = blockIdx.x % BPH;
  __shared__ float sq[80];
  if (threadIdx.x < 80) {
    int l = threadIdx.x >> 3, j = threadIdx.x & 7;
    sq[threadIdx.x] = qh[l * 64 + h * 8 + j];
  }
  __syncthreads();
  const float4* Kp = (const float4*)(Kh + (size_t)h * NN * 8);
  const float4* Vp = (const float4*)(Vh + (size_t)h * NN * 8);
  const float4* sq4 = (const float4*)sq;
  float s[10], o[80];
#pragma unroll
  for (int l = 0; l < 10; l++) s[l] = 0.f;
#pragma unroll
  for (int t = 0; t < 80; t++) o[t] = 0.f;
  for (int n = b * 256 + threadIdx.x; n < NN; n += BPH * 256) {
    float4 k0 = Kp[n * 2], k1 = Kp[n * 2 + 1];
    float4 v0 = Vp[n * 2], v1 = Vp[n * 2 + 1];
#pragma unroll
    for (int l = 0; l < 10; l++) {
      float4 q0 = sq4[l * 2], q1 = sq4[l * 2 + 1];
      float z = q0.x * k0.x + q0.y * k0.y + q0.z * k0.z + q0.w * k0.w +
                q1.x * k1.x + q1.y * k1.y + q1.z * k1.z + q1.w * k1.w;
      float w = __expf(z);
      s[l] += w;
      o[l * 8 + 0] = fmaf(w, v0.x, o[l * 8 + 0]);
      o[l * 8 + 1] = fmaf(w, v0.y, o[l * 8 + 1]);
      o[l * 8 + 2] = fmaf(w, v0.z, o[l * 8 + 2]);
      o[l * 8 + 3] = fmaf(w, v0.w, o[l * 8 + 3]);
      o[l * 8 + 4] = fmaf(w, v1.x, o[l * 8 + 4]);
      o[l * 8 + 5] = fmaf(w, v1.y, o[l * 8 + 5]);
      o[l * 8 + 6] = fmaf(w, v1.z, o[l * 8 + 6]);
      o[l * 8 + 7] = fmaf(w, v1.w, o[l * 8 + 7]);
    }
  }
  int lane = threadIdx.x & 63;
#pragma unroll
  for (int l = 0; l < 10; l++) {
    float v = s[l];
#pragma unroll
    for (int off = 32; off > 0; off >>= 1) v += __shfl_down(v, off);
    if (lane == 0) atomicAdd(&acc[h * 10 + l], v);
  }
#pragma unroll
  for (int t = 0; t < 80; t++) {
    float v = o[t];
#pragma unroll
    for (int off = 32; off > 0; off >>= 1) v += __shfl_down(v, off);
    if (lane == 0) atomicAdd(&acc[80 + h * 80 + t], v);
  }
}

// ---------------- softmax finalize -> cluster -> context -> a_eff ----------------
__global__ void k_context(const float* __restrict__ acc, const float* __restrict__ out_w,
                          const float* __restrict__ out_b, const float* __restrict__ a_src,
                          const float* __restrict__ gat_Wc, float* __restrict__ aeff) {
  __shared__ float po[640], cl[640], ctx[64];
  int t = threadIdx.x;  // blockDim = 640
  {
    int h = t / 80, r = t % 80, l = r >> 3, j = r & 7;
    po[l * 64 + h * 8 + j] = acc[80 + t] / acc[h * 10 + l];
  }
  __syncthreads();
  {
    int l = t >> 6, d = t & 63;
    float v = out_b[d];
    for (int c = 0; c < 64; c++) v = fmaf(po[l * 64 + c], out_w[d * 64 + c], v);
    cl[t] = v;
  }
  __syncthreads();
  if (t < 64) {
    float m = 0.f;
#pragma unroll
    for (int l = 0; l < 10; l++) m += cl[l * 64 + t];
    ctx[t] = m * 0.1f;
  }
  __syncthreads();
  if (t < 64) {
    float v = a_src[t];
    for (int i = 0; i < 64; i++) v = fmaf(ctx[i], gat_Wc[i * 64 + t], v);
    aeff[t] = v;
  }
}

// ---------------- s_src[n] = dot(hG[n], a_eff) ----------------
__launch_bounds__(256)
__global__ void k_ssrc(const unsigned* __restrict__ hGb, const float* __restrict__ aeff,
                       float* __restrict__ s_src) {
  int gid = blockIdx.x * 256 + threadIdx.x;
  int n = gid >> 6, lane = gid & 63;
  if (n >= NN) return;
  const __hip_bfloat16* hp = (const __hip_bfloat16*)hGb;
  float v = __bfloat162float(hp[(size_t)n * 64 + lane]) * aeff[lane];
#pragma unroll
  for (int off = 32; off > 0; off >>= 1) v += __shfl_xor(v, off);
  if (lane == 0) s_src[n] = v;
}

// ---------------- GAT: single-sweep segment softmax + bf16 weighted gather ----------------
__launch_bounds__(256)
__global__ void k_gat(const int* __restrict__ offsets, const int* __restrict__ csr,
                      const float* __restrict__ s_src, const float* __restrict__ s_dstv,
                      const unsigned* __restrict__ hGb, const float* __restrict__ gat_b,
                      float* __restrict__ g) {
  int gid = blockIdx.x * 256 + threadIdx.x;
  int n = gid >> 6;
  if (n >= NN) return;
  int lane = gid & 63, l = lane & 31, half = lane >> 5;
  int e0 = offsets[n], e1 = offsets[n + 1];
  float sd = s_dstv[n];
  float den = 0.f, a0 = 0.f, a1 = 0.f;
  for (int j = e0 + half; j < e1; j += 2) {
    int s = csr[j];
    float z = s_src[s] + sd;
    z = z > 0.f ? z : 0.2f * z;
    float ex = __expf(z);   // logits O(1): softmax is shift-invariant, skip segment-max
    den += ex;
    unsigned u = hGb[(size_t)s * 32 + l];
    __hip_bfloat162 v = *reinterpret_cast<__hip_bfloat162*>(&u);
    a0 = fmaf(ex, __bfloat162float(v.x), a0);
    a1 = fmaf(ex, __bfloat162float(v.y), a1);
  }
  den += __shfl_xor(den, 32);
  a0 += __shfl_xor(a0, 32);
  a1 += __shfl_xor(a1, 32);
  float inv = 1.f / (den + 1e-16f);
  if (!half)
    ((float2*)g)[(size_t)n * 32 + l] =
        make_float2(a0 * inv + gat_b[2 * l], a1 * inv + gat_b[2 * l + 1]);
}

// ---------------- fused MLP (in-place on d_out) ----------------
__launch_bounds__(256)
__global__ void k_mlp(float* __restrict__ io, const float* __restrict__ W1,
                      const float* __restrict__ b1, const float* __restrict__ W2,
                      const float* __restrict__ b2) {
  __shared__ float sW1[64 * 128];  // transposed: [j][i]
  __shared__ float sW2[128 * 64];  // natural [j][k]
  __shared__ float sb1[128], sb2[64];
  for (int t = threadIdx.x; t < 8192; t += 256) {
    int j = t >> 6, i = t & 63;
    sW1[j * 64 + i] = W1[i * 128 + j];
    sW2[t] = W2[t];
  }
  for (int t = threadIdx.x; t < 128; t += 256) sb1[t] = b1[t];
  for (int t = threadIdx.x; t < 64; t += 256) sb2[t] = b2[t];
  __syncthreads();
  int row = blockIdx.x * 256 + threadIdx.x;
  if (row >= NN) return;
  float4* iop = (float4*)(io + (size_t)row * 64);
  float gr[64];
#pragma unroll
  for (int i4 = 0; i4 < 16; i4++) {
    float4 v = iop[i4];
    gr[4 * i4] = v.x; gr[4 * i4 + 1] = v.y; gr[4 * i4 + 2] = v.z; gr[4 * i4 + 3] = v.w;
  }
  float out[64];
#pragma unroll
  for (int k = 0; k < 64; k++) out[k] = sb2[k];
  const float4* W1t4 = (const float4*)sW1;
  const float4* W24 = (const float4*)sW2;
  for (int j = 0; j < 128; j++) {
    float hv = sb1[j];
#pragma unroll
    for (int i4 = 0; i4 < 16; i4++) {
      float4 wr = W1t4[j * 16 + i4];
      hv = fmaf(gr[4 * i4], wr.x, hv);
      hv = fmaf(gr[4 * i4 + 1], wr.y, hv);
      hv = fmaf(gr[4 * i4 + 2], wr.z, hv);
      hv = fmaf(gr[4 * i4 + 3], wr.w, hv);
    }
    hv = fmaxf(hv, 0.f);
#pragma unroll
    for (int k4 = 0; k4 < 16; k4++) {
      float4 wr = W24[j * 16 + k4];
      FMA4(hv, wr, out, 4 * k4);
    }
  }
#pragma unroll
  for (int k4 = 0; k4 < 16; k4++)
    iop[k4] = make_float4(fmaxf(out[4 * k4], 0.f), fmaxf(out[4 * k4 + 1], 0.f),
                          fmaxf(out[4 * k4 + 2], 0.f), fmaxf(out[4 * k4 + 3], 0.f));
}

// ---------------- host ----------------
extern "C" void kernel_launch(void* const* d_in, const int* in_sizes, int n_in,
                              void* d_out, int out_size, void* d_ws, size_t ws_size,
                              hipStream_t stream) {
  (void)in_sizes; (void)n_in; (void)out_size; (void)ws_size;
  const float* x        = (const float*)d_in[0];
  const int*   ei       = (const int*)d_in[1];
  const float* gcnK_W   = (const float*)d_in[2];
  const float* gcnK_b   = (const float*)d_in[3];
  const float* gcnV_W   = (const float*)d_in[4];
  const float* gcnV_b   = (const float*)d_in[5];
  const float* super_Q  = (const float*)d_in[6];
  const float* mha_in_w = (const float*)d_in[7];
  const float* mha_in_b = (const float*)d_in[8];
  const float* mha_out_w= (const float*)d_in[9];
  const float* mha_out_b= (const float*)d_in[10];
  const float* gat_W    = (const float*)d_in[11];
  const float* gat_Wc   = (const float*)d_in[12];
  const float* gat_a_src= (const float*)d_in[13];
  const float* gat_a_dst= (const float*)d_in[14];
  const float* gat_b    = (const float*)d_in[15];
  const float* t1_W     = (const float*)d_in[16];
  const float* t1_b     = (const float*)d_in[17];
  const float* t2_W     = (const float*)d_in[18];
  const float* t2_b     = (const float*)d_in[19];

  char* ws = (char*)d_ws;
  size_t cur = 0;
  auto alloc = [&](size_t bytes) -> char* {
    char* p = ws + cur;
    cur = (cur + bytes + 255) & ~(size_t)255;
    return p;
  };
  // zero-initialized region (single memset): counts, partition histogram, mha accumulators
  int*      counts = (int*)alloc((size_t)NN * 4);
  int*      pcnt   = (int*)alloc((size_t)NB * 8 * 16 * 4);   // padded: 1 counter / 64B line
  float*    macc   = (float*)alloc(720 * 4);
  size_t zero_bytes = cur;
  int*      ppos    = (int*)alloc((size_t)NB * 8 * 16 * 4);  // running cursors (init by k_boff)
  int*      offsets = (int*)alloc((size_t)(NN + 1) * 4);
  int*      tiles   = (int*)alloc((size_t)NT * 4);
  float*    dinv    = (float*)alloc((size_t)NN * 4);
  int*      csr     = (int*)alloc((size_t)EE * 4);
  unsigned* brec    = (unsigned*)alloc((size_t)EE * 4);
  float*    qh      = (float*)alloc(640 * 4);
  float*    aeff    = (float*)alloc(64 * 4);
  float*    s_src   = (float*)alloc((size_t)NN * 4);
  float*    s_dstv  = (float*)alloc((size_t)NN * 4);
  unsigned* xbf     = (unsigned*)alloc((size_t)NN * 128);   // bf16 x*dinv, 32 pairs/row
  float*    ax      = (float*)alloc((size_t)NN * 64 * 4);
  float*    xK      = (float*)alloc((size_t)NN * 64 * 4);
  float*    xV      = (float*)alloc((size_t)NN * 64 * 4);
  float*    Vh      = (float*)alloc((size_t)NN * 64 * 4);
  unsigned* hGb     = (unsigned*)alloc((size_t)NN * 128);   // bf16 GAT features
  float*    Kh      = ax;   // ax dead after k_gemm_kv; k_gemm2 writes Kh there
  float*    g       = (float*)d_out;

  (void)hipMemsetAsync(d_ws, 0, zero_bytes, stream);
  k_deg<<<(EE + 255) / 256, 256, 0, stream>>>(ei, counts, pcnt);
  k_scan_block<<<NT, 1024, 0, stream>>>(counts, offsets, tiles, dinv);
  k_scan_tiles<<<1, 64, 0, stream>>>(tiles);
  k_scan_add<<<(NN + 255) / 256, 256, 0, stream>>>(offsets, tiles);
  k_boff<<<(NB + 255) / 256, 256, 0, stream>>>(offsets, pcnt, ppos);
  k_fill_b<<<(EE + 255) / 256, 256, 0, stream>>>(ei, ppos, brec);
  k_fill_c<<<NB, 256, 0, stream>>>(brec, offsets, csr);
  k_prep<<<(NN * 32 + 255) / 256, 256, 0, stream>>>(x, dinv, xbf);
  k_agg_x<<<NN / 4, 256, 0, stream>>>(xbf, offsets, csr, dinv, ax);
  k_gemm_kv<<<(NN + 255) / 256, 256, 0, stream>>>(ax, gcnK_W, gcnV_W, gcnK_b, gcnV_b, xK, xV);
  k_qh<<<3, 256, 0, stream>>>(super_Q, mha_in_w, mha_in_b, qh);
  k_gemm2<<<(NN + 255) / 256, 256, 0, stream>>>(xK, xV, mha_in_w, mha_in_b, gat_W, gat_a_dst,
                                                Kh, Vh, hGb, s_dstv);
  k_mha<<<8 * BPH, 256, 0, stream>>>(Kh, Vh, qh, macc);
  k_context<<<1, 640, 0, stream>>>(macc, mha_out_w, mha_out_b, gat_a_src, gat_Wc, aeff);
  k_ssrc<<<NN / 4, 256, 0, stream>>>(hGb, aeff, s_src);
  k_gat<<<NN / 4, 256, 0, stream>>>(offsets, csr, s_src, s_dstv, hGb, gat_b, g);
  k_mlp<<<(NN + 255) / 256, 256, 0, stream>>>(g, t1_W, t1_b, t2_W, t2_b);
}

// Round 6
// 791.264 us; speedup vs baseline: 1.3875x; 1.0702x over previous
//
#include <hip/hip_runtime.h>
#include <hip/hip_bf16.h>
#include <stdint.h>

#define NN 100000
#define EE 1600000
#define NB 782         // ceil(NN/128) buckets for CSR fill
#define NP (NB * 8)    // (bucket, partition) regions
#define BPH 32         // MHA blocks per head

// fma of scalar xi with float4 vv into acc[base..base+3]
// (param name must NOT be 'x'/'y'/'z'/'w' — member tokens get macro-substituted!)
#define FMA4(xi, vv, a, base)                      \
  a[(base)+0] = fmaf((xi), (vv).x, a[(base)+0]);   \
  a[(base)+1] = fmaf((xi), (vv).y, a[(base)+1]);   \
  a[(base)+2] = fmaf((xi), (vv).z, a[(base)+2]);   \
  a[(base)+3] = fmaf((xi), (vv).w, a[(base)+3]);

__device__ inline unsigned pack_bf2(float a, float b) {
  __hip_bfloat162 t;
  t.x = __float2bfloat16(a);
  t.y = __float2bfloat16(b);
  return *reinterpret_cast<unsigned*>(&t);
}

// ---------------- per-(bucket,partition) histogram ONLY ----------------
// No random counts[] atomic: round-5 showed 1.6M device-wide scattered atomics
// = 64B HBM line-RMW each (100 MB WRITE, 124 us). pcnt atomics are
// partition(~XCD)-local, padded 1/64B-line -> L2-resident, cheap.
__global__ void k_hist(const int* __restrict__ ei, int* __restrict__ pcnt) {
  int e = blockIdx.x * 256 + threadIdx.x;
  if (e < EE) {
    int d = ei[EE + e];
    atomicAdd(&pcnt[((d >> 7) * 8 + (blockIdx.x & 7)) * 16], 1);
  }
}

// ---------------- scan 6256 region sizes -> ppos cursors + bucket bases ----------------
__launch_bounds__(1024)
__global__ void k_scanp(const int* __restrict__ pcnt, int* __restrict__ ppos,
                        int* __restrict__ bstart, int* __restrict__ offsets) {
  __shared__ int part[1024];
  int t = threadIdx.x;
  int i0 = t * 7, i1 = i0 + 7; if (i1 > NP) i1 = NP; if (i0 > NP) i0 = NP;
  int vals[7]; int sum = 0;
  for (int i = i0; i < i1; i++) { int v = pcnt[i * 16]; vals[i - i0] = v; sum += v; }
  part[t] = sum;
  __syncthreads();
  for (int off = 1; off < 1024; off <<= 1) {
    int v = (t >= off) ? part[t - off] : 0;
    __syncthreads();
    part[t] += v;
    __syncthreads();
  }
  int run = part[t] - sum;  // exclusive prefix
  for (int i = i0; i < i1; i++) {
    ppos[i * 16] = run;
    if ((i & 7) == 0) bstart[i >> 3] = run;
    run += vals[i - i0];
  }
  if (t == 0) { bstart[NB] = EE; offsets[NN] = EE; }
}

// ---------------- CSR fill pass B: partitioned bucket scatter ----------------
// Same launch geometry as k_hist => identical edge->partition mapping.
__global__ void k_fill_b(const int* __restrict__ ei, int* __restrict__ ppos,
                         unsigned* __restrict__ brec) {
  int e = blockIdx.x * 256 + threadIdx.x;
  if (e < EE) {
    int s = ei[e], d = ei[EE + e];
    int idx = ((d >> 7) * 8 + (blockIdx.x & 7)) * 16;
    int p = atomicAdd(&ppos[idx], 1);
    brec[p] = (unsigned)s | ((unsigned)(d & 127) << 17);  // NN < 2^17
  }
}

// ---------------- CSR fill pass C: bucket-local histogram + scan + place ----------------
// Also produces offsets[] and dinv[] with coalesced writes (replaces the three
// 100K-wide scan kernels and the random counts[] pass entirely).
__launch_bounds__(256)
__global__ void k_fill_c(const unsigned* __restrict__ brec, const int* __restrict__ bstart,
                         int* __restrict__ csr, int* __restrict__ offsets,
                         float* __restrict__ dinv) {
  __shared__ int lcnt[128], sm[128];
  int b = blockIdx.x, t = threadIdx.x;
  int nb0 = b << 7;
  int nn = NN - nb0; if (nn > 128) nn = 128;
  if (t < 128) lcnt[t] = 0;
  __syncthreads();
  int e0 = bstart[b], e1 = bstart[b + 1];
  for (int j = e0 + t; j < e1; j += 256)
    atomicAdd(&lcnt[(brec[j] >> 17) & 127], 1);
  __syncthreads();
  if (t < 128) sm[t] = lcnt[t];
  __syncthreads();
  for (int off = 1; off < 128; off <<= 1) {
    int v = (t < 128 && t >= off) ? sm[t - off] : 0;
    __syncthreads();
    if (t < 128) sm[t] += v;
    __syncthreads();
  }
  if (t < 128) {
    int cnt = lcnt[t];
    sm[t] -= cnt;  // exclusive prefix
    if (t < nn) {
      offsets[nb0 + t] = e0 + sm[t];
      dinv[nb0 + t] = rsqrtf((float)(cnt + 1));  // deg includes self loop
    }
    lcnt[t] = 0;  // reuse as placement cursor
  }
  __syncthreads();
  for (int j = e0 + t; j < e1; j += 256) {
    unsigned r = brec[j];
    int dl = (r >> 17) & 127;
    int p = atomicAdd(&lcnt[dl], 1);
    csr[e0 + sm[dl] + p] = r & 0x1FFFF;  // writes confined to this bucket's ~8KB window
  }
}

// ---------------- x~ = bf16(x * dinv[row]) ----------------
__global__ void k_prep(const float* __restrict__ x, const float* __restrict__ dinv,
                       unsigned* __restrict__ xbf2) {
  int i = blockIdx.x * 256 + threadIdx.x;  // pair index
  if (i >= NN * 32) return;
  float dv = dinv[i >> 5];
  float2 v = ((const float2*)x)[i];
  xbf2[i] = pack_bf2(v.x * dv, v.y * dv);
}

// ---------------- ax = A_norm @ x (wave per node, half-wave per edge parity) ----------------
__launch_bounds__(256)
__global__ void k_agg_x(const unsigned* __restrict__ xbf2, const int* __restrict__ offsets,
                        const int* __restrict__ csr, const float* __restrict__ dinv,
                        float* __restrict__ ax) {
  int gid = blockIdx.x * 256 + threadIdx.x;
  int n = gid >> 6;
  if (n >= NN) return;
  int lane = gid & 63, l = lane & 31, half = lane >> 5;
  int e0 = offsets[n], e1 = offsets[n + 1];
  float dv = dinv[n];
  float a0 = 0.f, a1 = 0.f;
  {  // self loop (half 0 only): x~[n] already contains x[n]*dv
    unsigned u = xbf2[(size_t)n * 32 + l];
    __hip_bfloat162 v = *reinterpret_cast<__hip_bfloat162*>(&u);
    if (!half) { a0 = __bfloat162float(v.x); a1 = __bfloat162float(v.y); }
  }
  for (int j = e0 + half; j < e1; j += 2) {
    int s = csr[j];
    unsigned u = xbf2[(size_t)s * 32 + l];
    __hip_bfloat162 v = *reinterpret_cast<__hip_bfloat162*>(&u);
    a0 += __bfloat162float(v.x);
    a1 += __bfloat162float(v.y);
  }
  a0 += __shfl_xor(a0, 32);
  a1 += __shfl_xor(a1, 32);
  if (!half) ((float2*)ax)[(size_t)n * 32 + l] = make_float2(a0 * dv, a1 * dv);
}

// ---------------- xK = ax@WK+bK, xV = ax@WV+bV ----------------
__launch_bounds__(256)
__global__ void k_gemm_kv(const float* __restrict__ ax, const float* __restrict__ WK,
                          const float* __restrict__ WV, const float* __restrict__ bK,
                          const float* __restrict__ bV, float* __restrict__ xK,
                          float* __restrict__ xV) {
  __shared__ float sK[4096], sV[4096], sbK[64], sbV[64];
  for (int i = threadIdx.x; i < 4096; i += 256) { sK[i] = WK[i]; sV[i] = WV[i]; }
  for (int i = threadIdx.x; i < 64; i += 256) { sbK[i] = bK[i]; sbV[i] = bV[i]; }
  __syncthreads();
  int row = blockIdx.x * 256 + threadIdx.x;
  if (row >= NN) return;
  const float4* xr = (const float4*)(ax + (size_t)row * 64);
  const float4* K4 = (const float4*)sK;
  const float4* V4 = (const float4*)sV;
  float aK[64], aV[64];
#pragma unroll
  for (int j = 0; j < 64; j++) { aK[j] = 0.f; aV[j] = 0.f; }
  for (int i4 = 0; i4 < 16; i4++) {
    float4 xv = xr[i4];
    float xs[4] = {xv.x, xv.y, xv.z, xv.w};
#pragma unroll
    for (int ii = 0; ii < 4; ii++) {
      int i = i4 * 4 + ii;
      float xi = xs[ii];
#pragma unroll
      for (int j4 = 0; j4 < 16; j4++) {
        float4 wk = K4[i * 16 + j4];
        float4 wv = V4[i * 16 + j4];
        FMA4(xi, wk, aK, 4 * j4);
        FMA4(xi, wv, aV, 4 * j4);
      }
    }
  }
  float4* oK = (float4*)(xK + (size_t)row * 64);
  float4* oV = (float4*)(xV + (size_t)row * 64);
#pragma unroll
  for (int j4 = 0; j4 < 16; j4++) {
    oK[j4] = make_float4(aK[4 * j4] + sbK[4 * j4], aK[4 * j4 + 1] + sbK[4 * j4 + 1],
                         aK[4 * j4 + 2] + sbK[4 * j4 + 2], aK[4 * j4 + 3] + sbK[4 * j4 + 3]);
    oV[j4] = make_float4(aV[4 * j4] + sbV[4 * j4], aV[4 * j4 + 1] + sbV[4 * j4 + 1],
                         aV[4 * j4 + 2] + sbV[4 * j4 + 2], aV[4 * j4 + 3] + sbV[4 * j4 + 3]);
  }
}

// ---------------- qh = (super_Q @ Wq^T + bq) * scale ----------------
__global__ void k_qh(const float* __restrict__ sQ, const float* __restrict__ in_w,
                     const float* __restrict__ in_b, float* __restrict__ qh) {
  int t = blockIdx.x * 256 + threadIdx.x;
  if (t >= 640) return;
  int l = t >> 6, c = t & 63;
  float acc = 0.f;
  for (int i = 0; i < 64; i++) acc = fmaf(sQ[l * 64 + i], in_w[c * 64 + i], acc);
  qh[t] = (acc + in_b[c]) * 0.35355339059327373f;  // 1/sqrt(8)
}

// ---------------- Kh/Vh (head-blocked), hGb (bf16), s_dst ----------------
__launch_bounds__(256)
__global__ void k_gemm2(const float* __restrict__ xK, const float* __restrict__ xV,
                        const float* __restrict__ in_w, const float* __restrict__ in_b,
                        const float* __restrict__ gatW, const float* __restrict__ a_dst,
                        float* __restrict__ Kh, float* __restrict__ Vh,
                        unsigned* __restrict__ hGb, float* __restrict__ s_dst) {
  __shared__ float sWk[4096], sWv[4096], sGW[4096];
  __shared__ float sBk[64], sBv[64], sAd[64];
  for (int t = threadIdx.x; t < 4096; t += 256) {
    int c = t & 63, i = t >> 6;
    sWk[i * 64 + c] = in_w[(64 + c) * 64 + i];   // transposed: [i][c]
    sWv[i * 64 + c] = in_w[(128 + c) * 64 + i];
    sGW[t] = gatW[t];                            // natural [i][j]
  }
  for (int t = threadIdx.x; t < 64; t += 256) {
    sBk[t] = in_b[64 + t]; sBv[t] = in_b[128 + t]; sAd[t] = a_dst[t];
  }
  __syncthreads();
  int row = blockIdx.x * 256 + threadIdx.x;
  if (row >= NN) return;
  // phase 1: K projection
  {
    const float4* xr = (const float4*)(xK + (size_t)row * 64);
    const float4* W4 = (const float4*)sWk;
    float a[64];
#pragma unroll
    for (int c = 0; c < 64; c++) a[c] = 0.f;
    for (int i4 = 0; i4 < 16; i4++) {
      float4 xv4 = xr[i4];
      float xs[4] = {xv4.x, xv4.y, xv4.z, xv4.w};
#pragma unroll
      for (int ii = 0; ii < 4; ii++) {
        float xi = xs[ii];
        int i = i4 * 4 + ii;
#pragma unroll
        for (int c4 = 0; c4 < 16; c4++) {
          float4 wk = W4[i * 16 + c4];
          FMA4(xi, wk, a, 4 * c4);
        }
      }
    }
#pragma unroll
    for (int h = 0; h < 8; h++) {
      float4* dst = (float4*)(Kh + (size_t)h * NN * 8 + (size_t)row * 8);
      dst[0] = make_float4(a[h * 8 + 0] + sBk[h * 8 + 0], a[h * 8 + 1] + sBk[h * 8 + 1],
                           a[h * 8 + 2] + sBk[h * 8 + 2], a[h * 8 + 3] + sBk[h * 8 + 3]);
      dst[1] = make_float4(a[h * 8 + 4] + sBk[h * 8 + 4], a[h * 8 + 5] + sBk[h * 8 + 5],
                           a[h * 8 + 6] + sBk[h * 8 + 6], a[h * 8 + 7] + sBk[h * 8 + 7]);
    }
  }
  // phase 2: V projection + GAT features + s_dst
  {
    const float4* xr = (const float4*)(xV + (size_t)row * 64);
    const float4* Wv4 = (const float4*)sWv;
    const float4* G4 = (const float4*)sGW;
    float av[64], ag[64];
#pragma unroll
    for (int c = 0; c < 64; c++) { av[c] = 0.f; ag[c] = 0.f; }
    for (int i4 = 0; i4 < 16; i4++) {
      float4 xv4 = xr[i4];
      float xs[4] = {xv4.x, xv4.y, xv4.z, xv4.w};
#pragma unroll
      for (int ii = 0; ii < 4; ii++) {
        float xi = xs[ii];
        int i = i4 * 4 + ii;
#pragma unroll
        for (int c4 = 0; c4 < 16; c4++) {
          float4 wv = Wv4[i * 16 + c4];
          float4 wg = G4[i * 16 + c4];
          FMA4(xi, wv, av, 4 * c4);
          FMA4(xi, wg, ag, 4 * c4);
        }
      }
    }
#pragma unroll
    for (int h = 0; h < 8; h++) {
      float4* dst = (float4*)(Vh + (size_t)h * NN * 8 + (size_t)row * 8);
      dst[0] = make_float4(av[h * 8 + 0] + sBv[h * 8 + 0], av[h * 8 + 1] + sBv[h * 8 + 1],
                           av[h * 8 + 2] + sBv[h * 8 + 2], av[h * 8 + 3] + sBv[h * 8 + 3]);
      dst[1] = make_float4(av[h * 8 + 4] + sBv[h * 8 + 4], av[h * 8 + 5] + sBv[h * 8 + 5],
                           av[h * 8 + 6] + sBv[h * 8 + 6], av[h * 8 + 7] + sBv[h * 8 + 7]);
    }
    float sd = 0.f;
#pragma unroll
    for (int j = 0; j < 64; j++) sd = fmaf(ag[j], sAd[j], sd);
    s_dst[row] = sd;
    uint4* gb4 = (uint4*)(hGb + (size_t)row * 32);
#pragma unroll
    for (int q = 0; q < 8; q++) {
      uint4 u;
      u.x = pack_bf2(ag[8 * q + 0], ag[8 * q + 1]);
      u.y = pack_bf2(ag[8 * q + 2], ag[8 * q + 3]);
      u.z = pack_bf2(ag[8 * q + 4], ag[8 * q + 5]);
      u.w = pack_bf2(ag[8 * q + 6], ag[8 * q + 7]);
      gb4[q] = u;
    }
  }
}

// ---------------- MHA main ----------------
__launch_bounds__(256)
__global__ void k_mha(const float* __restrict__ Kh, const float* __restrict__ Vh,
                      const float* __restrict__ qh, float* __restrict__ acc) {
  int h = blockIdx.x / BPH, b = blockIdx.x % BPH;
  __shared__ float sq[80];
  if (threadIdx.x < 80) {
    int l = threadIdx.x >> 3, j = threadIdx.x & 7;
    sq[threadIdx.x] = qh[l * 64 + h * 8 + j];
  }
  __syncthreads();
  const float4* Kp = (const float4*)(Kh + (size_t)h * NN * 8);
  const float4* Vp = (const float4*)(Vh + (size_t)h * NN * 8);
  const float4* sq4 = (const float4*)sq;
  float s[10], o[80];
#pragma unroll
  for (int l = 0; l < 10; l++) s[l] = 0.f;
#pragma unroll
  for (int t = 0; t < 80; t++) o[t] = 0.f;
  for (int n = b * 256 + threadIdx.x; n < NN; n += BPH * 256) {
    float4 k0 = Kp[n * 2], k1 = Kp[n * 2 + 1];
    float4 v0 = Vp[n * 2], v1 = Vp[n * 2 + 1];
#pragma unroll
    for (int l = 0; l < 10; l++) {
      float4 q0 = sq4[l * 2], q1 = sq4[l * 2 + 1];
      float z = q0.x * k0.x + q0.y * k0.y + q0.z * k0.z + q0.w * k0.w +
                q1.x * k1.x + q1.y * k1.y + q1.z * k1.z + q1.w * k1.w;
      float w = __expf(z);
      s[l] += w;
      o[l * 8 + 0] = fmaf(w, v0.x, o[l * 8 + 0]);
      o[l * 8 + 1] = fmaf(w, v0.y, o[l * 8 + 1]);
      o[l * 8 + 2] = fmaf(w, v0.z, o[l * 8 + 2]);
      o[l * 8 + 3] = fmaf(w, v0.w, o[l * 8 + 3]);
      o[l * 8 + 4] = fmaf(w, v1.x, o[l * 8 + 4]);
      o[l * 8 + 5] = fmaf(w, v1.y, o[l * 8 + 5]);
      o[l * 8 + 6] = fmaf(w, v1.z, o[l * 8 + 6]);
      o[l * 8 + 7] = fmaf(w, v1.w, o[l * 8 + 7]);
    }
  }
  int lane = threadIdx.x & 63;
#pragma unroll
  for (int l = 0; l < 10; l++) {
    float v = s[l];
#pragma unroll
    for (int off = 32; off > 0; off >>= 1) v += __shfl_down(v, off);
    if (lane == 0) atomicAdd(&acc[h * 10 + l], v);
  }
#pragma unroll
  for (int t = 0; t < 80; t++) {
    float v = o[t];
#pragma unroll
    for (int off = 32; off > 0; off >>= 1) v += __shfl_down(v, off);
    if (lane == 0) atomicAdd(&acc[80 + h * 80 + t], v);
  }
}

// ---------------- softmax finalize -> cluster -> context -> a_eff ----------------
__global__ void k_context(const float* __restrict__ acc, const float* __restrict__ out_w,
                          const float* __restrict__ out_b, const float* __restrict__ a_src,
                          const float* __restrict__ gat_Wc, float* __restrict__ aeff) {
  __shared__ float po[640], cl[640], ctx[64];
  int t = threadIdx.x;  // blockDim = 640
  {
    int h = t / 80, r = t % 80, l = r >> 3, j = r & 7;
    po[l * 64 + h * 8 + j] = acc[80 + t] / acc[h * 10 + l];
  }
  __syncthreads();
  {
    int l = t >> 6, d = t & 63;
    float v = out_b[d];
    for (int c = 0; c < 64; c++) v = fmaf(po[l * 64 + c], out_w[d * 64 + c], v);
    cl[t] = v;
  }
  __syncthreads();
  if (t < 64) {
    float m = 0.f;
#pragma unroll
    for (int l = 0; l < 10; l++) m += cl[l * 64 + t];
    ctx[t] = m * 0.1f;
  }
  __syncthreads();
  if (t < 64) {
    float v = a_src[t];
    for (int i = 0; i < 64; i++) v = fmaf(ctx[i], gat_Wc[i * 64 + t], v);
    aeff[t] = v;
  }
}

// ---------------- s_src[n] = dot(hG[n], a_eff) ----------------
__launch_bounds__(256)
__global__ void k_ssrc(const unsigned* __restrict__ hGb, const float* __restrict__ aeff,
                       float* __restrict__ s_src) {
  int gid = blockIdx.x * 256 + threadIdx.x;
  int n = gid >> 6, lane = gid & 63;
  if (n >= NN) return;
  const __hip_bfloat16* hp = (const __hip_bfloat16*)hGb;
  float v = __bfloat162float(hp[(size_t)n * 64 + lane]) * aeff[lane];
#pragma unroll
  for (int off = 32; off > 0; off >>= 1) v += __shfl_xor(v, off);
  if (lane == 0) s_src[n] = v;
}

// ---------------- GAT: single-sweep segment softmax + bf16 weighted gather ----------------
__launch_bounds__(256)
__global__ void k_gat(const int* __restrict__ offsets, const int* __restrict__ csr,
                      const float* __restrict__ s_src, const float* __restrict__ s_dstv,
                      const unsigned* __restrict__ hGb, const float* __restrict__ gat_b,
                      float* __restrict__ g) {
  int gid = blockIdx.x * 256 + threadIdx.x;
  int n = gid >> 6;
  if (n >= NN) return;
  int lane = gid & 63, l = lane & 31, half = lane >> 5;
  int e0 = offsets[n], e1 = offsets[n + 1];
  float sd = s_dstv[n];
  float den = 0.f, a0 = 0.f, a1 = 0.f;
  for (int j = e0 + half; j < e1; j += 2) {
    int s = csr[j];
    float z = s_src[s] + sd;
    z = z > 0.f ? z : 0.2f * z;
    float ex = __expf(z);   // logits O(1): softmax is shift-invariant, skip segment-max
    den += ex;
    unsigned u = hGb[(size_t)s * 32 + l];
    __hip_bfloat162 v = *reinterpret_cast<__hip_bfloat162*>(&u);
    a0 = fmaf(ex, __bfloat162float(v.x), a0);
    a1 = fmaf(ex, __bfloat162float(v.y), a1);
  }
  den += __shfl_xor(den, 32);
  a0 += __shfl_xor(a0, 32);
  a1 += __shfl_xor(a1, 32);
  float inv = 1.f / (den + 1e-16f);
  if (!half)
    ((float2*)g)[(size_t)n * 32 + l] =
        make_float2(a0 * inv + gat_b[2 * l], a1 * inv + gat_b[2 * l + 1]);
}

// ---------------- fused MLP (in-place on d_out) ----------------
__launch_bounds__(256)
__global__ void k_mlp(float* __restrict__ io, const float* __restrict__ W1,
                      const float* __restrict__ b1, const float* __restrict__ W2,
                      const float* __restrict__ b2) {
  __shared__ float sW1[64 * 128];  // transposed: [j][i]
  __shared__ float sW2[128 * 64];  // natural [j][k]
  __shared__ float sb1[128], sb2[64];
  for (int t = threadIdx.x; t < 8192; t += 256) {
    int j = t >> 6, i = t & 63;
    sW1[j * 64 + i] = W1[i * 128 + j];
    sW2[t] = W2[t];
  }
  for (int t = threadIdx.x; t < 128; t += 256) sb1[t] = b1[t];
  for (int t = threadIdx.x; t < 64; t += 256) sb2[t] = b2[t];
  __syncthreads();
  int row = blockIdx.x * 256 + threadIdx.x;
  if (row >= NN) return;
  float4* iop = (float4*)(io + (size_t)row * 64);
  float gr[64];
#pragma unroll
  for (int i4 = 0; i4 < 16; i4++) {
    float4 v = iop[i4];
    gr[4 * i4] = v.x; gr[4 * i4 + 1] = v.y; gr[4 * i4 + 2] = v.z; gr[4 * i4 + 3] = v.w;
  }
  float out[64];
#pragma unroll
  for (int k = 0; k < 64; k++) out[k] = sb2[k];
  const float4* W1t4 = (const float4*)sW1;
  const float4* W24 = (const float4*)sW2;
  for (int j = 0; j < 128; j++) {
    float hv = sb1[j];
#pragma unroll
    for (int i4 = 0; i4 < 16; i4++) {
      float4 wr = W1t4[j * 16 + i4];
      hv = fmaf(gr[4 * i4], wr.x, hv);
      hv = fmaf(gr[4 * i4 + 1], wr.y, hv);
      hv = fmaf(gr[4 * i4 + 2], wr.z, hv);
      hv = fmaf(gr[4 * i4 + 3], wr.w, hv);
    }
    hv = fmaxf(hv, 0.f);
#pragma unroll
    for (int k4 = 0; k4 < 16; k4++) {
      float4 wr = W24[j * 16 + k4];
      FMA4(hv, wr, out, 4 * k4);
    }
  }
#pragma unroll
  for (int k4 = 0; k4 < 16; k4++)
    iop[k4] = make_float4(fmaxf(out[4 * k4], 0.f), fmaxf(out[4 * k4 + 1], 0.f),
                          fmaxf(out[4 * k4 + 2], 0.f), fmaxf(out[4 * k4 + 3], 0.f));
}

// ---------------- host ----------------
extern "C" void kernel_launch(void* const* d_in, const int* in_sizes, int n_in,
                              void* d_out, int out_size, void* d_ws, size_t ws_size,
                              hipStream_t stream) {
  (void)in_sizes; (void)n_in; (void)out_size; (void)ws_size;
  const float* x        = (const float*)d_in[0];
  const int*   ei       = (const int*)d_in[1];
  const float* gcnK_W   = (const float*)d_in[2];
  const float* gcnK_b   = (const float*)d_in[3];
  const float* gcnV_W   = (const float*)d_in[4];
  const float* gcnV_b   = (const float*)d_in[5];
  const float* super_Q  = (const float*)d_in[6];
  const float* mha_in_w = (const float*)d_in[7];
  const float* mha_in_b = (const float*)d_in[8];
  const float* mha_out_w= (const float*)d_in[9];
  const float* mha_out_b= (const float*)d_in[10];
  const float* gat_W    = (const float*)d_in[11];
  const float* gat_Wc   = (const float*)d_in[12];
  const float* gat_a_src= (const float*)d_in[13];
  const float* gat_a_dst= (const float*)d_in[14];
  const float* gat_b    = (const float*)d_in[15];
  const float* t1_W     = (const float*)d_in[16];
  const float* t1_b     = (const float*)d_in[17];
  const float* t2_W     = (const float*)d_in[18];
  const float* t2_b     = (const float*)d_in[19];

  char* ws = (char*)d_ws;
  size_t cur = 0;
  auto alloc = [&](size_t bytes) -> char* {
    char* p = ws + cur;
    cur = (cur + bytes + 255) & ~(size_t)255;
    return p;
  };
  // zero-initialized region (single memset): partition histogram, mha accumulators
  int*      pcnt   = (int*)alloc((size_t)NP * 16 * 4);   // padded: 1 counter / 64B line
  float*    macc   = (float*)alloc(720 * 4);
  size_t zero_bytes = cur;
  int*      ppos    = (int*)alloc((size_t)NP * 16 * 4);  // running cursors (init by k_scanp)
  int*      bstart  = (int*)alloc((size_t)(NB + 1) * 4);
  int*      offsets = (int*)alloc((size_t)(NN + 1) * 4);
  float*    dinv    = (float*)alloc((size_t)NN * 4);
  int*      csr     = (int*)alloc((size_t)EE * 4);
  unsigned* brec    = (unsigned*)alloc((size_t)EE * 4);
  float*    qh      = (float*)alloc(640 * 4);
  float*    aeff    = (float*)alloc(64 * 4);
  float*    s_src   = (float*)alloc((size_t)NN * 4);
  float*    s_dstv  = (float*)alloc((size_t)NN * 4);
  unsigned* xbf     = (unsigned*)alloc((size_t)NN * 128);   // bf16 x*dinv, 32 pairs/row
  float*    ax      = (float*)alloc((size_t)NN * 64 * 4);
  float*    xK      = (float*)alloc((size_t)NN * 64 * 4);
  float*    xV      = (float*)alloc((size_t)NN * 64 * 4);
  float*    Vh      = (float*)alloc((size_t)NN * 64 * 4);
  unsigned* hGb     = (unsigned*)alloc((size_t)NN * 128);   // bf16 GAT features
  float*    Kh      = ax;   // ax dead after k_gemm_kv; k_gemm2 writes Kh there
  float*    g       = (float*)d_out;

  (void)hipMemsetAsync(d_ws, 0, zero_bytes, stream);
  k_hist<<<(EE + 255) / 256, 256, 0, stream>>>(ei, pcnt);
  k_scanp<<<1, 1024, 0, stream>>>(pcnt, ppos, bstart, offsets);
  k_fill_b<<<(EE + 255) / 256, 256, 0, stream>>>(ei, ppos, brec);
  k_fill_c<<<NB, 256, 0, stream>>>(brec, bstart, csr, offsets, dinv);
  k_prep<<<(NN * 32 + 255) / 256, 256, 0, stream>>>(x, dinv, xbf);
  k_agg_x<<<NN / 4, 256, 0, stream>>>(xbf, offsets, csr, dinv, ax);
  k_gemm_kv<<<(NN + 255) / 256, 256, 0, stream>>>(ax, gcnK_W, gcnV_W, gcnK_b, gcnV_b, xK, xV);
  k_qh<<<3, 256, 0, stream>>>(super_Q, mha_in_w, mha_in_b, qh);
  k_gemm2<<<(NN + 255) / 256, 256, 0, stream>>>(xK, xV, mha_in_w, mha_in_b, gat_W, gat_a_dst,
                                                Kh, Vh, hGb, s_dstv);
  k_mha<<<8 * BPH, 256, 0, stream>>>(Kh, Vh, qh, macc);
  k_context<<<1, 640, 0, stream>>>(macc, mha_out_w, mha_out_b, gat_a_src, gat_Wc, aeff);
  k_ssrc<<<NN / 4, 256, 0, stream>>>(hGb, aeff, s_src);
  k_gat<<<NN / 4, 256, 0, stream>>>(offsets, csr, s_src, s_dstv, hGb, gat_b, g);
  k_mlp<<<(NN + 255) / 256, 256, 0, stream>>>(g, t1_W, t1_b, t2_W, t2_b);
}

// Round 7
// 697.914 us; speedup vs baseline: 1.5731x; 1.1338x over previous
//
#include <hip/hip_runtime.h>
#include <hip/hip_bf16.h>
#include <stdint.h>

#define NN 100000
#define EE 1600000
#define NB 782         // ceil(NN/128) buckets for CSR fill
#define NP (NB * 8)    // (bucket, partition) regions
#define BPH 32         // MHA blocks per head

// fma of scalar xi with float4 vv into acc[base..base+3]
// (param name must NOT be 'x'/'y'/'z'/'w' — member tokens get macro-substituted!)
#define FMA4(xi, vv, a, base)                      \
  a[(base)+0] = fmaf((xi), (vv).x, a[(base)+0]);   \
  a[(base)+1] = fmaf((xi), (vv).y, a[(base)+1]);   \
  a[(base)+2] = fmaf((xi), (vv).z, a[(base)+2]);   \
  a[(base)+3] = fmaf((xi), (vv).w, a[(base)+3]);

__device__ inline unsigned pack_bf2(float a, float b) {
  __hip_bfloat162 t;
  t.x = __float2bfloat16(a);
  t.y = __float2bfloat16(b);
  return *reinterpret_cast<unsigned*>(&t);
}

// ---------------- per-(bucket,partition) histogram ----------------
__global__ void k_hist(const int* __restrict__ ei, int* __restrict__ pcnt) {
  int e = blockIdx.x * 256 + threadIdx.x;
  if (e < EE) {
    int d = ei[EE + e];
    atomicAdd(&pcnt[((d >> 7) * 8 + (blockIdx.x & 7)) * 16], 1);
  }
}

// ---------------- scan 6256 region sizes -> ppos cursors + bucket bases ----------------
__launch_bounds__(1024)
__global__ void k_scanp(const int* __restrict__ pcnt, int* __restrict__ ppos,
                        int* __restrict__ bstart, int* __restrict__ offsets) {
  __shared__ int part[1024];
  int t = threadIdx.x;
  int i0 = t * 7, i1 = i0 + 7; if (i1 > NP) i1 = NP; if (i0 > NP) i0 = NP;
  int vals[7]; int sum = 0;
  for (int i = i0; i < i1; i++) { int v = pcnt[i * 16]; vals[i - i0] = v; sum += v; }
  part[t] = sum;
  __syncthreads();
  for (int off = 1; off < 1024; off <<= 1) {
    int v = (t >= off) ? part[t - off] : 0;
    __syncthreads();
    part[t] += v;
    __syncthreads();
  }
  int run = part[t] - sum;  // exclusive prefix
  for (int i = i0; i < i1; i++) {
    ppos[i * 16] = run;
    if ((i & 7) == 0) bstart[i >> 3] = run;
    run += vals[i - i0];
  }
  if (t == 0) { bstart[NB] = EE; offsets[NN] = EE; }
}

// ---------------- CSR fill pass B: partitioned bucket scatter ----------------
__global__ void k_fill_b(const int* __restrict__ ei, int* __restrict__ ppos,
                         unsigned* __restrict__ brec) {
  int e = blockIdx.x * 256 + threadIdx.x;
  if (e < EE) {
    int s = ei[e], d = ei[EE + e];
    int idx = ((d >> 7) * 8 + (blockIdx.x & 7)) * 16;
    int p = atomicAdd(&ppos[idx], 1);
    brec[p] = (unsigned)s | ((unsigned)(d & 127) << 17);  // NN < 2^17
  }
}

// ---------------- CSR fill pass C: bucket-local histogram + scan + place ----------------
__launch_bounds__(256)
__global__ void k_fill_c(const unsigned* __restrict__ brec, const int* __restrict__ bstart,
                         int* __restrict__ csr, int* __restrict__ offsets,
                         float* __restrict__ dinv) {
  __shared__ int lcnt[128], sm[128];
  int b = blockIdx.x, t = threadIdx.x;
  int nb0 = b << 7;
  int nn = NN - nb0; if (nn > 128) nn = 128;
  if (t < 128) lcnt[t] = 0;
  __syncthreads();
  int e0 = bstart[b], e1 = bstart[b + 1];
  for (int j = e0 + t; j < e1; j += 256)
    atomicAdd(&lcnt[(brec[j] >> 17) & 127], 1);
  __syncthreads();
  if (t < 128) sm[t] = lcnt[t];
  __syncthreads();
  for (int off = 1; off < 128; off <<= 1) {
    int v = (t < 128 && t >= off) ? sm[t - off] : 0;
    __syncthreads();
    if (t < 128) sm[t] += v;
    __syncthreads();
  }
  if (t < 128) {
    int cnt = lcnt[t];
    sm[t] -= cnt;
    if (t < nn) {
      offsets[nb0 + t] = e0 + sm[t];
      dinv[nb0 + t] = rsqrtf((float)(cnt + 1));  // deg includes self loop
    }
    lcnt[t] = 0;  // reuse as placement cursor
  }
  __syncthreads();
  for (int j = e0 + t; j < e1; j += 256) {
    unsigned r = brec[j];
    int dl = (r >> 17) & 127;
    int p = atomicAdd(&lcnt[dl], 1);
    csr[e0 + sm[dl] + p] = r & 0x1FFFF;
  }
}

// ---------------- x~ = bf16(x * dinv[row]) ----------------
__global__ void k_prep(const float* __restrict__ x, const float* __restrict__ dinv,
                       unsigned* __restrict__ xbf2) {
  int i = blockIdx.x * 256 + threadIdx.x;  // pair index
  if (i >= NN * 32) return;
  float dv = dinv[i >> 5];
  float2 v = ((const float2*)x)[i];
  xbf2[i] = pack_bf2(v.x * dv, v.y * dv);
}

// ---------------- ax = A_norm @ x (wave per node, half-wave per edge parity) ----------------
__launch_bounds__(256)
__global__ void k_agg_x(const unsigned* __restrict__ xbf2, const int* __restrict__ offsets,
                        const int* __restrict__ csr, const float* __restrict__ dinv,
                        float* __restrict__ ax) {
  int gid = blockIdx.x * 256 + threadIdx.x;
  int n = gid >> 6;
  if (n >= NN) return;
  int lane = gid & 63, l = lane & 31, half = lane >> 5;
  int e0 = offsets[n], e1 = offsets[n + 1];
  float dv = dinv[n];
  float a0 = 0.f, a1 = 0.f;
  {
    unsigned u = xbf2[(size_t)n * 32 + l];
    __hip_bfloat162 v = *reinterpret_cast<__hip_bfloat162*>(&u);
    if (!half) { a0 = __bfloat162float(v.x); a1 = __bfloat162float(v.y); }
  }
  for (int j = e0 + half; j < e1; j += 2) {
    int s = csr[j];
    unsigned u = xbf2[(size_t)s * 32 + l];
    __hip_bfloat162 v = *reinterpret_cast<__hip_bfloat162*>(&u);
    a0 += __bfloat162float(v.x);
    a1 += __bfloat162float(v.y);
  }
  a0 += __shfl_xor(a0, 32);
  a1 += __shfl_xor(a1, 32);
  if (!half) ((float2*)ax)[(size_t)n * 32 + l] = make_float2(a0 * dv, a1 * dv);
}

// ---------------- fused weights: Wfk = WK@Wk^T, Wfv = WV@Wv^T, Wfg = WV@gatW ----------------
// Kh = ax@Wfk + bfk (etc.): associativity removes the xK/xV intermediates entirely.
__global__ void k_fusew(const float* __restrict__ gcnK_W, const float* __restrict__ gcnK_b,
                        const float* __restrict__ gcnV_W, const float* __restrict__ gcnV_b,
                        const float* __restrict__ mha_in_w, const float* __restrict__ mha_in_b,
                        const float* __restrict__ gat_W,
                        float* __restrict__ Wfk, float* __restrict__ Wfv,
                        float* __restrict__ Wfg, float* __restrict__ bf) {
  int blk = blockIdx.x;
  if (blk < 48) {
    int m = blk >> 4;
    int e = (blk & 15) * 256 + threadIdx.x;  // 0..4095
    int i = e >> 6, c = e & 63;
    float s = 0.f;
    if (m == 0) {
      for (int j = 0; j < 64; j++) s = fmaf(gcnK_W[i * 64 + j], mha_in_w[(64 + c) * 64 + j], s);
      Wfk[e] = s;
    } else if (m == 1) {
      for (int j = 0; j < 64; j++) s = fmaf(gcnV_W[i * 64 + j], mha_in_w[(128 + c) * 64 + j], s);
      Wfv[e] = s;
    } else {
      for (int j = 0; j < 64; j++) s = fmaf(gcnV_W[i * 64 + j], gat_W[j * 64 + c], s);
      Wfg[e] = s;
    }
  } else {
    int t = threadIdx.x;
    if (t < 64) {
      float s = mha_in_b[64 + t];
      for (int j = 0; j < 64; j++) s = fmaf(gcnK_b[j], mha_in_w[(64 + t) * 64 + j], s);
      bf[t] = s;
    } else if (t < 128) {
      int c = t - 64;
      float s = mha_in_b[128 + c];
      for (int j = 0; j < 64; j++) s = fmaf(gcnV_b[j], mha_in_w[(128 + c) * 64 + j], s);
      bf[64 + c] = s;
    } else if (t < 192) {
      int c = t - 128;
      float s = 0.f;
      for (int j = 0; j < 64; j++) s = fmaf(gcnV_b[j], gat_W[j * 64 + c], s);
      bf[128 + c] = s;
    }
  }
}

// ---------------- qh = (super_Q @ Wq^T + bq) * scale ----------------
__global__ void k_qh(const float* __restrict__ sQ, const float* __restrict__ in_w,
                     const float* __restrict__ in_b, float* __restrict__ qh) {
  int t = blockIdx.x * 256 + threadIdx.x;
  if (t >= 640) return;
  int l = t >> 6, c = t & 63;
  float acc = 0.f;
  for (int i = 0; i < 64; i++) acc = fmaf(sQ[l * 64 + i], in_w[c * 64 + i], acc);
  qh[t] = (acc + in_b[c]) * 0.35355339059327373f;  // 1/sqrt(8)
}

// ---------------- k_proj: ax -> Kh, Vh, hGb, s_dst (register-blocked 2rx8c) ----------------
// Round-6 gemm2 was LDS-BW-bound (48 KB LDS reads per row). Here: weights read
// once per 2 rows and 8 cols/thread (4x less LDS traffic), grid 1563 blocks.
__launch_bounds__(256)
__global__ void k_proj(const float* __restrict__ ax, const float* __restrict__ Wfk,
                       const float* __restrict__ Wfv, const float* __restrict__ Wfg,
                       const float* __restrict__ bf, const float* __restrict__ a_dst,
                       float* __restrict__ Kh, float* __restrict__ Vh,
                       unsigned* __restrict__ hGb, float* __restrict__ s_dstv) {
  __shared__ float sX[64 * 65];  // +1 pad: staging writes <=2-way conflict (free)
  __shared__ float sWk[4096], sWv[4096], sWg[4096];
  __shared__ float sB[192], sAd[64];
  int t = threadIdx.x;
  int base = blockIdx.x * 64;
  for (int i = t; i < 4096; i += 256) { sWk[i] = Wfk[i]; sWv[i] = Wfv[i]; sWg[i] = Wfg[i]; }
  if (t < 192) sB[t] = bf[t];
  if (t < 64) sAd[t] = a_dst[t];
  for (int idx = t; idx < 64 * 16; idx += 256) {
    int rl = idx >> 4, k4 = idx & 15;
    int row = base + rl;
    float4 v = (row < NN) ? ((const float4*)ax)[(size_t)row * 16 + k4]
                          : make_float4(0.f, 0.f, 0.f, 0.f);
    sX[rl * 65 + 4 * k4 + 0] = v.x;
    sX[rl * 65 + 4 * k4 + 1] = v.y;
    sX[rl * 65 + 4 * k4 + 2] = v.z;
    sX[rl * 65 + 4 * k4 + 3] = v.w;
  }
  __syncthreads();
  int cg = t & 7, rg = t >> 3;  // rows 2rg, 2rg+1; cols 8cg..8cg+7 (= head cg)
  int r0 = rg * 2;
  float aK[16], aV[16], aG[16];
#pragma unroll
  for (int i = 0; i < 16; i++) { aK[i] = 0.f; aV[i] = 0.f; aG[i] = 0.f; }
  const float4* Wk4 = (const float4*)sWk;
  const float4* Wv4 = (const float4*)sWv;
  const float4* Wg4 = (const float4*)sWg;
#pragma unroll 2
  for (int i = 0; i < 64; i++) {
    float x0 = sX[r0 * 65 + i];
    float x1 = sX[(r0 + 1) * 65 + i];
    float4 wk0 = Wk4[i * 16 + cg * 2], wk1 = Wk4[i * 16 + cg * 2 + 1];
    float4 wv0 = Wv4[i * 16 + cg * 2], wv1 = Wv4[i * 16 + cg * 2 + 1];
    float4 wg0 = Wg4[i * 16 + cg * 2], wg1 = Wg4[i * 16 + cg * 2 + 1];
    FMA4(x0, wk0, aK, 0); FMA4(x0, wk1, aK, 4);
    FMA4(x1, wk0, aK, 8); FMA4(x1, wk1, aK, 12);
    FMA4(x0, wv0, aV, 0); FMA4(x0, wv1, aV, 4);
    FMA4(x1, wv0, aV, 8); FMA4(x1, wv1, aV, 12);
    FMA4(x0, wg0, aG, 0); FMA4(x0, wg1, aG, 4);
    FMA4(x1, wg0, aG, 8); FMA4(x1, wg1, aG, 12);
  }
#pragma unroll
  for (int r = 0; r < 2; r++) {
    int row = base + r0 + r;
    bool ok = row < NN;
    int o = r * 8;
    float hg[8];
    float sd = 0.f;
#pragma unroll
    for (int c = 0; c < 8; c++) {
      hg[c] = aG[o + c] + sB[128 + cg * 8 + c];
      sd = fmaf(hg[c], sAd[cg * 8 + c], sd);
    }
    sd += __shfl_xor(sd, 1);
    sd += __shfl_xor(sd, 2);
    sd += __shfl_xor(sd, 4);
    if (ok) {
      float4* kp = (float4*)(Kh + (size_t)cg * NN * 8 + (size_t)row * 8);
      kp[0] = make_float4(aK[o + 0] + sB[cg * 8 + 0], aK[o + 1] + sB[cg * 8 + 1],
                          aK[o + 2] + sB[cg * 8 + 2], aK[o + 3] + sB[cg * 8 + 3]);
      kp[1] = make_float4(aK[o + 4] + sB[cg * 8 + 4], aK[o + 5] + sB[cg * 8 + 5],
                          aK[o + 6] + sB[cg * 8 + 6], aK[o + 7] + sB[cg * 8 + 7]);
      float4* vp = (float4*)(Vh + (size_t)cg * NN * 8 + (size_t)row * 8);
      vp[0] = make_float4(aV[o + 0] + sB[64 + cg * 8 + 0], aV[o + 1] + sB[64 + cg * 8 + 1],
                          aV[o + 2] + sB[64 + cg * 8 + 2], aV[o + 3] + sB[64 + cg * 8 + 3]);
      vp[1] = make_float4(aV[o + 4] + sB[64 + cg * 8 + 4], aV[o + 5] + sB[64 + cg * 8 + 5],
                          aV[o + 6] + sB[64 + cg * 8 + 6], aV[o + 7] + sB[64 + cg * 8 + 7]);
      uint4 u;
      u.x = pack_bf2(hg[0], hg[1]);
      u.y = pack_bf2(hg[2], hg[3]);
      u.z = pack_bf2(hg[4], hg[5]);
      u.w = pack_bf2(hg[6], hg[7]);
      ((uint4*)(hGb + (size_t)row * 32))[cg] = u;
      if (cg == 0) s_dstv[row] = sd;
    }
  }
}

// ---------------- MHA main ----------------
__launch_bounds__(256)
__global__ void k_mha(const float* __restrict__ Kh, const float* __restrict__ Vh,
                      const float* __restrict__ qh, float* __restrict__ acc) {
  int h = blockIdx.x / BPH, b = blockIdx.x % BPH;
  __shared__ float sq[80];
  if (threadIdx.x < 80) {
    int l = threadIdx.x >> 3, j = threadIdx.x & 7;
    sq[threadIdx.x] = qh[l * 64 + h * 8 + j];
  }
  __syncthreads();
  const float4* Kp = (const float4*)(Kh + (size_t)h * NN * 8);
  const float4* Vp = (const float4*)(Vh + (size_t)h * NN * 8);
  const float4* sq4 = (const float4*)sq;
  float s[10], o[80];
#pragma unroll
  for (int l = 0; l < 10; l++) s[l] = 0.f;
#pragma unroll
  for (int t = 0; t < 80; t++) o[t] = 0.f;
  for (int n = b * 256 + threadIdx.x; n < NN; n += BPH * 256) {
    float4 k0 = Kp[n * 2], k1 = Kp[n * 2 + 1];
    float4 v0 = Vp[n * 2], v1 = Vp[n * 2 + 1];
#pragma unroll
    for (int l = 0; l < 10; l++) {
      float4 q0 = sq4[l * 2], q1 = sq4[l * 2 + 1];
      float z = q0.x * k0.x + q0.y * k0.y + q0.z * k0.z + q0.w * k0.w +
                q1.x * k1.x + q1.y * k1.y + q1.z * k1.z + q1.w * k1.w;
      float w = __expf(z);
      s[l] += w;
      o[l * 8 + 0] = fmaf(w, v0.x, o[l * 8 + 0]);
      o[l * 8 + 1] = fmaf(w, v0.y, o[l * 8 + 1]);
      o[l * 8 + 2] = fmaf(w, v0.z, o[l * 8 + 2]);
      o[l * 8 + 3] = fmaf(w, v0.w, o[l * 8 + 3]);
      o[l * 8 + 4] = fmaf(w, v1.x, o[l * 8 + 4]);
      o[l * 8 + 5] = fmaf(w, v1.y, o[l * 8 + 5]);
      o[l * 8 + 6] = fmaf(w, v1.z, o[l * 8 + 6]);
      o[l * 8 + 7] = fmaf(w, v1.w, o[l * 8 + 7]);
    }
  }
  int lane = threadIdx.x & 63;
#pragma unroll
  for (int l = 0; l < 10; l++) {
    float v = s[l];
#pragma unroll
    for (int off = 32; off > 0; off >>= 1) v += __shfl_down(v, off);
    if (lane == 0) atomicAdd(&acc[h * 10 + l], v);
  }
#pragma unroll
  for (int t = 0; t < 80; t++) {
    float v = o[t];
#pragma unroll
    for (int off = 32; off > 0; off >>= 1) v += __shfl_down(v, off);
    if (lane == 0) atomicAdd(&acc[80 + h * 80 + t], v);
  }
}

// ---------------- softmax finalize -> cluster -> context -> a_eff ----------------
__global__ void k_context(const float* __restrict__ acc, const float* __restrict__ out_w,
                          const float* __restrict__ out_b, const float* __restrict__ a_src,
                          const float* __restrict__ gat_Wc, float* __restrict__ aeff) {
  __shared__ float po[640], cl[640], ctx[64];
  int t = threadIdx.x;  // blockDim = 640
  {
    int h = t / 80, r = t % 80, l = r >> 3, j = r & 7;
    po[l * 64 + h * 8 + j] = acc[80 + t] / acc[h * 10 + l];
  }
  __syncthreads();
  {
    int l = t >> 6, d = t & 63;
    float v = out_b[d];
    for (int c = 0; c < 64; c++) v = fmaf(po[l * 64 + c], out_w[d * 64 + c], v);
    cl[t] = v;
  }
  __syncthreads();
  if (t < 64) {
    float m = 0.f;
#pragma unroll
    for (int l = 0; l < 10; l++) m += cl[l * 64 + t];
    ctx[t] = m * 0.1f;
  }
  __syncthreads();
  if (t < 64) {
    float v = a_src[t];
    for (int i = 0; i < 64; i++) v = fmaf(ctx[i], gat_Wc[i * 64 + t], v);
    aeff[t] = v;
  }
}

// ---------------- s_src[n] = dot(hG[n], a_eff) ----------------
__launch_bounds__(256)
__global__ void k_ssrc(const unsigned* __restrict__ hGb, const float* __restrict__ aeff,
                       float* __restrict__ s_src) {
  int gid = blockIdx.x * 256 + threadIdx.x;
  int n = gid >> 6, lane = gid & 63;
  if (n >= NN) return;
  const __hip_bfloat16* hp = (const __hip_bfloat16*)hGb;
  float v = __bfloat162float(hp[(size_t)n * 64 + lane]) * aeff[lane];
#pragma unroll
  for (int off = 32; off > 0; off >>= 1) v += __shfl_xor(v, off);
  if (lane == 0) s_src[n] = v;
}

// ---------------- GAT: single-sweep segment softmax + bf16 weighted gather ----------------
__launch_bounds__(256)
__global__ void k_gat(const int* __restrict__ offsets, const int* __restrict__ csr,
                      const float* __restrict__ s_src, const float* __restrict__ s_dstv,
                      const unsigned* __restrict__ hGb, const float* __restrict__ gat_b,
                      float* __restrict__ g) {
  int gid = blockIdx.x * 256 + threadIdx.x;
  int n = gid >> 6;
  if (n >= NN) return;
  int lane = gid & 63, l = lane & 31, half = lane >> 5;
  int e0 = offsets[n], e1 = offsets[n + 1];
  float sd = s_dstv[n];
  float den = 0.f, a0 = 0.f, a1 = 0.f;
  for (int j = e0 + half; j < e1; j += 2) {
    int s = csr[j];
    float z = s_src[s] + sd;
    z = z > 0.f ? z : 0.2f * z;
    float ex = __expf(z);
    den += ex;
    unsigned u = hGb[(size_t)s * 32 + l];
    __hip_bfloat162 v = *reinterpret_cast<__hip_bfloat162*>(&u);
    a0 = fmaf(ex, __bfloat162float(v.x), a0);
    a1 = fmaf(ex, __bfloat162float(v.y), a1);
  }
  den += __shfl_xor(den, 32);
  a0 += __shfl_xor(a0, 32);
  a1 += __shfl_xor(a1, 32);
  float inv = 1.f / (den + 1e-16f);
  if (!half)
    ((float2*)g)[(size_t)n * 32 + l] =
        make_float2(a0 * inv + gat_b[2 * l], a1 * inv + gat_b[2 * l + 1]);
}

// ---------------- MLP stage 1: h1 = relu(g@W1+b1) -> bf16 (2r x 8c / thread) ----------------
__launch_bounds__(256)
__global__ void k_mlp1(const float* __restrict__ g, const float* __restrict__ W1,
                       const float* __restrict__ b1, unsigned* __restrict__ h1b) {
  __shared__ float sX[32 * 65];
  __shared__ float sW[64 * 128];
  __shared__ float sb[128];
  int t = threadIdx.x;
  int base = blockIdx.x * 32;
  for (int i = t; i < 8192; i += 256) sW[i] = W1[i];
  if (t < 128) sb[t] = b1[t];
  for (int idx = t; idx < 32 * 16; idx += 256) {
    int rl = idx >> 4, k4 = idx & 15;
    int row = base + rl;
    float4 v = (row < NN) ? ((const float4*)g)[(size_t)row * 16 + k4]
                          : make_float4(0.f, 0.f, 0.f, 0.f);
    sX[rl * 65 + 4 * k4 + 0] = v.x;
    sX[rl * 65 + 4 * k4 + 1] = v.y;
    sX[rl * 65 + 4 * k4 + 2] = v.z;
    sX[rl * 65 + 4 * k4 + 3] = v.w;
  }
  __syncthreads();
  int cg = t & 15, rg = t >> 4;  // rows 2rg, 2rg+1; cols 8cg..8cg+7
  int r0 = rg * 2;
  float a0[8], a1[8];
#pragma unroll
  for (int i = 0; i < 8; i++) { a0[i] = 0.f; a1[i] = 0.f; }
  const float4* W4 = (const float4*)sW;
#pragma unroll 4
  for (int i = 0; i < 64; i++) {
    float x0 = sX[r0 * 65 + i];
    float x1 = sX[(r0 + 1) * 65 + i];
    float4 w0 = W4[i * 32 + cg * 2], w1 = W4[i * 32 + cg * 2 + 1];
    FMA4(x0, w0, a0, 0); FMA4(x0, w1, a0, 4);
    FMA4(x1, w0, a1, 0); FMA4(x1, w1, a1, 4);
  }
#pragma unroll
  for (int r = 0; r < 2; r++) {
    int row = base + r0 + r;
    if (row >= NN) continue;
    float* a = r ? a1 : a0;
    float h[8];
#pragma unroll
    for (int c = 0; c < 8; c++) h[c] = fmaxf(a[c] + sb[cg * 8 + c], 0.f);
    uint4 u;
    u.x = pack_bf2(h[0], h[1]);
    u.y = pack_bf2(h[2], h[3]);
    u.z = pack_bf2(h[4], h[5]);
    u.w = pack_bf2(h[6], h[7]);
    ((uint4*)(h1b + (size_t)row * 64))[cg] = u;
  }
}

// ---------------- MLP stage 2: out = relu(h1@W2+b2) (2r x 8c / thread) ----------------
__launch_bounds__(256)
__global__ void k_mlp2(const unsigned* __restrict__ h1b, const float* __restrict__ W2,
                       const float* __restrict__ b2, float* __restrict__ out) {
  __shared__ unsigned sH[64 * 65];  // bf16 pairs
  __shared__ float sW[128 * 64];
  __shared__ float sb[64];
  int t = threadIdx.x;
  int base = blockIdx.x * 64;
  for (int i = t; i < 8192; i += 256) sW[i] = W2[i];
  if (t < 64) sb[t] = b2[t];
  for (int idx = t; idx < 64 * 16; idx += 256) {
    int rl = idx >> 4, c4 = idx & 15;
    int row = base + rl;
    uint4 v = (row < NN) ? ((const uint4*)h1b)[(size_t)row * 16 + c4]
                         : make_uint4(0u, 0u, 0u, 0u);
    sH[rl * 65 + 4 * c4 + 0] = v.x;
    sH[rl * 65 + 4 * c4 + 1] = v.y;
    sH[rl * 65 + 4 * c4 + 2] = v.z;
    sH[rl * 65 + 4 * c4 + 3] = v.w;
  }
  __syncthreads();
  int cg = t & 7, rg = t >> 3;  // rows 2rg, 2rg+1; cols 8cg..8cg+7
  int r0 = rg * 2;
  float a0[8], a1[8];
#pragma unroll
  for (int i = 0; i < 8; i++) { a0[i] = 0.f; a1[i] = 0.f; }
  const float4* W4 = (const float4*)sW;
#pragma unroll 2
  for (int kp = 0; kp < 64; kp++) {
    unsigned u0 = sH[r0 * 65 + kp];
    unsigned u1 = sH[(r0 + 1) * 65 + kp];
    float x0a = __uint_as_float(u0 << 16), x0b = __uint_as_float(u0 & 0xffff0000u);
    float x1a = __uint_as_float(u1 << 16), x1b = __uint_as_float(u1 & 0xffff0000u);
    int k0 = 2 * kp, k1 = 2 * kp + 1;
    float4 wa0 = W4[k0 * 16 + cg * 2], wa1 = W4[k0 * 16 + cg * 2 + 1];
    float4 wb0 = W4[k1 * 16 + cg * 2], wb1 = W4[k1 * 16 + cg * 2 + 1];
    FMA4(x0a, wa0, a0, 0); FMA4(x0a, wa1, a0, 4);
    FMA4(x0b, wb0, a0, 0); FMA4(x0b, wb1, a0, 4);
    FMA4(x1a, wa0, a1, 0); FMA4(x1a, wa1, a1, 4);
    FMA4(x1b, wb0, a1, 0); FMA4(x1b, wb1, a1, 4);
  }
#pragma unroll
  for (int r = 0; r < 2; r++) {
    int row = base + r0 + r;
    if (row >= NN) continue;
    float* a = r ? a1 : a0;
    float4* op = (float4*)(out + (size_t)row * 64 + cg * 8);
    op[0] = make_float4(fmaxf(a[0] + sb[cg * 8 + 0], 0.f), fmaxf(a[1] + sb[cg * 8 + 1], 0.f),
                        fmaxf(a[2] + sb[cg * 8 + 2], 0.f), fmaxf(a[3] + sb[cg * 8 + 3], 0.f));
    op[1] = make_float4(fmaxf(a[4] + sb[cg * 8 + 4], 0.f), fmaxf(a[5] + sb[cg * 8 + 5], 0.f),
                        fmaxf(a[6] + sb[cg * 8 + 6], 0.f), fmaxf(a[7] + sb[cg * 8 + 7], 0.f));
  }
}

// ---------------- host ----------------
extern "C" void kernel_launch(void* const* d_in, const int* in_sizes, int n_in,
                              void* d_out, int out_size, void* d_ws, size_t ws_size,
                              hipStream_t stream) {
  (void)in_sizes; (void)n_in; (void)out_size; (void)ws_size;
  const float* x        = (const float*)d_in[0];
  const int*   ei       = (const int*)d_in[1];
  const float* gcnK_W   = (const float*)d_in[2];
  const float* gcnK_b   = (const float*)d_in[3];
  const float* gcnV_W   = (const float*)d_in[4];
  const float* gcnV_b   = (const float*)d_in[5];
  const float* super_Q  = (const float*)d_in[6];
  const float* mha_in_w = (const float*)d_in[7];
  const float* mha_in_b = (const float*)d_in[8];
  const float* mha_out_w= (const float*)d_in[9];
  const float* mha_out_b= (const float*)d_in[10];
  const float* gat_W    = (const float*)d_in[11];
  const float* gat_Wc   = (const float*)d_in[12];
  const float* gat_a_src= (const float*)d_in[13];
  const float* gat_a_dst= (const float*)d_in[14];
  const float* gat_b    = (const float*)d_in[15];
  const float* t1_W     = (const float*)d_in[16];
  const float* t1_b     = (const float*)d_in[17];
  const float* t2_W     = (const float*)d_in[18];
  const float* t2_b     = (const float*)d_in[19];

  char* ws = (char*)d_ws;
  size_t cur = 0;
  auto alloc = [&](size_t bytes) -> char* {
    char* p = ws + cur;
    cur = (cur + bytes + 255) & ~(size_t)255;
    return p;
  };
  // zero-initialized region (single memset): partition histogram, mha accumulators
  int*      pcnt   = (int*)alloc((size_t)NP * 16 * 4);   // padded: 1 counter / 64B line
  float*    macc   = (float*)alloc(720 * 4);
  size_t zero_bytes = cur;
  int*      ppos    = (int*)alloc((size_t)NP * 16 * 4);
  int*      bstart  = (int*)alloc((size_t)(NB + 1) * 4);
  int*      offsets = (int*)alloc((size_t)(NN + 1) * 4);
  float*    dinv    = (float*)alloc((size_t)NN * 4);
  int*      csr     = (int*)alloc((size_t)EE * 4);
  unsigned* brec    = (unsigned*)alloc((size_t)EE * 4);
  float*    Wfk     = (float*)alloc(4096 * 4);
  float*    Wfv     = (float*)alloc(4096 * 4);
  float*    Wfg     = (float*)alloc(4096 * 4);
  float*    bfuse   = (float*)alloc(192 * 4);
  float*    qh      = (float*)alloc(640 * 4);
  float*    aeff    = (float*)alloc(64 * 4);
  float*    s_src   = (float*)alloc((size_t)NN * 4);
  float*    s_dstv  = (float*)alloc((size_t)NN * 4);
  unsigned* xbf     = (unsigned*)alloc((size_t)NN * 128);   // bf16 x*dinv
  float*    ax      = (float*)alloc((size_t)NN * 64 * 4);
  float*    Kh      = (float*)alloc((size_t)NN * 64 * 4);
  float*    Vh      = (float*)alloc((size_t)NN * 64 * 4);
  unsigned* hGb     = (unsigned*)alloc((size_t)NN * 128);   // bf16 GAT features
  unsigned* h1b     = (unsigned*)alloc((size_t)NN * 64 * 4); // bf16 MLP hidden (128/row)
  float*    g       = (float*)d_out;

  (void)hipMemsetAsync(d_ws, 0, zero_bytes, stream);
  k_hist<<<(EE + 255) / 256, 256, 0, stream>>>(ei, pcnt);
  k_scanp<<<1, 1024, 0, stream>>>(pcnt, ppos, bstart, offsets);
  k_fill_b<<<(EE + 255) / 256, 256, 0, stream>>>(ei, ppos, brec);
  k_fill_c<<<NB, 256, 0, stream>>>(brec, bstart, csr, offsets, dinv);
  k_prep<<<(NN * 32 + 255) / 256, 256, 0, stream>>>(x, dinv, xbf);
  k_agg_x<<<NN / 4, 256, 0, stream>>>(xbf, offsets, csr, dinv, ax);
  k_fusew<<<49, 256, 0, stream>>>(gcnK_W, gcnK_b, gcnV_W, gcnV_b, mha_in_w, mha_in_b,
                                  gat_W, Wfk, Wfv, Wfg, bfuse);
  k_qh<<<3, 256, 0, stream>>>(super_Q, mha_in_w, mha_in_b, qh);
  k_proj<<<(NN + 63) / 64, 256, 0, stream>>>(ax, Wfk, Wfv, Wfg, bfuse, gat_a_dst,
                                             Kh, Vh, hGb, s_dstv);
  k_mha<<<8 * BPH, 256, 0, stream>>>(Kh, Vh, qh, macc);
  k_context<<<1, 640, 0, stream>>>(macc, mha_out_w, mha_out_b, gat_a_src, gat_Wc, aeff);
  k_ssrc<<<NN / 4, 256, 0, stream>>>(hGb, aeff, s_src);
  k_gat<<<NN / 4, 256, 0, stream>>>(offsets, csr, s_src, s_dstv, hGb, gat_b, g);
  k_mlp1<<<(NN + 31) / 32, 256, 0, stream>>>(g, t1_W, t1_b, h1b);
  k_mlp2<<<(NN + 63) / 64, 256, 0, stream>>>(h1b, t2_W, t2_b, g);
}

// Round 8
// 657.656 us; speedup vs baseline: 1.6694x; 1.0612x over previous
//
#include <hip/hip_runtime.h>
#include <hip/hip_bf16.h>
#include <stdint.h>

#define NN 100000
#define EE 1600000
#define NB 782         // ceil(NN/128) buckets for CSR fill
#define NP (NB * 8)    // (bucket, partition) regions
#define BPH 128        // MHA blocks per head (atomic-free now -> more is fine)

// fma of scalar xi with float4 vv into acc[base..base+3]
// (param name must NOT be 'x'/'y'/'z'/'w' — member tokens get macro-substituted!)
#define FMA4(xi, vv, a, base)                      \
  a[(base)+0] = fmaf((xi), (vv).x, a[(base)+0]);   \
  a[(base)+1] = fmaf((xi), (vv).y, a[(base)+1]);   \
  a[(base)+2] = fmaf((xi), (vv).z, a[(base)+2]);   \
  a[(base)+3] = fmaf((xi), (vv).w, a[(base)+3]);

__device__ inline unsigned pack_bf2(float a, float b) {
  __hip_bfloat162 t;
  t.x = __float2bfloat16(a);
  t.y = __float2bfloat16(b);
  return *reinterpret_cast<unsigned*>(&t);
}

// ---------------- per-(bucket,partition) histogram ----------------
__global__ void k_hist(const int* __restrict__ ei, int* __restrict__ pcnt) {
  int e = blockIdx.x * 256 + threadIdx.x;
  if (e < EE) {
    int d = ei[EE + e];
    atomicAdd(&pcnt[((d >> 7) * 8 + (blockIdx.x & 7)) * 16], 1);
  }
}

// ---------------- scan 6256 region sizes -> ppos cursors + bucket bases ----------------
__launch_bounds__(1024)
__global__ void k_scanp(const int* __restrict__ pcnt, int* __restrict__ ppos,
                        int* __restrict__ bstart, int* __restrict__ offsets) {
  __shared__ int part[1024];
  int t = threadIdx.x;
  int i0 = t * 7, i1 = i0 + 7; if (i1 > NP) i1 = NP; if (i0 > NP) i0 = NP;
  int vals[7]; int sum = 0;
  for (int i = i0; i < i1; i++) { int v = pcnt[i * 16]; vals[i - i0] = v; sum += v; }
  part[t] = sum;
  __syncthreads();
  for (int off = 1; off < 1024; off <<= 1) {
    int v = (t >= off) ? part[t - off] : 0;
    __syncthreads();
    part[t] += v;
    __syncthreads();
  }
  int run = part[t] - sum;  // exclusive prefix
  for (int i = i0; i < i1; i++) {
    ppos[i * 16] = run;
    if ((i & 7) == 0) bstart[i >> 3] = run;
    run += vals[i - i0];
  }
  if (t == 0) { bstart[NB] = EE; offsets[NN] = EE; }
}

// ---------------- CSR fill pass B: partitioned bucket scatter ----------------
__global__ void k_fill_b(const int* __restrict__ ei, int* __restrict__ ppos,
                         unsigned* __restrict__ brec) {
  int e = blockIdx.x * 256 + threadIdx.x;
  if (e < EE) {
    int s = ei[e], d = ei[EE + e];
    int idx = ((d >> 7) * 8 + (blockIdx.x & 7)) * 16;
    int p = atomicAdd(&ppos[idx], 1);
    brec[p] = (unsigned)s | ((unsigned)(d & 127) << 17);  // NN < 2^17
  }
}

// ---------------- CSR fill pass C: bucket-local histogram + scan + place ----------------
__launch_bounds__(256)
__global__ void k_fill_c(const unsigned* __restrict__ brec, const int* __restrict__ bstart,
                         int* __restrict__ csr, int* __restrict__ offsets,
                         float* __restrict__ dinv) {
  __shared__ int lcnt[128], sm[128];
  int b = blockIdx.x, t = threadIdx.x;
  int nb0 = b << 7;
  int nn = NN - nb0; if (nn > 128) nn = 128;
  if (t < 128) lcnt[t] = 0;
  __syncthreads();
  int e0 = bstart[b], e1 = bstart[b + 1];
  for (int j = e0 + t; j < e1; j += 256)
    atomicAdd(&lcnt[(brec[j] >> 17) & 127], 1);
  __syncthreads();
  if (t < 128) sm[t] = lcnt[t];
  __syncthreads();
  for (int off = 1; off < 128; off <<= 1) {
    int v = (t < 128 && t >= off) ? sm[t - off] : 0;
    __syncthreads();
    if (t < 128) sm[t] += v;
    __syncthreads();
  }
  if (t < 128) {
    int cnt = lcnt[t];
    sm[t] -= cnt;
    if (t < nn) {
      offsets[nb0 + t] = e0 + sm[t];
      dinv[nb0 + t] = rsqrtf((float)(cnt + 1));  // deg includes self loop
    }
    lcnt[t] = 0;  // reuse as placement cursor
  }
  __syncthreads();
  for (int j = e0 + t; j < e1; j += 256) {
    unsigned r = brec[j];
    int dl = (r >> 17) & 127;
    int p = atomicAdd(&lcnt[dl], 1);
    csr[e0 + sm[dl] + p] = r & 0x1FFFF;
  }
}

// ---------------- x~ = bf16(x * dinv[row]) ----------------
__global__ void k_prep(const float* __restrict__ x, const float* __restrict__ dinv,
                       unsigned* __restrict__ xbf2) {
  int i = blockIdx.x * 256 + threadIdx.x;  // pair index
  if (i >= NN * 32) return;
  float dv = dinv[i >> 5];
  float2 v = ((const float2*)x)[i];
  xbf2[i] = pack_bf2(v.x * dv, v.y * dv);
}

// ---------------- ax = A_norm @ x (wave per node, half-wave per edge parity) ----------------
__launch_bounds__(256)
__global__ void k_agg_x(const unsigned* __restrict__ xbf2, const int* __restrict__ offsets,
                        const int* __restrict__ csr, const float* __restrict__ dinv,
                        float* __restrict__ ax) {
  int gid = blockIdx.x * 256 + threadIdx.x;
  int n = gid >> 6;
  if (n >= NN) return;
  int lane = gid & 63, l = lane & 31, half = lane >> 5;
  int e0 = offsets[n], e1 = offsets[n + 1];
  float dv = dinv[n];
  float a0 = 0.f, a1 = 0.f;
  {
    unsigned u = xbf2[(size_t)n * 32 + l];
    __hip_bfloat162 v = *reinterpret_cast<__hip_bfloat162*>(&u);
    if (!half) { a0 = __bfloat162float(v.x); a1 = __bfloat162float(v.y); }
  }
  for (int j = e0 + half; j < e1; j += 2) {
    int s = csr[j];
    unsigned u = xbf2[(size_t)s * 32 + l];
    __hip_bfloat162 v = *reinterpret_cast<__hip_bfloat162*>(&u);
    a0 += __bfloat162float(v.x);
    a1 += __bfloat162float(v.y);
  }
  a0 += __shfl_xor(a0, 32);
  a1 += __shfl_xor(a1, 32);
  if (!half) ((float2*)ax)[(size_t)n * 32 + l] = make_float2(a0 * dv, a1 * dv);
}

// ---------------- fused weights: Wfk = WK@Wk^T, Wfv = WV@Wv^T, Wfg = WV@gatW ----------------
__global__ void k_fusew(const float* __restrict__ gcnK_W, const float* __restrict__ gcnK_b,
                        const float* __restrict__ gcnV_W, const float* __restrict__ gcnV_b,
                        const float* __restrict__ mha_in_w, const float* __restrict__ mha_in_b,
                        const float* __restrict__ gat_W,
                        float* __restrict__ Wfk, float* __restrict__ Wfv,
                        float* __restrict__ Wfg, float* __restrict__ bf) {
  int blk = blockIdx.x;
  if (blk < 48) {
    int m = blk >> 4;
    int e = (blk & 15) * 256 + threadIdx.x;  // 0..4095
    int i = e >> 6, c = e & 63;
    float s = 0.f;
    if (m == 0) {
      for (int j = 0; j < 64; j++) s = fmaf(gcnK_W[i * 64 + j], mha_in_w[(64 + c) * 64 + j], s);
      Wfk[e] = s;
    } else if (m == 1) {
      for (int j = 0; j < 64; j++) s = fmaf(gcnV_W[i * 64 + j], mha_in_w[(128 + c) * 64 + j], s);
      Wfv[e] = s;
    } else {
      for (int j = 0; j < 64; j++) s = fmaf(gcnV_W[i * 64 + j], gat_W[j * 64 + c], s);
      Wfg[e] = s;
    }
  } else {
    int t = threadIdx.x;
    if (t < 64) {
      float s = mha_in_b[64 + t];
      for (int j = 0; j < 64; j++) s = fmaf(gcnK_b[j], mha_in_w[(64 + t) * 64 + j], s);
      bf[t] = s;
    } else if (t < 128) {
      int c = t - 64;
      float s = mha_in_b[128 + c];
      for (int j = 0; j < 64; j++) s = fmaf(gcnV_b[j], mha_in_w[(128 + c) * 64 + j], s);
      bf[64 + c] = s;
    } else if (t < 192) {
      int c = t - 128;
      float s = 0.f;
      for (int j = 0; j < 64; j++) s = fmaf(gcnV_b[j], gat_W[j * 64 + c], s);
      bf[128 + c] = s;
    }
  }
}

// ---------------- qh = (super_Q @ Wq^T + bq) * scale ----------------
__global__ void k_qh(const float* __restrict__ sQ, const float* __restrict__ in_w,
                     const float* __restrict__ in_b, float* __restrict__ qh) {
  int t = blockIdx.x * 256 + threadIdx.x;
  if (t >= 640) return;
  int l = t >> 6, c = t & 63;
  float acc = 0.f;
  for (int i = 0; i < 64; i++) acc = fmaf(sQ[l * 64 + i], in_w[c * 64 + i], acc);
  qh[t] = (acc + in_b[c]) * 0.35355339059327373f;  // 1/sqrt(8)
}

// ---------------- k_proj: ax -> Kh, Vh, hGb, s_dst (register-blocked 2rx8c) ----------------
__launch_bounds__(256)
__global__ void k_proj(const float* __restrict__ ax, const float* __restrict__ Wfk,
                       const float* __restrict__ Wfv, const float* __restrict__ Wfg,
                       const float* __restrict__ bf, const float* __restrict__ a_dst,
                       float* __restrict__ Kh, float* __restrict__ Vh,
                       unsigned* __restrict__ hGb, float* __restrict__ s_dstv) {
  __shared__ float sX[64 * 65];  // +1 pad: staging writes <=2-way conflict (free)
  __shared__ float sWk[4096], sWv[4096], sWg[4096];
  __shared__ float sB[192], sAd[64];
  int t = threadIdx.x;
  int base = blockIdx.x * 64;
  for (int i = t; i < 4096; i += 256) { sWk[i] = Wfk[i]; sWv[i] = Wfv[i]; sWg[i] = Wfg[i]; }
  if (t < 192) sB[t] = bf[t];
  if (t < 64) sAd[t] = a_dst[t];
  for (int idx = t; idx < 64 * 16; idx += 256) {
    int rl = idx >> 4, k4 = idx & 15;
    int row = base + rl;
    float4 v = (row < NN) ? ((const float4*)ax)[(size_t)row * 16 + k4]
                          : make_float4(0.f, 0.f, 0.f, 0.f);
    sX[rl * 65 + 4 * k4 + 0] = v.x;
    sX[rl * 65 + 4 * k4 + 1] = v.y;
    sX[rl * 65 + 4 * k4 + 2] = v.z;
    sX[rl * 65 + 4 * k4 + 3] = v.w;
  }
  __syncthreads();
  int cg = t & 7, rg = t >> 3;  // rows 2rg, 2rg+1; cols 8cg..8cg+7 (= head cg)
  int r0 = rg * 2;
  float aK[16], aV[16], aG[16];
#pragma unroll
  for (int i = 0; i < 16; i++) { aK[i] = 0.f; aV[i] = 0.f; aG[i] = 0.f; }
  const float4* Wk4 = (const float4*)sWk;
  const float4* Wv4 = (const float4*)sWv;
  const float4* Wg4 = (const float4*)sWg;
#pragma unroll 2
  for (int i = 0; i < 64; i++) {
    float x0 = sX[r0 * 65 + i];
    float x1 = sX[(r0 + 1) * 65 + i];
    float4 wk0 = Wk4[i * 16 + cg * 2], wk1 = Wk4[i * 16 + cg * 2 + 1];
    float4 wv0 = Wv4[i * 16 + cg * 2], wv1 = Wv4[i * 16 + cg * 2 + 1];
    float4 wg0 = Wg4[i * 16 + cg * 2], wg1 = Wg4[i * 16 + cg * 2 + 1];
    FMA4(x0, wk0, aK, 0); FMA4(x0, wk1, aK, 4);
    FMA4(x1, wk0, aK, 8); FMA4(x1, wk1, aK, 12);
    FMA4(x0, wv0, aV, 0); FMA4(x0, wv1, aV, 4);
    FMA4(x1, wv0, aV, 8); FMA4(x1, wv1, aV, 12);
    FMA4(x0, wg0, aG, 0); FMA4(x0, wg1, aG, 4);
    FMA4(x1, wg0, aG, 8); FMA4(x1, wg1, aG, 12);
  }
#pragma unroll
  for (int r = 0; r < 2; r++) {
    int row = base + r0 + r;
    bool ok = row < NN;
    int o = r * 8;
    float hg[8];
    float sd = 0.f;
#pragma unroll
    for (int c = 0; c < 8; c++) {
      hg[c] = aG[o + c] + sB[128 + cg * 8 + c];
      sd = fmaf(hg[c], sAd[cg * 8 + c], sd);
    }
    sd += __shfl_xor(sd, 1);
    sd += __shfl_xor(sd, 2);
    sd += __shfl_xor(sd, 4);
    if (ok) {
      float4* kp = (float4*)(Kh + (size_t)cg * NN * 8 + (size_t)row * 8);
      kp[0] = make_float4(aK[o + 0] + sB[cg * 8 + 0], aK[o + 1] + sB[cg * 8 + 1],
                          aK[o + 2] + sB[cg * 8 + 2], aK[o + 3] + sB[cg * 8 + 3]);
      kp[1] = make_float4(aK[o + 4] + sB[cg * 8 + 4], aK[o + 5] + sB[cg * 8 + 5],
                          aK[o + 6] + sB[cg * 8 + 6], aK[o + 7] + sB[cg * 8 + 7]);
      float4* vp = (float4*)(Vh + (size_t)cg * NN * 8 + (size_t)row * 8);
      vp[0] = make_float4(aV[o + 0] + sB[64 + cg * 8 + 0], aV[o + 1] + sB[64 + cg * 8 + 1],
                          aV[o + 2] + sB[64 + cg * 8 + 2], aV[o + 3] + sB[64 + cg * 8 + 3]);
      vp[1] = make_float4(aV[o + 4] + sB[64 + cg * 8 + 4], aV[o + 5] + sB[64 + cg * 8 + 5],
                          aV[o + 6] + sB[64 + cg * 8 + 6], aV[o + 7] + sB[64 + cg * 8 + 7]);
      uint4 u;
      u.x = pack_bf2(hg[0], hg[1]);
      u.y = pack_bf2(hg[2], hg[3]);
      u.z = pack_bf2(hg[4], hg[5]);
      u.w = pack_bf2(hg[6], hg[7]);
      ((uint4*)(hGb + (size_t)row * 32))[cg] = u;
      if (cg == 0) s_dstv[row] = sd;
    }
  }
}

// ---------------- MHA main: atomic-free (round-7: 92K cross-XCD atomic RMWs
// on 45 lines = ~100us serialized chain). Per-block partials, reduced by k_mred.
__launch_bounds__(256)
__global__ void k_mha(const float* __restrict__ Kh, const float* __restrict__ Vh,
                      const float* __restrict__ qh, float* __restrict__ part) {
  int h = blockIdx.x / BPH, b = blockIdx.x % BPH;
  __shared__ float sq[80];
  __shared__ float red[4][90];
  if (threadIdx.x < 80) {
    int l = threadIdx.x >> 3, j = threadIdx.x & 7;
    sq[threadIdx.x] = qh[l * 64 + h * 8 + j];
  }
  __syncthreads();
  const float4* Kp = (const float4*)(Kh + (size_t)h * NN * 8);
  const float4* Vp = (const float4*)(Vh + (size_t)h * NN * 8);
  const float4* sq4 = (const float4*)sq;
  float s[10], o[80];
#pragma unroll
  for (int l = 0; l < 10; l++) s[l] = 0.f;
#pragma unroll
  for (int t = 0; t < 80; t++) o[t] = 0.f;
  for (int n = b * 256 + threadIdx.x; n < NN; n += BPH * 256) {
    float4 k0 = Kp[n * 2], k1 = Kp[n * 2 + 1];
    float4 v0 = Vp[n * 2], v1 = Vp[n * 2 + 1];
#pragma unroll
    for (int l = 0; l < 10; l++) {
      float4 q0 = sq4[l * 2], q1 = sq4[l * 2 + 1];
      float z = q0.x * k0.x + q0.y * k0.y + q0.z * k0.z + q0.w * k0.w +
                q1.x * k1.x + q1.y * k1.y + q1.z * k1.z + q1.w * k1.w;
      float w = __expf(z);
      s[l] += w;
      o[l * 8 + 0] = fmaf(w, v0.x, o[l * 8 + 0]);
      o[l * 8 + 1] = fmaf(w, v0.y, o[l * 8 + 1]);
      o[l * 8 + 2] = fmaf(w, v0.z, o[l * 8 + 2]);
      o[l * 8 + 3] = fmaf(w, v0.w, o[l * 8 + 3]);
      o[l * 8 + 4] = fmaf(w, v1.x, o[l * 8 + 4]);
      o[l * 8 + 5] = fmaf(w, v1.y, o[l * 8 + 5]);
      o[l * 8 + 6] = fmaf(w, v1.z, o[l * 8 + 6]);
      o[l * 8 + 7] = fmaf(w, v1.w, o[l * 8 + 7]);
    }
  }
  int lane = threadIdx.x & 63, wave = threadIdx.x >> 6;
#pragma unroll
  for (int l = 0; l < 10; l++) {
    float v = s[l];
#pragma unroll
    for (int off = 32; off > 0; off >>= 1) v += __shfl_down(v, off);
    if (lane == 0) red[wave][l] = v;
  }
#pragma unroll
  for (int t = 0; t < 80; t++) {
    float v = o[t];
#pragma unroll
    for (int off = 32; off > 0; off >>= 1) v += __shfl_down(v, off);
    if (lane == 0) red[wave][10 + t] = v;
  }
  __syncthreads();
  if (threadIdx.x < 90) {
    float v = red[0][threadIdx.x] + red[1][threadIdx.x] +
              red[2][threadIdx.x] + red[3][threadIdx.x];
    part[(size_t)blockIdx.x * 90 + threadIdx.x] = v;
  }
}

// ---------------- reduce partials -> acc (layout k_context expects) ----------------
__global__ void k_mred(const float* __restrict__ part, float* __restrict__ acc) {
  int t = blockIdx.x * 256 + threadIdx.x;
  if (t >= 720) return;
  int h = t / 90, j = t % 90;
  float v = 0.f;
  for (int b = 0; b < BPH; b++) v += part[(size_t)(h * BPH + b) * 90 + j];
  if (j < 10) acc[h * 10 + j] = v;
  else acc[80 + h * 80 + (j - 10)] = v;
}

// ---------------- softmax finalize -> cluster -> context -> a_eff ----------------
__global__ void k_context(const float* __restrict__ acc, const float* __restrict__ out_w,
                          const float* __restrict__ out_b, const float* __restrict__ a_src,
                          const float* __restrict__ gat_Wc, float* __restrict__ aeff) {
  __shared__ float po[640], cl[640], ctx[64];
  int t = threadIdx.x;  // blockDim = 640
  {
    int h = t / 80, r = t % 80, l = r >> 3, j = r & 7;
    po[l * 64 + h * 8 + j] = acc[80 + t] / acc[h * 10 + l];
  }
  __syncthreads();
  {
    int l = t >> 6, d = t & 63;
    float v = out_b[d];
    for (int c = 0; c < 64; c++) v = fmaf(po[l * 64 + c], out_w[d * 64 + c], v);
    cl[t] = v;
  }
  __syncthreads();
  if (t < 64) {
    float m = 0.f;
#pragma unroll
    for (int l = 0; l < 10; l++) m += cl[l * 64 + t];
    ctx[t] = m * 0.1f;
  }
  __syncthreads();
  if (t < 64) {
    float v = a_src[t];
    for (int i = 0; i < 64; i++) v = fmaf(ctx[i], gat_Wc[i * 64 + t], v);
    aeff[t] = v;
  }
}

// ---------------- s_src[n] = dot(hG[n], a_eff) ----------------
__launch_bounds__(256)
__global__ void k_ssrc(const unsigned* __restrict__ hGb, const float* __restrict__ aeff,
                       float* __restrict__ s_src) {
  int gid = blockIdx.x * 256 + threadIdx.x;
  int n = gid >> 6, lane = gid & 63;
  if (n >= NN) return;
  const __hip_bfloat16* hp = (const __hip_bfloat16*)hGb;
  float v = __bfloat162float(hp[(size_t)n * 64 + lane]) * aeff[lane];
#pragma unroll
  for (int off = 32; off > 0; off >>= 1) v += __shfl_xor(v, off);
  if (lane == 0) s_src[n] = v;
}

// ---------------- GAT: single-sweep segment softmax + bf16 weighted gather ----------------
__launch_bounds__(256)
__global__ void k_gat(const int* __restrict__ offsets, const int* __restrict__ csr,
                      const float* __restrict__ s_src, const float* __restrict__ s_dstv,
                      const unsigned* __restrict__ hGb, const float* __restrict__ gat_b,
                      float* __restrict__ g) {
  int gid = blockIdx.x * 256 + threadIdx.x;
  int n = gid >> 6;
  if (n >= NN) return;
  int lane = gid & 63, l = lane & 31, half = lane >> 5;
  int e0 = offsets[n], e1 = offsets[n + 1];
  float sd = s_dstv[n];
  float den = 0.f, a0 = 0.f, a1 = 0.f;
  for (int j = e0 + half; j < e1; j += 2) {
    int s = csr[j];
    float z = s_src[s] + sd;
    z = z > 0.f ? z : 0.2f * z;
    float ex = __expf(z);
    den += ex;
    unsigned u = hGb[(size_t)s * 32 + l];
    __hip_bfloat162 v = *reinterpret_cast<__hip_bfloat162*>(&u);
    a0 = fmaf(ex, __bfloat162float(v.x), a0);
    a1 = fmaf(ex, __bfloat162float(v.y), a1);
  }
  den += __shfl_xor(den, 32);
  a0 += __shfl_xor(a0, 32);
  a1 += __shfl_xor(a1, 32);
  float inv = 1.f / (den + 1e-16f);
  if (!half)
    ((float2*)g)[(size_t)n * 32 + l] =
        make_float2(a0 * inv + gat_b[2 * l], a1 * inv + gat_b[2 * l + 1]);
}

// ---------------- MLP stage 1: h1 = relu(g@W1+b1) -> bf16 (2r x 8c / thread) ----------------
__launch_bounds__(256)
__global__ void k_mlp1(const float* __restrict__ g, const float* __restrict__ W1,
                       const float* __restrict__ b1, unsigned* __restrict__ h1b) {
  __shared__ float sX[32 * 65];
  __shared__ float sW[64 * 128];
  __shared__ float sb[128];
  int t = threadIdx.x;
  int base = blockIdx.x * 32;
  for (int i = t; i < 8192; i += 256) sW[i] = W1[i];
  if (t < 128) sb[t] = b1[t];
  for (int idx = t; idx < 32 * 16; idx += 256) {
    int rl = idx >> 4, k4 = idx & 15;
    int row = base + rl;
    float4 v = (row < NN) ? ((const float4*)g)[(size_t)row * 16 + k4]
                          : make_float4(0.f, 0.f, 0.f, 0.f);
    sX[rl * 65 + 4 * k4 + 0] = v.x;
    sX[rl * 65 + 4 * k4 + 1] = v.y;
    sX[rl * 65 + 4 * k4 + 2] = v.z;
    sX[rl * 65 + 4 * k4 + 3] = v.w;
  }
  __syncthreads();
  int cg = t & 15, rg = t >> 4;  // rows 2rg, 2rg+1; cols 8cg..8cg+7
  int r0 = rg * 2;
  float a0[8], a1[8];
#pragma unroll
  for (int i = 0; i < 8; i++) { a0[i] = 0.f; a1[i] = 0.f; }
  const float4* W4 = (const float4*)sW;
#pragma unroll 4
  for (int i = 0; i < 64; i++) {
    float x0 = sX[r0 * 65 + i];
    float x1 = sX[(r0 + 1) * 65 + i];
    float4 w0 = W4[i * 32 + cg * 2], w1 = W4[i * 32 + cg * 2 + 1];
    FMA4(x0, w0, a0, 0); FMA4(x0, w1, a0, 4);
    FMA4(x1, w0, a1, 0); FMA4(x1, w1, a1, 4);
  }
#pragma unroll
  for (int r = 0; r < 2; r++) {
    int row = base + r0 + r;
    if (row >= NN) continue;
    float* a = r ? a1 : a0;
    float h[8];
#pragma unroll
    for (int c = 0; c < 8; c++) h[c] = fmaxf(a[c] + sb[cg * 8 + c], 0.f);
    uint4 u;
    u.x = pack_bf2(h[0], h[1]);
    u.y = pack_bf2(h[2], h[3]);
    u.z = pack_bf2(h[4], h[5]);
    u.w = pack_bf2(h[6], h[7]);
    ((uint4*)(h1b + (size_t)row * 64))[cg] = u;
  }
}

// ---------------- MLP stage 2: out = relu(h1@W2+b2) (2r x 8c / thread) ----------------
__launch_bounds__(256)
__global__ void k_mlp2(const unsigned* __restrict__ h1b, const float* __restrict__ W2,
                       const float* __restrict__ b2, float* __restrict__ out) {
  __shared__ unsigned sH[64 * 65];  // bf16 pairs
  __shared__ float sW[128 * 64];
  __shared__ float sb[64];
  int t = threadIdx.x;
  int base = blockIdx.x * 64;
  for (int i = t; i < 8192; i += 256) sW[i] = W2[i];
  if (t < 64) sb[t] = b2[t];
  for (int idx = t; idx < 64 * 16; idx += 256) {
    int rl = idx >> 4, c4 = idx & 15;
    int row = base + rl;
    uint4 v = (row < NN) ? ((const uint4*)h1b)[(size_t)row * 16 + c4]
                         : make_uint4(0u, 0u, 0u, 0u);
    sH[rl * 65 + 4 * c4 + 0] = v.x;
    sH[rl * 65 + 4 * c4 + 1] = v.y;
    sH[rl * 65 + 4 * c4 + 2] = v.z;
    sH[rl * 65 + 4 * c4 + 3] = v.w;
  }
  __syncthreads();
  int cg = t & 7, rg = t >> 3;  // rows 2rg, 2rg+1; cols 8cg..8cg+7
  int r0 = rg * 2;
  float a0[8], a1[8];
#pragma unroll
  for (int i = 0; i < 8; i++) { a0[i] = 0.f; a1[i] = 0.f; }
  const float4* W4 = (const float4*)sW;
#pragma unroll 2
  for (int kp = 0; kp < 64; kp++) {
    unsigned u0 = sH[r0 * 65 + kp];
    unsigned u1 = sH[(r0 + 1) * 65 + kp];
    float x0a = __uint_as_float(u0 << 16), x0b = __uint_as_float(u0 & 0xffff0000u);
    float x1a = __uint_as_float(u1 << 16), x1b = __uint_as_float(u1 & 0xffff0000u);
    int k0 = 2 * kp, k1 = 2 * kp + 1;
    float4 wa0 = W4[k0 * 16 + cg * 2], wa1 = W4[k0 * 16 + cg * 2 + 1];
    float4 wb0 = W4[k1 * 16 + cg * 2], wb1 = W4[k1 * 16 + cg * 2 + 1];
    FMA4(x0a, wa0, a0, 0); FMA4(x0a, wa1, a0, 4);
    FMA4(x0b, wb0, a0, 0); FMA4(x0b, wb1, a0, 4);
    FMA4(x1a, wa0, a1, 0); FMA4(x1a, wa1, a1, 4);
    FMA4(x1b, wb0, a1, 0); FMA4(x1b, wb1, a1, 4);
  }
#pragma unroll
  for (int r = 0; r < 2; r++) {
    int row = base + r0 + r;
    if (row >= NN) continue;
    float* a = r ? a1 : a0;
    float4* op = (float4*)(out + (size_t)row * 64 + cg * 8);
    op[0] = make_float4(fmaxf(a[0] + sb[cg * 8 + 0], 0.f), fmaxf(a[1] + sb[cg * 8 + 1], 0.f),
                        fmaxf(a[2] + sb[cg * 8 + 2], 0.f), fmaxf(a[3] + sb[cg * 8 + 3], 0.f));
    op[1] = make_float4(fmaxf(a[4] + sb[cg * 8 + 4], 0.f), fmaxf(a[5] + sb[cg * 8 + 5], 0.f),
                        fmaxf(a[6] + sb[cg * 8 + 6], 0.f), fmaxf(a[7] + sb[cg * 8 + 7], 0.f));
  }
}

// ---------------- host ----------------
extern "C" void kernel_launch(void* const* d_in, const int* in_sizes, int n_in,
                              void* d_out, int out_size, void* d_ws, size_t ws_size,
                              hipStream_t stream) {
  (void)in_sizes; (void)n_in; (void)out_size; (void)ws_size;
  const float* x        = (const float*)d_in[0];
  const int*   ei       = (const int*)d_in[1];
  const float* gcnK_W   = (const float*)d_in[2];
  const float* gcnK_b   = (const float*)d_in[3];
  const float* gcnV_W   = (const float*)d_in[4];
  const float* gcnV_b   = (const float*)d_in[5];
  const float* super_Q  = (const float*)d_in[6];
  const float* mha_in_w = (const float*)d_in[7];
  const float* mha_in_b = (const float*)d_in[8];
  const float* mha_out_w= (const float*)d_in[9];
  const float* mha_out_b= (const float*)d_in[10];
  const float* gat_W    = (const float*)d_in[11];
  const float* gat_Wc   = (const float*)d_in[12];
  const float* gat_a_src= (const float*)d_in[13];
  const float* gat_a_dst= (const float*)d_in[14];
  const float* gat_b    = (const float*)d_in[15];
  const float* t1_W     = (const float*)d_in[16];
  const float* t1_b     = (const float*)d_in[17];
  const float* t2_W     = (const float*)d_in[18];
  const float* t2_b     = (const float*)d_in[19];

  char* ws = (char*)d_ws;
  size_t cur = 0;
  auto alloc = [&](size_t bytes) -> char* {
    char* p = ws + cur;
    cur = (cur + bytes + 255) & ~(size_t)255;
    return p;
  };
  // zero-initialized region (single memset): partition histogram only
  int*      pcnt   = (int*)alloc((size_t)NP * 16 * 4);   // padded: 1 counter / 64B line
  size_t zero_bytes = cur;
  int*      ppos    = (int*)alloc((size_t)NP * 16 * 4);
  int*      bstart  = (int*)alloc((size_t)(NB + 1) * 4);
  int*      offsets = (int*)alloc((size_t)(NN + 1) * 4);
  float*    dinv    = (float*)alloc((size_t)NN * 4);
  int*      csr     = (int*)alloc((size_t)EE * 4);
  unsigned* brec    = (unsigned*)alloc((size_t)EE * 4);
  float*    Wfk     = (float*)alloc(4096 * 4);
  float*    Wfv     = (float*)alloc(4096 * 4);
  float*    Wfg     = (float*)alloc(4096 * 4);
  float*    bfuse   = (float*)alloc(192 * 4);
  float*    qh      = (float*)alloc(640 * 4);
  float*    aeff    = (float*)alloc(64 * 4);
  float*    macc    = (float*)alloc(720 * 4);
  float*    part    = (float*)alloc((size_t)8 * BPH * 90 * 4);  // MHA partials
  float*    s_src   = (float*)alloc((size_t)NN * 4);
  float*    s_dstv  = (float*)alloc((size_t)NN * 4);
  unsigned* xbf     = (unsigned*)alloc((size_t)NN * 128);   // bf16 x*dinv
  float*    ax      = (float*)alloc((size_t)NN * 64 * 4);
  float*    Kh      = (float*)alloc((size_t)NN * 64 * 4);
  float*    Vh      = (float*)alloc((size_t)NN * 64 * 4);
  unsigned* hGb     = (unsigned*)alloc((size_t)NN * 128);   // bf16 GAT features
  unsigned* h1b     = (unsigned*)alloc((size_t)NN * 64 * 4); // bf16 MLP hidden (128/row)
  float*    g       = (float*)d_out;

  (void)hipMemsetAsync(d_ws, 0, zero_bytes, stream);
  k_hist<<<(EE + 255) / 256, 256, 0, stream>>>(ei, pcnt);
  k_scanp<<<1, 1024, 0, stream>>>(pcnt, ppos, bstart, offsets);
  k_fill_b<<<(EE + 255) / 256, 256, 0, stream>>>(ei, ppos, brec);
  k_fill_c<<<NB, 256, 0, stream>>>(brec, bstart, csr, offsets, dinv);
  k_prep<<<(NN * 32 + 255) / 256, 256, 0, stream>>>(x, dinv, xbf);
  k_agg_x<<<NN / 4, 256, 0, stream>>>(xbf, offsets, csr, dinv, ax);
  k_fusew<<<49, 256, 0, stream>>>(gcnK_W, gcnK_b, gcnV_W, gcnV_b, mha_in_w, mha_in_b,
                                  gat_W, Wfk, Wfv, Wfg, bfuse);
  k_qh<<<3, 256, 0, stream>>>(super_Q, mha_in_w, mha_in_b, qh);
  k_proj<<<(NN + 63) / 64, 256, 0, stream>>>(ax, Wfk, Wfv, Wfg, bfuse, gat_a_dst,
                                             Kh, Vh, hGb, s_dstv);
  k_mha<<<8 * BPH, 256, 0, stream>>>(Kh, Vh, qh, part);
  k_mred<<<3, 256, 0, stream>>>(part, macc);
  k_context<<<1, 640, 0, stream>>>(macc, mha_out_w, mha_out_b, gat_a_src, gat_Wc, aeff);
  k_ssrc<<<NN / 4, 256, 0, stream>>>(hGb, aeff, s_src);
  k_gat<<<NN / 4, 256, 0, stream>>>(offsets, csr, s_src, s_dstv, hGb, gat_b, g);
  k_mlp1<<<(NN + 31) / 32, 256, 0, stream>>>(g, t1_W, t1_b, h1b);
  k_mlp2<<<(NN + 63) / 64, 256, 0, stream>>>(h1b, t2_W, t2_b, g);
}

// Round 9
// 581.457 us; speedup vs baseline: 1.8882x; 1.1310x over previous
//
#include <hip/hip_runtime.h>
#include <hip/hip_bf16.h>
#include <stdint.h>

#define NN 100000
#define EE 1600000
#define NB 782         // ceil(NN/128) buckets for CSR fill
#define NP (NB * 8)    // (bucket, partition) regions
#define BPH 128        // MHA blocks per head

// fma of scalar xi with float4 vv into acc[base..base+3]
// (param name must NOT be 'x'/'y'/'z'/'w' — member tokens get macro-substituted!)
#define FMA4(xi, vv, a, base)                      \
  a[(base)+0] = fmaf((xi), (vv).x, a[(base)+0]);   \
  a[(base)+1] = fmaf((xi), (vv).y, a[(base)+1]);   \
  a[(base)+2] = fmaf((xi), (vv).z, a[(base)+2]);   \
  a[(base)+3] = fmaf((xi), (vv).w, a[(base)+3]);

__device__ inline unsigned pack_bf2(float a, float b) {
  __hip_bfloat162 t;
  t.x = __float2bfloat16(a);
  t.y = __float2bfloat16(b);
  return *reinterpret_cast<unsigned*>(&t);
}

// ---------------- per-(bucket,partition) histogram ----------------
__global__ void k_hist(const int* __restrict__ ei, int* __restrict__ pcnt) {
  int e = blockIdx.x * 256 + threadIdx.x;
  if (e < EE) {
    int d = ei[EE + e];
    atomicAdd(&pcnt[((d >> 7) * 8 + (blockIdx.x & 7)) * 16], 1);
  }
}

// ---------------- scan 6256 region sizes -> ppos cursors + bucket bases ----------------
__launch_bounds__(1024)
__global__ void k_scanp(const int* __restrict__ pcnt, int* __restrict__ ppos,
                        int* __restrict__ bstart, int* __restrict__ offsets) {
  __shared__ int part[1024];
  int t = threadIdx.x;
  int i0 = t * 7, i1 = i0 + 7; if (i1 > NP) i1 = NP; if (i0 > NP) i0 = NP;
  int vals[7]; int sum = 0;
  for (int i = i0; i < i1; i++) { int v = pcnt[i * 16]; vals[i - i0] = v; sum += v; }
  part[t] = sum;
  __syncthreads();
  for (int off = 1; off < 1024; off <<= 1) {
    int v = (t >= off) ? part[t - off] : 0;
    __syncthreads();
    part[t] += v;
    __syncthreads();
  }
  int run = part[t] - sum;  // exclusive prefix
  for (int i = i0; i < i1; i++) {
    ppos[i * 16] = run;
    if ((i & 7) == 0) bstart[i >> 3] = run;
    run += vals[i - i0];
  }
  if (t == 0) { bstart[NB] = EE; offsets[NN] = EE; }
}

// ---------------- CSR fill pass B: partitioned bucket scatter ----------------
__global__ void k_fill_b(const int* __restrict__ ei, int* __restrict__ ppos,
                         unsigned* __restrict__ brec) {
  int e = blockIdx.x * 256 + threadIdx.x;
  if (e < EE) {
    int s = ei[e], d = ei[EE + e];
    int idx = ((d >> 7) * 8 + (blockIdx.x & 7)) * 16;
    int p = atomicAdd(&ppos[idx], 1);
    brec[p] = (unsigned)s | ((unsigned)(d & 127) << 17);  // NN < 2^17
  }
}

// ---------------- CSR fill pass C: bucket-local histogram + scan + place ----------------
__launch_bounds__(256)
__global__ void k_fill_c(const unsigned* __restrict__ brec, const int* __restrict__ bstart,
                         int* __restrict__ csr, int* __restrict__ offsets,
                         float* __restrict__ dinv) {
  __shared__ int lcnt[128], sm[128];
  int b = blockIdx.x, t = threadIdx.x;
  int nb0 = b << 7;
  int nn = NN - nb0; if (nn > 128) nn = 128;
  if (t < 128) lcnt[t] = 0;
  __syncthreads();
  int e0 = bstart[b], e1 = bstart[b + 1];
  for (int j = e0 + t; j < e1; j += 256)
    atomicAdd(&lcnt[(brec[j] >> 17) & 127], 1);
  __syncthreads();
  if (t < 128) sm[t] = lcnt[t];
  __syncthreads();
  for (int off = 1; off < 128; off <<= 1) {
    int v = (t < 128 && t >= off) ? sm[t - off] : 0;
    __syncthreads();
    if (t < 128) sm[t] += v;
    __syncthreads();
  }
  if (t < 128) {
    int cnt = lcnt[t];
    sm[t] -= cnt;
    if (t < nn) {
      offsets[nb0 + t] = e0 + sm[t];
      dinv[nb0 + t] = rsqrtf((float)(cnt + 1));  // deg includes self loop
    }
    lcnt[t] = 0;  // reuse as placement cursor
  }
  __syncthreads();
  for (int j = e0 + t; j < e1; j += 256) {
    unsigned r = brec[j];
    int dl = (r >> 17) & 127;
    int p = atomicAdd(&lcnt[dl], 1);
    csr[e0 + sm[dl] + p] = r & 0x1FFFF;
  }
}

// ---------------- x~ = bf16(x * dinv[row]) ----------------
__global__ void k_prep(const float* __restrict__ x, const float* __restrict__ dinv,
                       unsigned* __restrict__ xbf2) {
  int i = blockIdx.x * 256 + threadIdx.x;  // pair index
  if (i >= NN * 32) return;
  float dv = dinv[i >> 5];
  float2 v = ((const float2*)x)[i];
  xbf2[i] = pack_bf2(v.x * dv, v.y * dv);
}

// ---------------- ax = A_norm @ x ----------------
// 8-lane-group gather: grp = lane>>3 picks 1 of 8 edges/iter, q = lane&7 picks a
// 16B uint4 chunk of the 128B row. 4x fewer load instrs, 4x less redundant
// scalar work vs half-wave scheme (round-8: mixed latency+VALU bound).
__launch_bounds__(256)
__global__ void k_agg_x(const unsigned* __restrict__ xbf2, const int* __restrict__ offsets,
                        const int* __restrict__ csr, const float* __restrict__ dinv,
                        float* __restrict__ ax) {
  int gid = blockIdx.x * 256 + threadIdx.x;
  int n = gid >> 6;
  if (n >= NN) return;
  int lane = gid & 63, q = lane & 7, grp = lane >> 3;
  int e0 = offsets[n], e1 = offsets[n + 1];
  float dv = dinv[n];
  float a[8];
#pragma unroll
  for (int i = 0; i < 8; i++) a[i] = 0.f;
  if (grp == 0) {  // self loop, counted once
    uint4 u = ((const uint4*)(xbf2 + (size_t)n * 32))[q];
    unsigned uu[4] = {u.x, u.y, u.z, u.w};
#pragma unroll
    for (int p = 0; p < 4; p++) {
      __hip_bfloat162 v = *reinterpret_cast<__hip_bfloat162*>(&uu[p]);
      a[2 * p] += __bfloat162float(v.x);
      a[2 * p + 1] += __bfloat162float(v.y);
    }
  }
  for (int base = e0; base < e1; base += 8) {
    int j = base + grp;
    if (j < e1) {
      int s = csr[j];
      uint4 u = ((const uint4*)(xbf2 + (size_t)s * 32))[q];
      unsigned uu[4] = {u.x, u.y, u.z, u.w};
#pragma unroll
      for (int p = 0; p < 4; p++) {
        __hip_bfloat162 v = *reinterpret_cast<__hip_bfloat162*>(&uu[p]);
        a[2 * p] += __bfloat162float(v.x);
        a[2 * p + 1] += __bfloat162float(v.y);
      }
    }
  }
#pragma unroll
  for (int i = 0; i < 8; i++) {
    a[i] += __shfl_xor(a[i], 8);
    a[i] += __shfl_xor(a[i], 16);
    a[i] += __shfl_xor(a[i], 32);
  }
  if (lane < 8) {
    float4* op = (float4*)(ax + (size_t)n * 64 + q * 8);
    op[0] = make_float4(a[0] * dv, a[1] * dv, a[2] * dv, a[3] * dv);
    op[1] = make_float4(a[4] * dv, a[5] * dv, a[6] * dv, a[7] * dv);
  }
}

// ---------------- fused weights: Wfk = WK@Wk^T, Wfv = WV@Wv^T, Wfg = WV@gatW ----------------
__global__ void k_fusew(const float* __restrict__ gcnK_W, const float* __restrict__ gcnK_b,
                        const float* __restrict__ gcnV_W, const float* __restrict__ gcnV_b,
                        const float* __restrict__ mha_in_w, const float* __restrict__ mha_in_b,
                        const float* __restrict__ gat_W,
                        float* __restrict__ Wfk, float* __restrict__ Wfv,
                        float* __restrict__ Wfg, float* __restrict__ bf) {
  int blk = blockIdx.x;
  if (blk < 48) {
    int m = blk >> 4;
    int e = (blk & 15) * 256 + threadIdx.x;  // 0..4095
    int i = e >> 6, c = e & 63;
    float s = 0.f;
    if (m == 0) {
      for (int j = 0; j < 64; j++) s = fmaf(gcnK_W[i * 64 + j], mha_in_w[(64 + c) * 64 + j], s);
      Wfk[e] = s;
    } else if (m == 1) {
      for (int j = 0; j < 64; j++) s = fmaf(gcnV_W[i * 64 + j], mha_in_w[(128 + c) * 64 + j], s);
      Wfv[e] = s;
    } else {
      for (int j = 0; j < 64; j++) s = fmaf(gcnV_W[i * 64 + j], gat_W[j * 64 + c], s);
      Wfg[e] = s;
    }
  } else {
    int t = threadIdx.x;
    if (t < 64) {
      float s = mha_in_b[64 + t];
      for (int j = 0; j < 64; j++) s = fmaf(gcnK_b[j], mha_in_w[(64 + t) * 64 + j], s);
      bf[t] = s;
    } else if (t < 128) {
      int c = t - 64;
      float s = mha_in_b[128 + c];
      for (int j = 0; j < 64; j++) s = fmaf(gcnV_b[j], mha_in_w[(128 + c) * 64 + j], s);
      bf[64 + c] = s;
    } else if (t < 192) {
      int c = t - 128;
      float s = 0.f;
      for (int j = 0; j < 64; j++) s = fmaf(gcnV_b[j], gat_W[j * 64 + c], s);
      bf[128 + c] = s;
    }
  }
}

// ---------------- qh = (super_Q @ Wq^T + bq) * scale ----------------
__global__ void k_qh(const float* __restrict__ sQ, const float* __restrict__ in_w,
                     const float* __restrict__ in_b, float* __restrict__ qh) {
  int t = blockIdx.x * 256 + threadIdx.x;
  if (t >= 640) return;
  int l = t >> 6, c = t & 63;
  float acc = 0.f;
  for (int i = 0; i < 64; i++) acc = fmaf(sQ[l * 64 + i], in_w[c * 64 + i], acc);
  qh[t] = (acc + in_b[c]) * 0.35355339059327373f;  // 1/sqrt(8)
}

// ---------------- k_proj: ax -> Kh, Vh, hGb, s_dst (register-blocked 2rx8c) ----------------
__launch_bounds__(256)
__global__ void k_proj(const float* __restrict__ ax, const float* __restrict__ Wfk,
                       const float* __restrict__ Wfv, const float* __restrict__ Wfg,
                       const float* __restrict__ bf, const float* __restrict__ a_dst,
                       float* __restrict__ Kh, float* __restrict__ Vh,
                       unsigned* __restrict__ hGb, float* __restrict__ s_dstv) {
  __shared__ float sX[64 * 65];  // +1 pad: staging writes <=2-way conflict (free)
  __shared__ float sWk[4096], sWv[4096], sWg[4096];
  __shared__ float sB[192], sAd[64];
  int t = threadIdx.x;
  int base = blockIdx.x * 64;
  for (int i = t; i < 4096; i += 256) { sWk[i] = Wfk[i]; sWv[i] = Wfv[i]; sWg[i] = Wfg[i]; }
  if (t < 192) sB[t] = bf[t];
  if (t < 64) sAd[t] = a_dst[t];
  for (int idx = t; idx < 64 * 16; idx += 256) {
    int rl = idx >> 4, k4 = idx & 15;
    int row = base + rl;
    float4 v = (row < NN) ? ((const float4*)ax)[(size_t)row * 16 + k4]
                          : make_float4(0.f, 0.f, 0.f, 0.f);
    sX[rl * 65 + 4 * k4 + 0] = v.x;
    sX[rl * 65 + 4 * k4 + 1] = v.y;
    sX[rl * 65 + 4 * k4 + 2] = v.z;
    sX[rl * 65 + 4 * k4 + 3] = v.w;
  }
  __syncthreads();
  int cg = t & 7, rg = t >> 3;  // rows 2rg, 2rg+1; cols 8cg..8cg+7 (= head cg)
  int r0 = rg * 2;
  float aK[16], aV[16], aG[16];
#pragma unroll
  for (int i = 0; i < 16; i++) { aK[i] = 0.f; aV[i] = 0.f; aG[i] = 0.f; }
  const float4* Wk4 = (const float4*)sWk;
  const float4* Wv4 = (const float4*)sWv;
  const float4* Wg4 = (const float4*)sWg;
#pragma unroll 2
  for (int i = 0; i < 64; i++) {
    float x0 = sX[r0 * 65 + i];
    float x1 = sX[(r0 + 1) * 65 + i];
    float4 wk0 = Wk4[i * 16 + cg * 2], wk1 = Wk4[i * 16 + cg * 2 + 1];
    float4 wv0 = Wv4[i * 16 + cg * 2], wv1 = Wv4[i * 16 + cg * 2 + 1];
    float4 wg0 = Wg4[i * 16 + cg * 2], wg1 = Wg4[i * 16 + cg * 2 + 1];
    FMA4(x0, wk0, aK, 0); FMA4(x0, wk1, aK, 4);
    FMA4(x1, wk0, aK, 8); FMA4(x1, wk1, aK, 12);
    FMA4(x0, wv0, aV, 0); FMA4(x0, wv1, aV, 4);
    FMA4(x1, wv0, aV, 8); FMA4(x1, wv1, aV, 12);
    FMA4(x0, wg0, aG, 0); FMA4(x0, wg1, aG, 4);
    FMA4(x1, wg0, aG, 8); FMA4(x1, wg1, aG, 12);
  }
#pragma unroll
  for (int r = 0; r < 2; r++) {
    int row = base + r0 + r;
    bool ok = row < NN;
    int o = r * 8;
    float hg[8];
    float sd = 0.f;
#pragma unroll
    for (int c = 0; c < 8; c++) {
      hg[c] = aG[o + c] + sB[128 + cg * 8 + c];
      sd = fmaf(hg[c], sAd[cg * 8 + c], sd);
    }
    sd += __shfl_xor(sd, 1);
    sd += __shfl_xor(sd, 2);
    sd += __shfl_xor(sd, 4);
    if (ok) {
      float4* kp = (float4*)(Kh + (size_t)cg * NN * 8 + (size_t)row * 8);
      kp[0] = make_float4(aK[o + 0] + sB[cg * 8 + 0], aK[o + 1] + sB[cg * 8 + 1],
                          aK[o + 2] + sB[cg * 8 + 2], aK[o + 3] + sB[cg * 8 + 3]);
      kp[1] = make_float4(aK[o + 4] + sB[cg * 8 + 4], aK[o + 5] + sB[cg * 8 + 5],
                          aK[o + 6] + sB[cg * 8 + 6], aK[o + 7] + sB[cg * 8 + 7]);
      float4* vp = (float4*)(Vh + (size_t)cg * NN * 8 + (size_t)row * 8);
      vp[0] = make_float4(aV[o + 0] + sB[64 + cg * 8 + 0], aV[o + 1] + sB[64 + cg * 8 + 1],
                          aV[o + 2] + sB[64 + cg * 8 + 2], aV[o + 3] + sB[64 + cg * 8 + 3]);
      vp[1] = make_float4(aV[o + 4] + sB[64 + cg * 8 + 4], aV[o + 5] + sB[64 + cg * 8 + 5],
                          aV[o + 6] + sB[64 + cg * 8 + 6], aV[o + 7] + sB[64 + cg * 8 + 7]);
      uint4 u;
      u.x = pack_bf2(hg[0], hg[1]);
      u.y = pack_bf2(hg[2], hg[3]);
      u.z = pack_bf2(hg[4], hg[5]);
      u.w = pack_bf2(hg[6], hg[7]);
      ((uint4*)(hGb + (size_t)row * 32))[cg] = u;
      if (cg == 0) s_dstv[row] = sd;
    }
  }
}

// ---------------- MHA main: atomic-free per-block partials ----------------
__launch_bounds__(256)
__global__ void k_mha(const float* __restrict__ Kh, const float* __restrict__ Vh,
                      const float* __restrict__ qh, float* __restrict__ part) {
  int h = blockIdx.x / BPH, b = blockIdx.x % BPH;
  __shared__ float sq[80];
  __shared__ float red[4][90];
  if (threadIdx.x < 80) {
    int l = threadIdx.x >> 3, j = threadIdx.x & 7;
    sq[threadIdx.x] = qh[l * 64 + h * 8 + j];
  }
  __syncthreads();
  const float4* Kp = (const float4*)(Kh + (size_t)h * NN * 8);
  const float4* Vp = (const float4*)(Vh + (size_t)h * NN * 8);
  const float4* sq4 = (const float4*)sq;
  float s[10], o[80];
#pragma unroll
  for (int l = 0; l < 10; l++) s[l] = 0.f;
#pragma unroll
  for (int t = 0; t < 80; t++) o[t] = 0.f;
  for (int n = b * 256 + threadIdx.x; n < NN; n += BPH * 256) {
    float4 k0 = Kp[n * 2], k1 = Kp[n * 2 + 1];
    float4 v0 = Vp[n * 2], v1 = Vp[n * 2 + 1];
#pragma unroll
    for (int l = 0; l < 10; l++) {
      float4 q0 = sq4[l * 2], q1 = sq4[l * 2 + 1];
      float z = q0.x * k0.x + q0.y * k0.y + q0.z * k0.z + q0.w * k0.w +
                q1.x * k1.x + q1.y * k1.y + q1.z * k1.z + q1.w * k1.w;
      float w = __expf(z);
      s[l] += w;
      o[l * 8 + 0] = fmaf(w, v0.x, o[l * 8 + 0]);
      o[l * 8 + 1] = fmaf(w, v0.y, o[l * 8 + 1]);
      o[l * 8 + 2] = fmaf(w, v0.z, o[l * 8 + 2]);
      o[l * 8 + 3] = fmaf(w, v0.w, o[l * 8 + 3]);
      o[l * 8 + 4] = fmaf(w, v1.x, o[l * 8 + 4]);
      o[l * 8 + 5] = fmaf(w, v1.y, o[l * 8 + 5]);
      o[l * 8 + 6] = fmaf(w, v1.z, o[l * 8 + 6]);
      o[l * 8 + 7] = fmaf(w, v1.w, o[l * 8 + 7]);
    }
  }
  int lane = threadIdx.x & 63, wave = threadIdx.x >> 6;
#pragma unroll
  for (int l = 0; l < 10; l++) {
    float v = s[l];
#pragma unroll
    for (int off = 32; off > 0; off >>= 1) v += __shfl_down(v, off);
    if (lane == 0) red[wave][l] = v;
  }
#pragma unroll
  for (int t = 0; t < 80; t++) {
    float v = o[t];
#pragma unroll
    for (int off = 32; off > 0; off >>= 1) v += __shfl_down(v, off);
    if (lane == 0) red[wave][10 + t] = v;
  }
  __syncthreads();
  if (threadIdx.x < 90) {
    float v = red[0][threadIdx.x] + red[1][threadIdx.x] +
              red[2][threadIdx.x] + red[3][threadIdx.x];
    part[(size_t)blockIdx.x * 90 + threadIdx.x] = v;
  }
}

// ---------------- reduce partials -> acc ----------------
__global__ void k_mred(const float* __restrict__ part, float* __restrict__ acc) {
  int t = blockIdx.x * 256 + threadIdx.x;
  if (t >= 720) return;
  int h = t / 90, j = t % 90;
  float v = 0.f;
  for (int b = 0; b < BPH; b++) v += part[(size_t)(h * BPH + b) * 90 + j];
  if (j < 10) acc[h * 10 + j] = v;
  else acc[80 + h * 80 + (j - 10)] = v;
}

// ---------------- softmax finalize -> cluster -> context -> a_eff ----------------
__global__ void k_context(const float* __restrict__ acc, const float* __restrict__ out_w,
                          const float* __restrict__ out_b, const float* __restrict__ a_src,
                          const float* __restrict__ gat_Wc, float* __restrict__ aeff) {
  __shared__ float po[640], cl[640], ctx[64];
  int t = threadIdx.x;  // blockDim = 640
  {
    int h = t / 80, r = t % 80, l = r >> 3, j = r & 7;
    po[l * 64 + h * 8 + j] = acc[80 + t] / acc[h * 10 + l];
  }
  __syncthreads();
  {
    int l = t >> 6, d = t & 63;
    float v = out_b[d];
    for (int c = 0; c < 64; c++) v = fmaf(po[l * 64 + c], out_w[d * 64 + c], v);
    cl[t] = v;
  }
  __syncthreads();
  if (t < 64) {
    float m = 0.f;
#pragma unroll
    for (int l = 0; l < 10; l++) m += cl[l * 64 + t];
    ctx[t] = m * 0.1f;
  }
  __syncthreads();
  if (t < 64) {
    float v = a_src[t];
    for (int i = 0; i < 64; i++) v = fmaf(ctx[i], gat_Wc[i * 64 + t], v);
    aeff[t] = v;
  }
}

// ---------------- s_src[n] = dot(hG[n], a_eff) ----------------
__launch_bounds__(256)
__global__ void k_ssrc(const unsigned* __restrict__ hGb, const float* __restrict__ aeff,
                       float* __restrict__ s_src) {
  int gid = blockIdx.x * 256 + threadIdx.x;
  int n = gid >> 6, lane = gid & 63;
  if (n >= NN) return;
  const __hip_bfloat16* hp = (const __hip_bfloat16*)hGb;
  float v = __bfloat162float(hp[(size_t)n * 64 + lane]) * aeff[lane];
#pragma unroll
  for (int off = 32; off > 0; off >>= 1) v += __shfl_xor(v, off);
  if (lane == 0) s_src[n] = v;
}

// ---------------- GAT: 8-lane-group gather (same scheme as k_agg_x) ----------------
__launch_bounds__(256)
__global__ void k_gat(const int* __restrict__ offsets, const int* __restrict__ csr,
                      const float* __restrict__ s_src, const float* __restrict__ s_dstv,
                      const unsigned* __restrict__ hGb, const float* __restrict__ gat_b,
                      float* __restrict__ g) {
  int gid = blockIdx.x * 256 + threadIdx.x;
  int n = gid >> 6;
  if (n >= NN) return;
  int lane = gid & 63, q = lane & 7, grp = lane >> 3;
  int e0 = offsets[n], e1 = offsets[n + 1];
  float sd = s_dstv[n];
  float den = 0.f;
  float a[8];
#pragma unroll
  for (int i = 0; i < 8; i++) a[i] = 0.f;
  for (int base = e0; base < e1; base += 8) {
    int j = base + grp;
    if (j < e1) {
      int s = csr[j];
      float z = s_src[s] + sd;
      z = z > 0.f ? z : 0.2f * z;
      float ex = __expf(z);  // logits O(1): softmax shift-invariant, skip segment-max
      den += ex;
      uint4 u = ((const uint4*)(hGb + (size_t)s * 32))[q];
      unsigned uu[4] = {u.x, u.y, u.z, u.w};
#pragma unroll
      for (int p = 0; p < 4; p++) {
        __hip_bfloat162 v = *reinterpret_cast<__hip_bfloat162*>(&uu[p]);
        a[2 * p] = fmaf(ex, __bfloat162float(v.x), a[2 * p]);
        a[2 * p + 1] = fmaf(ex, __bfloat162float(v.y), a[2 * p + 1]);
      }
    }
  }
  // den identical within a group; xor over group-id bits sums the 8 groups
  den += __shfl_xor(den, 8);
  den += __shfl_xor(den, 16);
  den += __shfl_xor(den, 32);
#pragma unroll
  for (int i = 0; i < 8; i++) {
    a[i] += __shfl_xor(a[i], 8);
    a[i] += __shfl_xor(a[i], 16);
    a[i] += __shfl_xor(a[i], 32);
  }
  float inv = 1.f / (den + 1e-16f);
  if (lane < 8) {
    float4* op = (float4*)(g + (size_t)n * 64 + q * 8);
    op[0] = make_float4(a[0] * inv + gat_b[q * 8 + 0], a[1] * inv + gat_b[q * 8 + 1],
                        a[2] * inv + gat_b[q * 8 + 2], a[3] * inv + gat_b[q * 8 + 3]);
    op[1] = make_float4(a[4] * inv + gat_b[q * 8 + 4], a[5] * inv + gat_b[q * 8 + 5],
                        a[6] * inv + gat_b[q * 8 + 6], a[7] * inv + gat_b[q * 8 + 7]);
  }
}

// ---------------- MLP stage 1: h1 = relu(g@W1+b1) -> bf16 (2r x 8c / thread) ----------------
__launch_bounds__(256)
__global__ void k_mlp1(const float* __restrict__ g, const float* __restrict__ W1,
                       const float* __restrict__ b1, unsigned* __restrict__ h1b) {
  __shared__ float sX[32 * 65];
  __shared__ float sW[64 * 128];
  __shared__ float sb[128];
  int t = threadIdx.x;
  int base = blockIdx.x * 32;
  for (int i = t; i < 8192; i += 256) sW[i] = W1[i];
  if (t < 128) sb[t] = b1[t];
  for (int idx = t; idx < 32 * 16; idx += 256) {
    int rl = idx >> 4, k4 = idx & 15;
    int row = base + rl;
    float4 v = (row < NN) ? ((const float4*)g)[(size_t)row * 16 + k4]
                          : make_float4(0.f, 0.f, 0.f, 0.f);
    sX[rl * 65 + 4 * k4 + 0] = v.x;
    sX[rl * 65 + 4 * k4 + 1] = v.y;
    sX[rl * 65 + 4 * k4 + 2] = v.z;
    sX[rl * 65 + 4 * k4 + 3] = v.w;
  }
  __syncthreads();
  int cg = t & 15, rg = t >> 4;  // rows 2rg, 2rg+1; cols 8cg..8cg+7
  int r0 = rg * 2;
  float a0[8], a1[8];
#pragma unroll
  for (int i = 0; i < 8; i++) { a0[i] = 0.f; a1[i] = 0.f; }
  const float4* W4 = (const float4*)sW;
#pragma unroll 4
  for (int i = 0; i < 64; i++) {
    float x0 = sX[r0 * 65 + i];
    float x1 = sX[(r0 + 1) * 65 + i];
    float4 w0 = W4[i * 32 + cg * 2], w1 = W4[i * 32 + cg * 2 + 1];
    FMA4(x0, w0, a0, 0); FMA4(x0, w1, a0, 4);
    FMA4(x1, w0, a1, 0); FMA4(x1, w1, a1, 4);
  }
#pragma unroll
  for (int r = 0; r < 2; r++) {
    int row = base + r0 + r;
    if (row >= NN) continue;
    float* a = r ? a1 : a0;
    float h[8];
#pragma unroll
    for (int c = 0; c < 8; c++) h[c] = fmaxf(a[c] + sb[cg * 8 + c], 0.f);
    uint4 u;
    u.x = pack_bf2(h[0], h[1]);
    u.y = pack_bf2(h[2], h[3]);
    u.z = pack_bf2(h[4], h[5]);
    u.w = pack_bf2(h[6], h[7]);
    ((uint4*)(h1b + (size_t)row * 64))[cg] = u;
  }
}

// ---------------- MLP stage 2: out = relu(h1@W2+b2) (2r x 8c / thread) ----------------
__launch_bounds__(256)
__global__ void k_mlp2(const unsigned* __restrict__ h1b, const float* __restrict__ W2,
                       const float* __restrict__ b2, float* __restrict__ out) {
  __shared__ unsigned sH[64 * 65];  // bf16 pairs
  __shared__ float sW[128 * 64];
  __shared__ float sb[64];
  int t = threadIdx.x;
  int base = blockIdx.x * 64;
  for (int i = t; i < 8192; i += 256) sW[i] = W2[i];
  if (t < 64) sb[t] = b2[t];
  for (int idx = t; idx < 64 * 16; idx += 256) {
    int rl = idx >> 4, c4 = idx & 15;
    int row = base + rl;
    uint4 v = (row < NN) ? ((const uint4*)h1b)[(size_t)row * 16 + c4]
                         : make_uint4(0u, 0u, 0u, 0u);
    sH[rl * 65 + 4 * c4 + 0] = v.x;
    sH[rl * 65 + 4 * c4 + 1] = v.y;
    sH[rl * 65 + 4 * c4 + 2] = v.z;
    sH[rl * 65 + 4 * c4 + 3] = v.w;
  }
  __syncthreads();
  int cg = t & 7, rg = t >> 3;  // rows 2rg, 2rg+1; cols 8cg..8cg+7
  int r0 = rg * 2;
  float a0[8], a1[8];
#pragma unroll
  for (int i = 0; i < 8; i++) { a0[i] = 0.f; a1[i] = 0.f; }
  const float4* W4 = (const float4*)sW;
#pragma unroll 2
  for (int kp = 0; kp < 64; kp++) {
    unsigned u0 = sH[r0 * 65 + kp];
    unsigned u1 = sH[(r0 + 1) * 65 + kp];
    float x0a = __uint_as_float(u0 << 16), x0b = __uint_as_float(u0 & 0xffff0000u);
    float x1a = __uint_as_float(u1 << 16), x1b = __uint_as_float(u1 & 0xffff0000u);
    int k0 = 2 * kp, k1 = 2 * kp + 1;
    float4 wa0 = W4[k0 * 16 + cg * 2], wa1 = W4[k0 * 16 + cg * 2 + 1];
    float4 wb0 = W4[k1 * 16 + cg * 2], wb1 = W4[k1 * 16 + cg * 2 + 1];
    FMA4(x0a, wa0, a0, 0); FMA4(x0a, wa1, a0, 4);
    FMA4(x0b, wb0, a0, 0); FMA4(x0b, wb1, a0, 4);
    FMA4(x1a, wa0, a1, 0); FMA4(x1a, wa1, a1, 4);
    FMA4(x1b, wb0, a1, 0); FMA4(x1b, wb1, a1, 4);
  }
#pragma unroll
  for (int r = 0; r < 2; r++) {
    int row = base + r0 + r;
    if (row >= NN) continue;
    float* a = r ? a1 : a0;
    float4* op = (float4*)(out + (size_t)row * 64 + cg * 8);
    op[0] = make_float4(fmaxf(a[0] + sb[cg * 8 + 0], 0.f), fmaxf(a[1] + sb[cg * 8 + 1], 0.f),
                        fmaxf(a[2] + sb[cg * 8 + 2], 0.f), fmaxf(a[3] + sb[cg * 8 + 3], 0.f));
    op[1] = make_float4(fmaxf(a[4] + sb[cg * 8 + 4], 0.f), fmaxf(a[5] + sb[cg * 8 + 5], 0.f),
                        fmaxf(a[6] + sb[cg * 8 + 6], 0.f), fmaxf(a[7] + sb[cg * 8 + 7], 0.f));
  }
}

// ---------------- host ----------------
extern "C" void kernel_launch(void* const* d_in, const int* in_sizes, int n_in,
                              void* d_out, int out_size, void* d_ws, size_t ws_size,
                              hipStream_t stream) {
  (void)in_sizes; (void)n_in; (void)out_size; (void)ws_size;
  const float* x        = (const float*)d_in[0];
  const int*   ei       = (const int*)d_in[1];
  const float* gcnK_W   = (const float*)d_in[2];
  const float* gcnK_b   = (const float*)d_in[3];
  const float* gcnV_W   = (const float*)d_in[4];
  const float* gcnV_b   = (const float*)d_in[5];
  const float* super_Q  = (const float*)d_in[6];
  const float* mha_in_w = (const float*)d_in[7];
  const float* mha_in_b = (const float*)d_in[8];
  const float* mha_out_w= (const float*)d_in[9];
  const float* mha_out_b= (const float*)d_in[10];
  const float* gat_W    = (const float*)d_in[11];
  const float* gat_Wc   = (const float*)d_in[12];
  const float* gat_a_src= (const float*)d_in[13];
  const float* gat_a_dst= (const float*)d_in[14];
  const float* gat_b    = (const float*)d_in[15];
  const float* t1_W     = (const float*)d_in[16];
  const float* t1_b     = (const float*)d_in[17];
  const float* t2_W     = (const float*)d_in[18];
  const float* t2_b     = (const float*)d_in[19];

  char* ws = (char*)d_ws;
  size_t cur = 0;
  auto alloc = [&](size_t bytes) -> char* {
    char* p = ws + cur;
    cur = (cur + bytes + 255) & ~(size_t)255;
    return p;
  };
  // zero-initialized region (single memset): partition histogram only
  int*      pcnt   = (int*)alloc((size_t)NP * 16 * 4);   // padded: 1 counter / 64B line
  size_t zero_bytes = cur;
  int*      ppos    = (int*)alloc((size_t)NP * 16 * 4);
  int*      bstart  = (int*)alloc((size_t)(NB + 1) * 4);
  int*      offsets = (int*)alloc((size_t)(NN + 1) * 4);
  float*    dinv    = (float*)alloc((size_t)NN * 4);
  int*      csr     = (int*)alloc((size_t)EE * 4);
  unsigned* brec    = (unsigned*)alloc((size_t)EE * 4);
  float*    Wfk     = (float*)alloc(4096 * 4);
  float*    Wfv     = (float*)alloc(4096 * 4);
  float*    Wfg     = (float*)alloc(4096 * 4);
  float*    bfuse   = (float*)alloc(192 * 4);
  float*    qh      = (float*)alloc(640 * 4);
  float*    aeff    = (float*)alloc(64 * 4);
  float*    macc    = (float*)alloc(720 * 4);
  float*    part    = (float*)alloc((size_t)8 * BPH * 90 * 4);  // MHA partials
  float*    s_src   = (float*)alloc((size_t)NN * 4);
  float*    s_dstv  = (float*)alloc((size_t)NN * 4);
  unsigned* xbf     = (unsigned*)alloc((size_t)NN * 128);   // bf16 x*dinv
  float*    ax      = (float*)alloc((size_t)NN * 64 * 4);
  float*    Kh      = (float*)alloc((size_t)NN * 64 * 4);
  float*    Vh      = (float*)alloc((size_t)NN * 64 * 4);
  unsigned* hGb     = (unsigned*)alloc((size_t)NN * 128);   // bf16 GAT features
  unsigned* h1b     = (unsigned*)alloc((size_t)NN * 64 * 4); // bf16 MLP hidden (128/row)
  float*    g       = (float*)d_out;

  (void)hipMemsetAsync(d_ws, 0, zero_bytes, stream);
  k_hist<<<(EE + 255) / 256, 256, 0, stream>>>(ei, pcnt);
  k_scanp<<<1, 1024, 0, stream>>>(pcnt, ppos, bstart, offsets);
  k_fill_b<<<(EE + 255) / 256, 256, 0, stream>>>(ei, ppos, brec);
  k_fill_c<<<NB, 256, 0, stream>>>(brec, bstart, csr, offsets, dinv);
  k_prep<<<(NN * 32 + 255) / 256, 256, 0, stream>>>(x, dinv, xbf);
  k_agg_x<<<NN / 4, 256, 0, stream>>>(xbf, offsets, csr, dinv, ax);
  k_fusew<<<49, 256, 0, stream>>>(gcnK_W, gcnK_b, gcnV_W, gcnV_b, mha_in_w, mha_in_b,
                                  gat_W, Wfk, Wfv, Wfg, bfuse);
  k_qh<<<3, 256, 0, stream>>>(super_Q, mha_in_w, mha_in_b, qh);
  k_proj<<<(NN + 63) / 64, 256, 0, stream>>>(ax, Wfk, Wfv, Wfg, bfuse, gat_a_dst,
                                             Kh, Vh, hGb, s_dstv);
  k_mha<<<8 * BPH, 256, 0, stream>>>(Kh, Vh, qh, part);
  k_mred<<<3, 256, 0, stream>>>(part, macc);
  k_context<<<1, 640, 0, stream>>>(macc, mha_out_w, mha_out_b, gat_a_src, gat_Wc, aeff);
  k_ssrc<<<NN / 4, 256, 0, stream>>>(hGb, aeff, s_src);
  k_gat<<<NN / 4, 256, 0, stream>>>(offsets, csr, s_src, s_dstv, hGb, gat_b, g);
  k_mlp1<<<(NN + 31) / 32, 256, 0, stream>>>(g, t1_W, t1_b, h1b);
  k_mlp2<<<(NN + 63) / 64, 256, 0, stream>>>(h1b, t2_W, t2_b, g);
}

// Round 10
// 516.075 us; speedup vs baseline: 2.1274x; 1.1267x over previous
//
#include <hip/hip_runtime.h>
#include <hip/hip_bf16.h>
#include <stdint.h>

#define NN 100000
#define EE 1600000
#define NBK 391        // fill blocks, 4096 edges each
#define CHUNK 4096
#define NCB 98         // coarse buckets of 1024 nodes (98*1024 >= NN)
#define BPH 128        // MHA blocks per head

// fma of scalar xi with float4 vv into acc[base..base+3]
// (param name must NOT be 'x'/'y'/'z'/'w' — member tokens get macro-substituted!)
#define FMA4(xi, vv, a, base)                      \
  a[(base)+0] = fmaf((xi), (vv).x, a[(base)+0]);   \
  a[(base)+1] = fmaf((xi), (vv).y, a[(base)+1]);   \
  a[(base)+2] = fmaf((xi), (vv).z, a[(base)+2]);   \
  a[(base)+3] = fmaf((xi), (vv).w, a[(base)+3]);

__device__ inline unsigned pack_bf2(float a, float b) {
  __hip_bfloat162 t;
  t.x = __float2bfloat16(a);
  t.y = __float2bfloat16(b);
  return *reinterpret_cast<unsigned*>(&t);
}

// ---------------- per-block LDS histogram over 98 coarse buckets ----------------
// Replaces 1.6M global atomics (round-9: fill_b 57MB write churn = fine-grained
// cross-XCD cursor claiming). Coalesced 98-int row per block.
__launch_bounds__(256)
__global__ void k_hist(const int* __restrict__ ei, int* __restrict__ histmat) {
  __shared__ int hist[NCB];
  int t = threadIdx.x;
  if (t < NCB) hist[t] = 0;
  __syncthreads();
  int base = blockIdx.x * CHUNK;
  int nb = EE - base; if (nb > CHUNK) nb = CHUNK;
  for (int k = t; k < nb; k += 256)
    atomicAdd(&hist[ei[EE + base + k] >> 10], 1);
  __syncthreads();
  if (t < NCB) histmat[blockIdx.x * NCB + t] = hist[t];
}

// ---------------- exact per-(block,bucket) bases via bucket-major scan ----------------
__launch_bounds__(1024)
__global__ void k_scanp(const int* __restrict__ histmat, int* __restrict__ ppos,
                        int* __restrict__ bstart, int* __restrict__ offsets) {
  __shared__ int part[1024];
  const int HM = NCB * NBK;
  int t = threadIdx.x;
  int i0 = t * 38, i1 = i0 + 38; if (i1 > HM) i1 = HM; if (i0 > HM) i0 = HM;
  int sum = 0;
  for (int i = i0; i < i1; i++) {
    int cb = i / NBK, blk = i - cb * NBK;
    sum += histmat[blk * NCB + cb];
  }
  part[t] = sum;
  __syncthreads();
  for (int off = 1; off < 1024; off <<= 1) {
    int v = (t >= off) ? part[t - off] : 0;
    __syncthreads();
    part[t] += v;
    __syncthreads();
  }
  int run = part[t] - sum;  // exclusive prefix
  for (int i = i0; i < i1; i++) {
    int cb = i / NBK, blk = i - cb * NBK;
    if (blk == 0) bstart[cb] = run;
    ppos[blk * NCB + cb] = run;
    run += histmat[blk * NCB + cb];
  }
  if (t == 0) { bstart[NCB] = EE; offsets[NN] = EE; }
}

// ---------------- fill pass B: LDS radix-partition + contiguous run copy ----------------
// Each (block,bucket) run (avg 42 records = 168B) is written contiguously by ONE
// block -> frontier lines assemble in one L2, no cross-XCD churn, no atomics.
__launch_bounds__(256)
__global__ void k_fill_b(const int* __restrict__ ei, const int* __restrict__ ppos,
                         unsigned* __restrict__ brec) {
  __shared__ int hist[NCB], binstart[NCB], bincur[NCB], pbase[NCB];
  __shared__ unsigned lbuf[CHUNK];
  __shared__ unsigned char cbArr[CHUNK];
  int t = threadIdx.x;
  int base = blockIdx.x * CHUNK;
  int nb = EE - base; if (nb > CHUNK) nb = CHUNK;
  if (t < NCB) { hist[t] = 0; pbase[t] = ppos[blockIdx.x * NCB + t]; }
  __syncthreads();
  unsigned rec[16]; int rcb[16]; int cnt = 0;
  for (int k = t; k < nb; k += 256) {
    int s = ei[base + k], d = ei[EE + base + k];
    rec[cnt] = (unsigned)s | ((unsigned)(d & 1023) << 17);  // s < 2^17, dlocal 10b
    rcb[cnt] = d >> 10;
    atomicAdd(&hist[rcb[cnt]], 1);
    cnt++;
  }
  __syncthreads();
  if (t < NCB) binstart[t] = hist[t];
  __syncthreads();
  for (int off = 1; off < NCB; off <<= 1) {
    int v = (t < NCB && t >= off) ? binstart[t - off] : 0;
    __syncthreads();
    if (t < NCB) binstart[t] += v;
    __syncthreads();
  }
  if (t < NCB) { binstart[t] -= hist[t]; bincur[t] = 0; }
  __syncthreads();
  for (int i = 0; i < cnt; i++) {
    int c = rcb[i];
    int pos = atomicAdd(&bincur[c], 1);
    int p = binstart[c] + pos;
    lbuf[p] = rec[i];
    cbArr[p] = (unsigned char)c;
  }
  __syncthreads();
  for (int i = t; i < nb; i += 256) {
    int c = cbArr[i];
    brec[pbase[c] + (i - binstart[c])] = lbuf[i];
  }
}

// ---------------- fill pass C: bucket-local histogram + scan + place ----------------
__launch_bounds__(1024)
__global__ void k_fill_c(const unsigned* __restrict__ brec, const int* __restrict__ bstart,
                         int* __restrict__ csr, int* __restrict__ offsets,
                         float* __restrict__ dinv) {
  __shared__ int cnt[1024], sm[1024];
  int cbk = blockIdx.x, t = threadIdx.x;
  int nb0 = cbk << 10;
  int nn = NN - nb0; if (nn > 1024) nn = 1024;
  cnt[t] = 0;
  __syncthreads();
  int e0 = bstart[cbk], e1 = bstart[cbk + 1];
  for (int j = e0 + t; j < e1; j += 1024)
    atomicAdd(&cnt[brec[j] >> 17], 1);
  __syncthreads();
  int cv = cnt[t];
  sm[t] = cv;
  __syncthreads();
  for (int off = 1; off < 1024; off <<= 1) {
    int v = (t >= off) ? sm[t - off] : 0;
    __syncthreads();
    sm[t] += v;
    __syncthreads();
  }
  sm[t] -= cv;  // exclusive
  if (t < nn) {
    offsets[nb0 + t] = e0 + sm[t];
    dinv[nb0 + t] = rsqrtf((float)(cv + 1));  // deg includes self loop
  }
  cnt[t] = 0;  // reuse as placement cursor
  __syncthreads();
  for (int j = e0 + t; j < e1; j += 1024) {
    unsigned r = brec[j];
    int dl = r >> 17;
    int p = atomicAdd(&cnt[dl], 1);
    csr[e0 + sm[dl] + p] = r & 0x1FFFF;  // confined to this bucket's window
  }
}

// ---------------- x~ = bf16(x * dinv[row]) ----------------
__global__ void k_prep(const float* __restrict__ x, const float* __restrict__ dinv,
                       unsigned* __restrict__ xbf2) {
  int i = blockIdx.x * 256 + threadIdx.x;  // pair index
  if (i >= NN * 32) return;
  float dv = dinv[i >> 5];
  float2 v = ((const float2*)x)[i];
  xbf2[i] = pack_bf2(v.x * dv, v.y * dv);
}

// ---------------- ax = A_norm @ x (8-lane-group gather) ----------------
__launch_bounds__(256)
__global__ void k_agg_x(const unsigned* __restrict__ xbf2, const int* __restrict__ offsets,
                        const int* __restrict__ csr, const float* __restrict__ dinv,
                        float* __restrict__ ax) {
  int gid = blockIdx.x * 256 + threadIdx.x;
  int n = gid >> 6;
  if (n >= NN) return;
  int lane = gid & 63, q = lane & 7, grp = lane >> 3;
  int e0 = offsets[n], e1 = offsets[n + 1];
  float dv = dinv[n];
  float a[8];
#pragma unroll
  for (int i = 0; i < 8; i++) a[i] = 0.f;
  if (grp == 0) {  // self loop, counted once
    uint4 u = ((const uint4*)(xbf2 + (size_t)n * 32))[q];
    unsigned uu[4] = {u.x, u.y, u.z, u.w};
#pragma unroll
    for (int p = 0; p < 4; p++) {
      __hip_bfloat162 v = *reinterpret_cast<__hip_bfloat162*>(&uu[p]);
      a[2 * p] += __bfloat162float(v.x);
      a[2 * p + 1] += __bfloat162float(v.y);
    }
  }
  for (int base = e0; base < e1; base += 8) {
    int j = base + grp;
    if (j < e1) {
      int s = csr[j];
      uint4 u = ((const uint4*)(xbf2 + (size_t)s * 32))[q];
      unsigned uu[4] = {u.x, u.y, u.z, u.w};
#pragma unroll
      for (int p = 0; p < 4; p++) {
        __hip_bfloat162 v = *reinterpret_cast<__hip_bfloat162*>(&uu[p]);
        a[2 * p] += __bfloat162float(v.x);
        a[2 * p + 1] += __bfloat162float(v.y);
      }
    }
  }
#pragma unroll
  for (int i = 0; i < 8; i++) {
    a[i] += __shfl_xor(a[i], 8);
    a[i] += __shfl_xor(a[i], 16);
    a[i] += __shfl_xor(a[i], 32);
  }
  if (lane < 8) {
    float4* op = (float4*)(ax + (size_t)n * 64 + q * 8);
    op[0] = make_float4(a[0] * dv, a[1] * dv, a[2] * dv, a[3] * dv);
    op[1] = make_float4(a[4] * dv, a[5] * dv, a[6] * dv, a[7] * dv);
  }
}

// ---------------- fused weights: Wfk = WK@Wk^T, Wfv = WV@Wv^T, Wfg = WV@gatW ----------------
__global__ void k_fusew(const float* __restrict__ gcnK_W, const float* __restrict__ gcnK_b,
                        const float* __restrict__ gcnV_W, const float* __restrict__ gcnV_b,
                        const float* __restrict__ mha_in_w, const float* __restrict__ mha_in_b,
                        const float* __restrict__ gat_W,
                        float* __restrict__ Wfk, float* __restrict__ Wfv,
                        float* __restrict__ Wfg, float* __restrict__ bf) {
  int blk = blockIdx.x;
  if (blk < 48) {
    int m = blk >> 4;
    int e = (blk & 15) * 256 + threadIdx.x;  // 0..4095
    int i = e >> 6, c = e & 63;
    float s = 0.f;
    if (m == 0) {
      for (int j = 0; j < 64; j++) s = fmaf(gcnK_W[i * 64 + j], mha_in_w[(64 + c) * 64 + j], s);
      Wfk[e] = s;
    } else if (m == 1) {
      for (int j = 0; j < 64; j++) s = fmaf(gcnV_W[i * 64 + j], mha_in_w[(128 + c) * 64 + j], s);
      Wfv[e] = s;
    } else {
      for (int j = 0; j < 64; j++) s = fmaf(gcnV_W[i * 64 + j], gat_W[j * 64 + c], s);
      Wfg[e] = s;
    }
  } else {
    int t = threadIdx.x;
    if (t < 64) {
      float s = mha_in_b[64 + t];
      for (int j = 0; j < 64; j++) s = fmaf(gcnK_b[j], mha_in_w[(64 + t) * 64 + j], s);
      bf[t] = s;
    } else if (t < 128) {
      int c = t - 64;
      float s = mha_in_b[128 + c];
      for (int j = 0; j < 64; j++) s = fmaf(gcnV_b[j], mha_in_w[(128 + c) * 64 + j], s);
      bf[64 + c] = s;
    } else if (t < 192) {
      int c = t - 128;
      float s = 0.f;
      for (int j = 0; j < 64; j++) s = fmaf(gcnV_b[j], gat_W[j * 64 + c], s);
      bf[128 + c] = s;
    }
  }
}

// ---------------- qh = (super_Q @ Wq^T + bq) * scale ----------------
__global__ void k_qh(const float* __restrict__ sQ, const float* __restrict__ in_w,
                     const float* __restrict__ in_b, float* __restrict__ qh) {
  int t = blockIdx.x * 256 + threadIdx.x;
  if (t >= 640) return;
  int l = t >> 6, c = t & 63;
  float acc = 0.f;
  for (int i = 0; i < 64; i++) acc = fmaf(sQ[l * 64 + i], in_w[c * 64 + i], acc);
  qh[t] = (acc + in_b[c]) * 0.35355339059327373f;  // 1/sqrt(8)
}

// ---------------- k_proj: ax -> Kh, Vh, hGb, s_dst (register-blocked 2rx8c) ----------------
__launch_bounds__(256)
__global__ void k_proj(const float* __restrict__ ax, const float* __restrict__ Wfk,
                       const float* __restrict__ Wfv, const float* __restrict__ Wfg,
                       const float* __restrict__ bf, const float* __restrict__ a_dst,
                       float* __restrict__ Kh, float* __restrict__ Vh,
                       unsigned* __restrict__ hGb, float* __restrict__ s_dstv) {
  __shared__ float sX[64 * 65];  // +1 pad: staging writes <=2-way conflict (free)
  __shared__ float sWk[4096], sWv[4096], sWg[4096];
  __shared__ float sB[192], sAd[64];
  int t = threadIdx.x;
  int base = blockIdx.x * 64;
  for (int i = t; i < 4096; i += 256) { sWk[i] = Wfk[i]; sWv[i] = Wfv[i]; sWg[i] = Wfg[i]; }
  if (t < 192) sB[t] = bf[t];
  if (t < 64) sAd[t] = a_dst[t];
  for (int idx = t; idx < 64 * 16; idx += 256) {
    int rl = idx >> 4, k4 = idx & 15;
    int row = base + rl;
    float4 v = (row < NN) ? ((const float4*)ax)[(size_t)row * 16 + k4]
                          : make_float4(0.f, 0.f, 0.f, 0.f);
    sX[rl * 65 + 4 * k4 + 0] = v.x;
    sX[rl * 65 + 4 * k4 + 1] = v.y;
    sX[rl * 65 + 4 * k4 + 2] = v.z;
    sX[rl * 65 + 4 * k4 + 3] = v.w;
  }
  __syncthreads();
  int cg = t & 7, rg = t >> 3;  // rows 2rg, 2rg+1; cols 8cg..8cg+7 (= head cg)
  int r0 = rg * 2;
  float aK[16], aV[16], aG[16];
#pragma unroll
  for (int i = 0; i < 16; i++) { aK[i] = 0.f; aV[i] = 0.f; aG[i] = 0.f; }
  const float4* Wk4 = (const float4*)sWk;
  const float4* Wv4 = (const float4*)sWv;
  const float4* Wg4 = (const float4*)sWg;
#pragma unroll 2
  for (int i = 0; i < 64; i++) {
    float x0 = sX[r0 * 65 + i];
    float x1 = sX[(r0 + 1) * 65 + i];
    float4 wk0 = Wk4[i * 16 + cg * 2], wk1 = Wk4[i * 16 + cg * 2 + 1];
    float4 wv0 = Wv4[i * 16 + cg * 2], wv1 = Wv4[i * 16 + cg * 2 + 1];
    float4 wg0 = Wg4[i * 16 + cg * 2], wg1 = Wg4[i * 16 + cg * 2 + 1];
    FMA4(x0, wk0, aK, 0); FMA4(x0, wk1, aK, 4);
    FMA4(x1, wk0, aK, 8); FMA4(x1, wk1, aK, 12);
    FMA4(x0, wv0, aV, 0); FMA4(x0, wv1, aV, 4);
    FMA4(x1, wv0, aV, 8); FMA4(x1, wv1, aV, 12);
    FMA4(x0, wg0, aG, 0); FMA4(x0, wg1, aG, 4);
    FMA4(x1, wg0, aG, 8); FMA4(x1, wg1, aG, 12);
  }
#pragma unroll
  for (int r = 0; r < 2; r++) {
    int row = base + r0 + r;
    bool ok = row < NN;
    int o = r * 8;
    float hg[8];
    float sd = 0.f;
#pragma unroll
    for (int c = 0; c < 8; c++) {
      hg[c] = aG[o + c] + sB[128 + cg * 8 + c];
      sd = fmaf(hg[c], sAd[cg * 8 + c], sd);
    }
    sd += __shfl_xor(sd, 1);
    sd += __shfl_xor(sd, 2);
    sd += __shfl_xor(sd, 4);
    if (ok) {
      float4* kp = (float4*)(Kh + (size_t)cg * NN * 8 + (size_t)row * 8);
      kp[0] = make_float4(aK[o + 0] + sB[cg * 8 + 0], aK[o + 1] + sB[cg * 8 + 1],
                          aK[o + 2] + sB[cg * 8 + 2], aK[o + 3] + sB[cg * 8 + 3]);
      kp[1] = make_float4(aK[o + 4] + sB[cg * 8 + 4], aK[o + 5] + sB[cg * 8 + 5],
                          aK[o + 6] + sB[cg * 8 + 6], aK[o + 7] + sB[cg * 8 + 7]);
      float4* vp = (float4*)(Vh + (size_t)cg * NN * 8 + (size_t)row * 8);
      vp[0] = make_float4(aV[o + 0] + sB[64 + cg * 8 + 0], aV[o + 1] + sB[64 + cg * 8 + 1],
                          aV[o + 2] + sB[64 + cg * 8 + 2], aV[o + 3] + sB[64 + cg * 8 + 3]);
      vp[1] = make_float4(aV[o + 4] + sB[64 + cg * 8 + 4], aV[o + 5] + sB[64 + cg * 8 + 5],
                          aV[o + 6] + sB[64 + cg * 8 + 6], aV[o + 7] + sB[64 + cg * 8 + 7]);
      uint4 u;
      u.x = pack_bf2(hg[0], hg[1]);
      u.y = pack_bf2(hg[2], hg[3]);
      u.z = pack_bf2(hg[4], hg[5]);
      u.w = pack_bf2(hg[6], hg[7]);
      ((uint4*)(hGb + (size_t)row * 32))[cg] = u;
      if (cg == 0) s_dstv[row] = sd;
    }
  }
}

// ---------------- MHA main: atomic-free per-block partials ----------------
__launch_bounds__(256)
__global__ void k_mha(const float* __restrict__ Kh, const float* __restrict__ Vh,
                      const float* __restrict__ qh, float* __restrict__ part) {
  int h = blockIdx.x / BPH, b = blockIdx.x % BPH;
  __shared__ float sq[80];
  __shared__ float red[4][90];
  if (threadIdx.x < 80) {
    int l = threadIdx.x >> 3, j = threadIdx.x & 7;
    sq[threadIdx.x] = qh[l * 64 + h * 8 + j];
  }
  __syncthreads();
  const float4* Kp = (const float4*)(Kh + (size_t)h * NN * 8);
  const float4* Vp = (const float4*)(Vh + (size_t)h * NN * 8);
  const float4* sq4 = (const float4*)sq;
  float s[10], o[80];
#pragma unroll
  for (int l = 0; l < 10; l++) s[l] = 0.f;
#pragma unroll
  for (int t = 0; t < 80; t++) o[t] = 0.f;
  for (int n = b * 256 + threadIdx.x; n < NN; n += BPH * 256) {
    float4 k0 = Kp[n * 2], k1 = Kp[n * 2 + 1];
    float4 v0 = Vp[n * 2], v1 = Vp[n * 2 + 1];
#pragma unroll
    for (int l = 0; l < 10; l++) {
      float4 q0 = sq4[l * 2], q1 = sq4[l * 2 + 1];
      float z = q0.x * k0.x + q0.y * k0.y + q0.z * k0.z + q0.w * k0.w +
                q1.x * k1.x + q1.y * k1.y + q1.z * k1.z + q1.w * k1.w;
      float w = __expf(z);
      s[l] += w;
      o[l * 8 + 0] = fmaf(w, v0.x, o[l * 8 + 0]);
      o[l * 8 + 1] = fmaf(w, v0.y, o[l * 8 + 1]);
      o[l * 8 + 2] = fmaf(w, v0.z, o[l * 8 + 2]);
      o[l * 8 + 3] = fmaf(w, v0.w, o[l * 8 + 3]);
      o[l * 8 + 4] = fmaf(w, v1.x, o[l * 8 + 4]);
      o[l * 8 + 5] = fmaf(w, v1.y, o[l * 8 + 5]);
      o[l * 8 + 6] = fmaf(w, v1.z, o[l * 8 + 6]);
      o[l * 8 + 7] = fmaf(w, v1.w, o[l * 8 + 7]);
    }
  }
  int lane = threadIdx.x & 63, wave = threadIdx.x >> 6;
#pragma unroll
  for (int l = 0; l < 10; l++) {
    float v = s[l];
#pragma unroll
    for (int off = 32; off > 0; off >>= 1) v += __shfl_down(v, off);
    if (lane == 0) red[wave][l] = v;
  }
#pragma unroll
  for (int t = 0; t < 80; t++) {
    float v = o[t];
#pragma unroll
    for (int off = 32; off > 0; off >>= 1) v += __shfl_down(v, off);
    if (lane == 0) red[wave][10 + t] = v;
  }
  __syncthreads();
  if (threadIdx.x < 90) {
    float v = red[0][threadIdx.x] + red[1][threadIdx.x] +
              red[2][threadIdx.x] + red[3][threadIdx.x];
    part[(size_t)blockIdx.x * 90 + threadIdx.x] = v;
  }
}

// ---------------- reduce partials -> acc ----------------
__global__ void k_mred(const float* __restrict__ part, float* __restrict__ acc) {
  int t = blockIdx.x * 256 + threadIdx.x;
  if (t >= 720) return;
  int h = t / 90, j = t % 90;
  float v = 0.f;
  for (int b = 0; b < BPH; b++) v += part[(size_t)(h * BPH + b) * 90 + j];
  if (j < 10) acc[h * 10 + j] = v;
  else acc[80 + h * 80 + (j - 10)] = v;
}

// ---------------- softmax finalize -> cluster -> context -> a_eff ----------------
__global__ void k_context(const float* __restrict__ acc, const float* __restrict__ out_w,
                          const float* __restrict__ out_b, const float* __restrict__ a_src,
                          const float* __restrict__ gat_Wc, float* __restrict__ aeff) {
  __shared__ float po[640], cl[640], ctx[64];
  int t = threadIdx.x;  // blockDim = 640
  {
    int h = t / 80, r = t % 80, l = r >> 3, j = r & 7;
    po[l * 64 + h * 8 + j] = acc[80 + t] / acc[h * 10 + l];
  }
  __syncthreads();
  {
    int l = t >> 6, d = t & 63;
    float v = out_b[d];
    for (int c = 0; c < 64; c++) v = fmaf(po[l * 64 + c], out_w[d * 64 + c], v);
    cl[t] = v;
  }
  __syncthreads();
  if (t < 64) {
    float m = 0.f;
#pragma unroll
    for (int l = 0; l < 10; l++) m += cl[l * 64 + t];
    ctx[t] = m * 0.1f;
  }
  __syncthreads();
  if (t < 64) {
    float v = a_src[t];
    for (int i = 0; i < 64; i++) v = fmaf(ctx[i], gat_Wc[i * 64 + t], v);
    aeff[t] = v;
  }
}

// ---------------- s_src[n] = dot(hG[n], a_eff) ----------------
__launch_bounds__(256)
__global__ void k_ssrc(const unsigned* __restrict__ hGb, const float* __restrict__ aeff,
                       float* __restrict__ s_src) {
  int gid = blockIdx.x * 256 + threadIdx.x;
  int n = gid >> 6, lane = gid & 63;
  if (n >= NN) return;
  const __hip_bfloat16* hp = (const __hip_bfloat16*)hGb;
  float v = __bfloat162float(hp[(size_t)n * 64 + lane]) * aeff[lane];
#pragma unroll
  for (int off = 32; off > 0; off >>= 1) v += __shfl_xor(v, off);
  if (lane == 0) s_src[n] = v;
}

// ---------------- GAT: 8-lane-group gather ----------------
__launch_bounds__(256)
__global__ void k_gat(const int* __restrict__ offsets, const int* __restrict__ csr,
                      const float* __restrict__ s_src, const float* __restrict__ s_dstv,
                      const unsigned* __restrict__ hGb, const float* __restrict__ gat_b,
                      float* __restrict__ g) {
  int gid = blockIdx.x * 256 + threadIdx.x;
  int n = gid >> 6;
  if (n >= NN) return;
  int lane = gid & 63, q = lane & 7, grp = lane >> 3;
  int e0 = offsets[n], e1 = offsets[n + 1];
  float sd = s_dstv[n];
  float den = 0.f;
  float a[8];
#pragma unroll
  for (int i = 0; i < 8; i++) a[i] = 0.f;
  for (int base = e0; base < e1; base += 8) {
    int j = base + grp;
    if (j < e1) {
      int s = csr[j];
      float z = s_src[s] + sd;
      z = z > 0.f ? z : 0.2f * z;
      float ex = __expf(z);  // logits O(1): softmax shift-invariant, skip segment-max
      den += ex;
      uint4 u = ((const uint4*)(hGb + (size_t)s * 32))[q];
      unsigned uu[4] = {u.x, u.y, u.z, u.w};
#pragma unroll
      for (int p = 0; p < 4; p++) {
        __hip_bfloat162 v = *reinterpret_cast<__hip_bfloat162*>(&uu[p]);
        a[2 * p] = fmaf(ex, __bfloat162float(v.x), a[2 * p]);
        a[2 * p + 1] = fmaf(ex, __bfloat162float(v.y), a[2 * p + 1]);
      }
    }
  }
  den += __shfl_xor(den, 8);
  den += __shfl_xor(den, 16);
  den += __shfl_xor(den, 32);
#pragma unroll
  for (int i = 0; i < 8; i++) {
    a[i] += __shfl_xor(a[i], 8);
    a[i] += __shfl_xor(a[i], 16);
    a[i] += __shfl_xor(a[i], 32);
  }
  float inv = 1.f / (den + 1e-16f);
  if (lane < 8) {
    float4* op = (float4*)(g + (size_t)n * 64 + q * 8);
    op[0] = make_float4(a[0] * inv + gat_b[q * 8 + 0], a[1] * inv + gat_b[q * 8 + 1],
                        a[2] * inv + gat_b[q * 8 + 2], a[3] * inv + gat_b[q * 8 + 3]);
    op[1] = make_float4(a[4] * inv + gat_b[q * 8 + 4], a[5] * inv + gat_b[q * 8 + 5],
                        a[6] * inv + gat_b[q * 8 + 6], a[7] * inv + gat_b[q * 8 + 7]);
  }
}

// ---------------- MLP stage 1: h1 = relu(g@W1+b1) -> bf16 (2r x 8c / thread) ----------------
__launch_bounds__(256)
__global__ void k_mlp1(const float* __restrict__ g, const float* __restrict__ W1,
                       const float* __restrict__ b1, unsigned* __restrict__ h1b) {
  __shared__ float sX[32 * 65];
  __shared__ float sW[64 * 128];
  __shared__ float sb[128];
  int t = threadIdx.x;
  int base = blockIdx.x * 32;
  for (int i = t; i < 8192; i += 256) sW[i] = W1[i];
  if (t < 128) sb[t] = b1[t];
  for (int idx = t; idx < 32 * 16; idx += 256) {
    int rl = idx >> 4, k4 = idx & 15;
    int row = base + rl;
    float4 v = (row < NN) ? ((const float4*)g)[(size_t)row * 16 + k4]
                          : make_float4(0.f, 0.f, 0.f, 0.f);
    sX[rl * 65 + 4 * k4 + 0] = v.x;
    sX[rl * 65 + 4 * k4 + 1] = v.y;
    sX[rl * 65 + 4 * k4 + 2] = v.z;
    sX[rl * 65 + 4 * k4 + 3] = v.w;
  }
  __syncthreads();
  int cg = t & 15, rg = t >> 4;  // rows 2rg, 2rg+1; cols 8cg..8cg+7
  int r0 = rg * 2;
  float a0[8], a1[8];
#pragma unroll
  for (int i = 0; i < 8; i++) { a0[i] = 0.f; a1[i] = 0.f; }
  const float4* W4 = (const float4*)sW;
#pragma unroll 4
  for (int i = 0; i < 64; i++) {
    float x0 = sX[r0 * 65 + i];
    float x1 = sX[(r0 + 1) * 65 + i];
    float4 w0 = W4[i * 32 + cg * 2], w1 = W4[i * 32 + cg * 2 + 1];
    FMA4(x0, w0, a0, 0); FMA4(x0, w1, a0, 4);
    FMA4(x1, w0, a1, 0); FMA4(x1, w1, a1, 4);
  }
#pragma unroll
  for (int r = 0; r < 2; r++) {
    int row = base + r0 + r;
    if (row >= NN) continue;
    float* a = r ? a1 : a0;
    float h[8];
#pragma unroll
    for (int c = 0; c < 8; c++) h[c] = fmaxf(a[c] + sb[cg * 8 + c], 0.f);
    uint4 u;
    u.x = pack_bf2(h[0], h[1]);
    u.y = pack_bf2(h[2], h[3]);
    u.z = pack_bf2(h[4], h[5]);
    u.w = pack_bf2(h[6], h[7]);
    ((uint4*)(h1b + (size_t)row * 64))[cg] = u;
  }
}

// ---------------- MLP stage 2: out = relu(h1@W2+b2) (2r x 8c / thread) ----------------
__launch_bounds__(256)
__global__ void k_mlp2(const unsigned* __restrict__ h1b, const float* __restrict__ W2,
                       const float* __restrict__ b2, float* __restrict__ out) {
  __shared__ unsigned sH[64 * 65];  // bf16 pairs
  __shared__ float sW[128 * 64];
  __shared__ float sb[64];
  int t = threadIdx.x;
  int base = blockIdx.x * 64;
  for (int i = t; i < 8192; i += 256) sW[i] = W2[i];
  if (t < 64) sb[t] = b2[t];
  for (int idx = t; idx < 64 * 16; idx += 256) {
    int rl = idx >> 4, c4 = idx & 15;
    int row = base + rl;
    uint4 v = (row < NN) ? ((const uint4*)h1b)[(size_t)row * 16 + c4]
                         : make_uint4(0u, 0u, 0u, 0u);
    sH[rl * 65 + 4 * c4 + 0] = v.x;
    sH[rl * 65 + 4 * c4 + 1] = v.y;
    sH[rl * 65 + 4 * c4 + 2] = v.z;
    sH[rl * 65 + 4 * c4 + 3] = v.w;
  }
  __syncthreads();
  int cg = t & 7, rg = t >> 3;  // rows 2rg, 2rg+1; cols 8cg..8cg+7
  int r0 = rg * 2;
  float a0[8], a1[8];
#pragma unroll
  for (int i = 0; i < 8; i++) { a0[i] = 0.f; a1[i] = 0.f; }
  const float4* W4 = (const float4*)sW;
#pragma unroll 2
  for (int kp = 0; kp < 64; kp++) {
    unsigned u0 = sH[r0 * 65 + kp];
    unsigned u1 = sH[(r0 + 1) * 65 + kp];
    float x0a = __uint_as_float(u0 << 16), x0b = __uint_as_float(u0 & 0xffff0000u);
    float x1a = __uint_as_float(u1 << 16), x1b = __uint_as_float(u1 & 0xffff0000u);
    int k0 = 2 * kp, k1 = 2 * kp + 1;
    float4 wa0 = W4[k0 * 16 + cg * 2], wa1 = W4[k0 * 16 + cg * 2 + 1];
    float4 wb0 = W4[k1 * 16 + cg * 2], wb1 = W4[k1 * 16 + cg * 2 + 1];
    FMA4(x0a, wa0, a0, 0); FMA4(x0a, wa1, a0, 4);
    FMA4(x0b, wb0, a0, 0); FMA4(x0b, wb1, a0, 4);
    FMA4(x1a, wa0, a1, 0); FMA4(x1a, wa1, a1, 4);
    FMA4(x1b, wb0, a1, 0); FMA4(x1b, wb1, a1, 4);
  }
#pragma unroll
  for (int r = 0; r < 2; r++) {
    int row = base + r0 + r;
    if (row >= NN) continue;
    float* a = r ? a1 : a0;
    float4* op = (float4*)(out + (size_t)row * 64 + cg * 8);
    op[0] = make_float4(fmaxf(a[0] + sb[cg * 8 + 0], 0.f), fmaxf(a[1] + sb[cg * 8 + 1], 0.f),
                        fmaxf(a[2] + sb[cg * 8 + 2], 0.f), fmaxf(a[3] + sb[cg * 8 + 3], 0.f));
    op[1] = make_float4(fmaxf(a[4] + sb[cg * 8 + 4], 0.f), fmaxf(a[5] + sb[cg * 8 + 5], 0.f),
                        fmaxf(a[6] + sb[cg * 8 + 6], 0.f), fmaxf(a[7] + sb[cg * 8 + 7], 0.f));
  }
}

// ---------------- host ----------------
extern "C" void kernel_launch(void* const* d_in, const int* in_sizes, int n_in,
                              void* d_out, int out_size, void* d_ws, size_t ws_size,
                              hipStream_t stream) {
  (void)in_sizes; (void)n_in; (void)out_size; (void)ws_size;
  const float* x        = (const float*)d_in[0];
  const int*   ei       = (const int*)d_in[1];
  const float* gcnK_W   = (const float*)d_in[2];
  const float* gcnK_b   = (const float*)d_in[3];
  const float* gcnV_W   = (const float*)d_in[4];
  const float* gcnV_b   = (const float*)d_in[5];
  const float* super_Q  = (const float*)d_in[6];
  const float* mha_in_w = (const float*)d_in[7];
  const float* mha_in_b = (const float*)d_in[8];
  const float* mha_out_w= (const float*)d_in[9];
  const float* mha_out_b= (const float*)d_in[10];
  const float* gat_W    = (const float*)d_in[11];
  const float* gat_Wc   = (const float*)d_in[12];
  const float* gat_a_src= (const float*)d_in[13];
  const float* gat_a_dst= (const float*)d_in[14];
  const float* gat_b    = (const float*)d_in[15];
  const float* t1_W     = (const float*)d_in[16];
  const float* t1_b     = (const float*)d_in[17];
  const float* t2_W     = (const float*)d_in[18];
  const float* t2_b     = (const float*)d_in[19];

  char* ws = (char*)d_ws;
  size_t cur = 0;
  auto alloc = [&](size_t bytes) -> char* {
    char* p = ws + cur;
    cur = (cur + bytes + 255) & ~(size_t)255;
    return p;
  };
  // no zero-init needed: every buffer is fully written before first read
  int*      histmat = (int*)alloc((size_t)NBK * NCB * 4);
  int*      ppos    = (int*)alloc((size_t)NBK * NCB * 4);
  int*      bstart  = (int*)alloc((size_t)(NCB + 1) * 4);
  int*      offsets = (int*)alloc((size_t)(NN + 1) * 4);
  float*    dinv    = (float*)alloc((size_t)NN * 4);
  int*      csr     = (int*)alloc((size_t)EE * 4);
  unsigned* brec    = (unsigned*)alloc((size_t)EE * 4);
  float*    Wfk     = (float*)alloc(4096 * 4);
  float*    Wfv     = (float*)alloc(4096 * 4);
  float*    Wfg     = (float*)alloc(4096 * 4);
  float*    bfuse   = (float*)alloc(192 * 4);
  float*    qh      = (float*)alloc(640 * 4);
  float*    aeff    = (float*)alloc(64 * 4);
  float*    macc    = (float*)alloc(720 * 4);
  float*    part    = (float*)alloc((size_t)8 * BPH * 90 * 4);  // MHA partials
  float*    s_src   = (float*)alloc((size_t)NN * 4);
  float*    s_dstv  = (float*)alloc((size_t)NN * 4);
  unsigned* xbf     = (unsigned*)alloc((size_t)NN * 128);   // bf16 x*dinv
  float*    ax      = (float*)alloc((size_t)NN * 64 * 4);
  float*    Kh      = (float*)alloc((size_t)NN * 64 * 4);
  float*    Vh      = (float*)alloc((size_t)NN * 64 * 4);
  unsigned* hGb     = (unsigned*)alloc((size_t)NN * 128);   // bf16 GAT features
  unsigned* h1b     = (unsigned*)alloc((size_t)NN * 64 * 4); // bf16 MLP hidden (128/row)
  float*    g       = (float*)d_out;

  k_hist<<<NBK, 256, 0, stream>>>(ei, histmat);
  k_scanp<<<1, 1024, 0, stream>>>(histmat, ppos, bstart, offsets);
  k_fill_b<<<NBK, 256, 0, stream>>>(ei, ppos, brec);
  k_fill_c<<<NCB, 1024, 0, stream>>>(brec, bstart, csr, offsets, dinv);
  k_prep<<<(NN * 32 + 255) / 256, 256, 0, stream>>>(x, dinv, xbf);
  k_agg_x<<<NN / 4, 256, 0, stream>>>(xbf, offsets, csr, dinv, ax);
  k_fusew<<<49, 256, 0, stream>>>(gcnK_W, gcnK_b, gcnV_W, gcnV_b, mha_in_w, mha_in_b,
                                  gat_W, Wfk, Wfv, Wfg, bfuse);
  k_qh<<<3, 256, 0, stream>>>(super_Q, mha_in_w, mha_in_b, qh);
  k_proj<<<(NN + 63) / 64, 256, 0, stream>>>(ax, Wfk, Wfv, Wfg, bfuse, gat_a_dst,
                                             Kh, Vh, hGb, s_dstv);
  k_mha<<<8 * BPH, 256, 0, stream>>>(Kh, Vh, qh, part);
  k_mred<<<3, 256, 0, stream>>>(part, macc);
  k_context<<<1, 640, 0, stream>>>(macc, mha_out_w, mha_out_b, gat_a_src, gat_Wc, aeff);
  k_ssrc<<<NN / 4, 256, 0, stream>>>(hGb, aeff, s_src);
  k_gat<<<NN / 4, 256, 0, stream>>>(offsets, csr, s_src, s_dstv, hGb, gat_b, g);
  k_mlp1<<<(NN + 31) / 32, 256, 0, stream>>>(g, t1_W, t1_b, h1b);
  k_mlp2<<<(NN + 63) / 64, 256, 0, stream>>>(h1b, t2_W, t2_b, g);
}

// Round 11
// 462.783 us; speedup vs baseline: 2.3724x; 1.1152x over previous
//
#include <hip/hip_runtime.h>
#include <hip/hip_bf16.h>
#include <stdint.h>

#define NN 100000
#define EE 1600000
#define NBK 391        // fill blocks, 4096 edges each
#define CHUNK 4096
#define NCB 98         // coarse buckets of 1024 nodes (98*1024 >= NN)
#define BPH 128        // MHA blocks per head

// fma of scalar xi with float4 vv into acc[base..base+3]
// (param name must NOT be 'x'/'y'/'z'/'w' — member tokens get macro-substituted!)
#define FMA4(xi, vv, a, base)                      \
  a[(base)+0] = fmaf((xi), (vv).x, a[(base)+0]);   \
  a[(base)+1] = fmaf((xi), (vv).y, a[(base)+1]);   \
  a[(base)+2] = fmaf((xi), (vv).z, a[(base)+2]);   \
  a[(base)+3] = fmaf((xi), (vv).w, a[(base)+3]);

__device__ inline unsigned pack_bf2(float a, float b) {
  __hip_bfloat162 t;
  t.x = __float2bfloat16(a);
  t.y = __float2bfloat16(b);
  return *reinterpret_cast<unsigned*>(&t);
}

// ---------------- per-block LDS histogram over 98 coarse buckets ----------------
__launch_bounds__(256)
__global__ void k_hist(const int* __restrict__ ei, int* __restrict__ histmat) {
  __shared__ int hist[NCB];
  int t = threadIdx.x;
  if (t < NCB) hist[t] = 0;
  __syncthreads();
  int base = blockIdx.x * CHUNK;
  int nb = EE - base; if (nb > CHUNK) nb = CHUNK;
  for (int k = t; k < nb; k += 256)
    atomicAdd(&hist[ei[EE + base + k] >> 10], 1);
  __syncthreads();
  if (t < NCB) histmat[blockIdx.x * NCB + t] = hist[t];
}

// ---------------- scan stage 1: column sums (98 blocks) ----------------
// Round-10: single-block k_scanp was 65us (1 CU, 78K scattered L2 loads,
// 0.15% occupancy). Parallelized into 3 tiny kernels across 98 blocks.
__launch_bounds__(256)
__global__ void k_sumcb(const int* __restrict__ histmat, int* __restrict__ cbsum) {
  __shared__ int red[4];
  int cb = blockIdx.x, t = threadIdx.x;
  int s = 0;
  for (int blk = t; blk < NBK; blk += 256) s += histmat[blk * NCB + cb];
#pragma unroll
  for (int off = 32; off > 0; off >>= 1) s += __shfl_down(s, off);
  if ((t & 63) == 0) red[t >> 6] = s;
  __syncthreads();
  if (t == 0) cbsum[cb] = red[0] + red[1] + red[2] + red[3];
}

// ---------------- scan stage 2: scan 98 sums -> bucket bases ----------------
__launch_bounds__(128)
__global__ void k_scancb(const int* __restrict__ cbsum, int* __restrict__ bstart,
                         int* __restrict__ offsets) {
  __shared__ int sm[128];
  int t = threadIdx.x;
  int v = (t < NCB) ? cbsum[t] : 0;
  sm[t] = v;
  __syncthreads();
  for (int off = 1; off < 128; off <<= 1) {
    int x = (t >= off) ? sm[t - off] : 0;
    __syncthreads();
    sm[t] += x;
    __syncthreads();
  }
  if (t < NCB) bstart[t] = sm[t] - v;
  if (t == 0) { bstart[NCB] = EE; offsets[NN] = EE; }
}

// ---------------- scan stage 3: per-bucket scan over 391 blocks ----------------
// ppos stored TRANSPOSED [cb][blk] so each block writes 391 contiguous ints
// (no cross-XCD frontier-line churn on the write side).
__launch_bounds__(512)
__global__ void k_ppos(const int* __restrict__ histmat, const int* __restrict__ bstart,
                       int* __restrict__ ppos) {
  __shared__ int sm[512];
  int cb = blockIdx.x, t = threadIdx.x;
  int v = (t < NBK) ? histmat[t * NCB + cb] : 0;
  sm[t] = v;
  __syncthreads();
  for (int off = 1; off < 512; off <<= 1) {
    int x = (t >= off) ? sm[t - off] : 0;
    __syncthreads();
    sm[t] += x;
    __syncthreads();
  }
  if (t < NBK) ppos[cb * NBK + t] = bstart[cb] + sm[t] - v;
}

// ---------------- fill pass B: LDS radix-partition + contiguous run copy ----------------
__launch_bounds__(256)
__global__ void k_fill_b(const int* __restrict__ ei, const int* __restrict__ ppos,
                         unsigned* __restrict__ brec) {
  __shared__ int hist[NCB], binstart[NCB], bincur[NCB], pbase[NCB];
  __shared__ unsigned lbuf[CHUNK];
  __shared__ unsigned char cbArr[CHUNK];
  int t = threadIdx.x;
  int base = blockIdx.x * CHUNK;
  int nb = EE - base; if (nb > CHUNK) nb = CHUNK;
  if (t < NCB) { hist[t] = 0; pbase[t] = ppos[t * NBK + blockIdx.x]; }
  __syncthreads();
  unsigned rec[16]; int rcb[16]; int cnt = 0;
  for (int k = t; k < nb; k += 256) {
    int s = ei[base + k], d = ei[EE + base + k];
    rec[cnt] = (unsigned)s | ((unsigned)(d & 1023) << 17);  // s < 2^17, dlocal 10b
    rcb[cnt] = d >> 10;
    atomicAdd(&hist[rcb[cnt]], 1);
    cnt++;
  }
  __syncthreads();
  if (t < NCB) binstart[t] = hist[t];
  __syncthreads();
  for (int off = 1; off < NCB; off <<= 1) {
    int v = (t < NCB && t >= off) ? binstart[t - off] : 0;
    __syncthreads();
    if (t < NCB) binstart[t] += v;
    __syncthreads();
  }
  if (t < NCB) { binstart[t] -= hist[t]; bincur[t] = 0; }
  __syncthreads();
  for (int i = 0; i < cnt; i++) {
    int c = rcb[i];
    int pos = atomicAdd(&bincur[c], 1);
    int p = binstart[c] + pos;
    lbuf[p] = rec[i];
    cbArr[p] = (unsigned char)c;
  }
  __syncthreads();
  for (int i = t; i < nb; i += 256) {
    int c = cbArr[i];
    brec[pbase[c] + (i - binstart[c])] = lbuf[i];
  }
}

// ---------------- fill pass C: bucket-local histogram + scan + place ----------------
__launch_bounds__(1024)
__global__ void k_fill_c(const unsigned* __restrict__ brec, const int* __restrict__ bstart,
                         int* __restrict__ csr, int* __restrict__ offsets,
                         float* __restrict__ dinv) {
  __shared__ int cnt[1024], sm[1024];
  int cbk = blockIdx.x, t = threadIdx.x;
  int nb0 = cbk << 10;
  int nn = NN - nb0; if (nn > 1024) nn = 1024;
  cnt[t] = 0;
  __syncthreads();
  int e0 = bstart[cbk], e1 = bstart[cbk + 1];
  for (int j = e0 + t; j < e1; j += 1024)
    atomicAdd(&cnt[brec[j] >> 17], 1);
  __syncthreads();
  int cv = cnt[t];
  sm[t] = cv;
  __syncthreads();
  for (int off = 1; off < 1024; off <<= 1) {
    int v = (t >= off) ? sm[t - off] : 0;
    __syncthreads();
    sm[t] += v;
    __syncthreads();
  }
  sm[t] -= cv;  // exclusive
  if (t < nn) {
    offsets[nb0 + t] = e0 + sm[t];
    dinv[nb0 + t] = rsqrtf((float)(cv + 1));  // deg includes self loop
  }
  cnt[t] = 0;  // reuse as placement cursor
  __syncthreads();
  for (int j = e0 + t; j < e1; j += 1024) {
    unsigned r = brec[j];
    int dl = r >> 17;
    int p = atomicAdd(&cnt[dl], 1);
    csr[e0 + sm[dl] + p] = r & 0x1FFFF;  // confined to this bucket's window
  }
}

// ---------------- x~ = bf16(x * dinv[row]) ----------------
__global__ void k_prep(const float* __restrict__ x, const float* __restrict__ dinv,
                       unsigned* __restrict__ xbf2) {
  int i = blockIdx.x * 256 + threadIdx.x;  // pair index
  if (i >= NN * 32) return;
  float dv = dinv[i >> 5];
  float2 v = ((const float2*)x)[i];
  xbf2[i] = pack_bf2(v.x * dv, v.y * dv);
}

// ---------------- ax = A_norm @ x (8-lane-group gather) ----------------
__launch_bounds__(256)
__global__ void k_agg_x(const unsigned* __restrict__ xbf2, const int* __restrict__ offsets,
                        const int* __restrict__ csr, const float* __restrict__ dinv,
                        float* __restrict__ ax) {
  int gid = blockIdx.x * 256 + threadIdx.x;
  int n = gid >> 6;
  if (n >= NN) return;
  int lane = gid & 63, q = lane & 7, grp = lane >> 3;
  int e0 = offsets[n], e1 = offsets[n + 1];
  float dv = dinv[n];
  float a[8];
#pragma unroll
  for (int i = 0; i < 8; i++) a[i] = 0.f;
  if (grp == 0) {  // self loop, counted once
    uint4 u = ((const uint4*)(xbf2 + (size_t)n * 32))[q];
    unsigned uu[4] = {u.x, u.y, u.z, u.w};
#pragma unroll
    for (int p = 0; p < 4; p++) {
      __hip_bfloat162 v = *reinterpret_cast<__hip_bfloat162*>(&uu[p]);
      a[2 * p] += __bfloat162float(v.x);
      a[2 * p + 1] += __bfloat162float(v.y);
    }
  }
  for (int base = e0; base < e1; base += 8) {
    int j = base + grp;
    if (j < e1) {
      int s = csr[j];
      uint4 u = ((const uint4*)(xbf2 + (size_t)s * 32))[q];
      unsigned uu[4] = {u.x, u.y, u.z, u.w};
#pragma unroll
      for (int p = 0; p < 4; p++) {
        __hip_bfloat162 v = *reinterpret_cast<__hip_bfloat162*>(&uu[p]);
        a[2 * p] += __bfloat162float(v.x);
        a[2 * p + 1] += __bfloat162float(v.y);
      }
    }
  }
#pragma unroll
  for (int i = 0; i < 8; i++) {
    a[i] += __shfl_xor(a[i], 8);
    a[i] += __shfl_xor(a[i], 16);
    a[i] += __shfl_xor(a[i], 32);
  }
  if (lane < 8) {
    float4* op = (float4*)(ax + (size_t)n * 64 + q * 8);
    op[0] = make_float4(a[0] * dv, a[1] * dv, a[2] * dv, a[3] * dv);
    op[1] = make_float4(a[4] * dv, a[5] * dv, a[6] * dv, a[7] * dv);
  }
}

// ---------------- fused weights: Wfk = WK@Wk^T, Wfv = WV@Wv^T, Wfg = WV@gatW ----------------
__global__ void k_fusew(const float* __restrict__ gcnK_W, const float* __restrict__ gcnK_b,
                        const float* __restrict__ gcnV_W, const float* __restrict__ gcnV_b,
                        const float* __restrict__ mha_in_w, const float* __restrict__ mha_in_b,
                        const float* __restrict__ gat_W,
                        float* __restrict__ Wfk, float* __restrict__ Wfv,
                        float* __restrict__ Wfg, float* __restrict__ bf) {
  int blk = blockIdx.x;
  if (blk < 48) {
    int m = blk >> 4;
    int e = (blk & 15) * 256 + threadIdx.x;  // 0..4095
    int i = e >> 6, c = e & 63;
    float s = 0.f;
    if (m == 0) {
      for (int j = 0; j < 64; j++) s = fmaf(gcnK_W[i * 64 + j], mha_in_w[(64 + c) * 64 + j], s);
      Wfk[e] = s;
    } else if (m == 1) {
      for (int j = 0; j < 64; j++) s = fmaf(gcnV_W[i * 64 + j], mha_in_w[(128 + c) * 64 + j], s);
      Wfv[e] = s;
    } else {
      for (int j = 0; j < 64; j++) s = fmaf(gcnV_W[i * 64 + j], gat_W[j * 64 + c], s);
      Wfg[e] = s;
    }
  } else {
    int t = threadIdx.x;
    if (t < 64) {
      float s = mha_in_b[64 + t];
      for (int j = 0; j < 64; j++) s = fmaf(gcnK_b[j], mha_in_w[(64 + t) * 64 + j], s);
      bf[t] = s;
    } else if (t < 128) {
      int c = t - 64;
      float s = mha_in_b[128 + c];
      for (int j = 0; j < 64; j++) s = fmaf(gcnV_b[j], mha_in_w[(128 + c) * 64 + j], s);
      bf[64 + c] = s;
    } else if (t < 192) {
      int c = t - 128;
      float s = 0.f;
      for (int j = 0; j < 64; j++) s = fmaf(gcnV_b[j], gat_W[j * 64 + c], s);
      bf[128 + c] = s;
    }
  }
}

// ---------------- qh = (super_Q @ Wq^T + bq) * scale ----------------
__global__ void k_qh(const float* __restrict__ sQ, const float* __restrict__ in_w,
                     const float* __restrict__ in_b, float* __restrict__ qh) {
  int t = blockIdx.x * 256 + threadIdx.x;
  if (t >= 640) return;
  int l = t >> 6, c = t & 63;
  float acc = 0.f;
  for (int i = 0; i < 64; i++) acc = fmaf(sQ[l * 64 + i], in_w[c * 64 + i], acc);
  qh[t] = (acc + in_b[c]) * 0.35355339059327373f;  // 1/sqrt(8)
}

// ---------------- k_proj: ax -> Kh, Vh, hGb, s_dst (register-blocked 2rx8c) ----------------
__launch_bounds__(256)
__global__ void k_proj(const float* __restrict__ ax, const float* __restrict__ Wfk,
                       const float* __restrict__ Wfv, const float* __restrict__ Wfg,
                       const float* __restrict__ bf, const float* __restrict__ a_dst,
                       float* __restrict__ Kh, float* __restrict__ Vh,
                       unsigned* __restrict__ hGb, float* __restrict__ s_dstv) {
  __shared__ float sX[64 * 65];  // +1 pad: staging writes <=2-way conflict (free)
  __shared__ float sWk[4096], sWv[4096], sWg[4096];
  __shared__ float sB[192], sAd[64];
  int t = threadIdx.x;
  int base = blockIdx.x * 64;
  for (int i = t; i < 4096; i += 256) { sWk[i] = Wfk[i]; sWv[i] = Wfv[i]; sWg[i] = Wfg[i]; }
  if (t < 192) sB[t] = bf[t];
  if (t < 64) sAd[t] = a_dst[t];
  for (int idx = t; idx < 64 * 16; idx += 256) {
    int rl = idx >> 4, k4 = idx & 15;
    int row = base + rl;
    float4 v = (row < NN) ? ((const float4*)ax)[(size_t)row * 16 + k4]
                          : make_float4(0.f, 0.f, 0.f, 0.f);
    sX[rl * 65 + 4 * k4 + 0] = v.x;
    sX[rl * 65 + 4 * k4 + 1] = v.y;
    sX[rl * 65 + 4 * k4 + 2] = v.z;
    sX[rl * 65 + 4 * k4 + 3] = v.w;
  }
  __syncthreads();
  int cg = t & 7, rg = t >> 3;  // rows 2rg, 2rg+1; cols 8cg..8cg+7 (= head cg)
  int r0 = rg * 2;
  float aK[16], aV[16], aG[16];
#pragma unroll
  for (int i = 0; i < 16; i++) { aK[i] = 0.f; aV[i] = 0.f; aG[i] = 0.f; }
  const float4* Wk4 = (const float4*)sWk;
  const float4* Wv4 = (const float4*)sWv;
  const float4* Wg4 = (const float4*)sWg;
#pragma unroll 2
  for (int i = 0; i < 64; i++) {
    float x0 = sX[r0 * 65 + i];
    float x1 = sX[(r0 + 1) * 65 + i];
    float4 wk0 = Wk4[i * 16 + cg * 2], wk1 = Wk4[i * 16 + cg * 2 + 1];
    float4 wv0 = Wv4[i * 16 + cg * 2], wv1 = Wv4[i * 16 + cg * 2 + 1];
    float4 wg0 = Wg4[i * 16 + cg * 2], wg1 = Wg4[i * 16 + cg * 2 + 1];
    FMA4(x0, wk0, aK, 0); FMA4(x0, wk1, aK, 4);
    FMA4(x1, wk0, aK, 8); FMA4(x1, wk1, aK, 12);
    FMA4(x0, wv0, aV, 0); FMA4(x0, wv1, aV, 4);
    FMA4(x1, wv0, aV, 8); FMA4(x1, wv1, aV, 12);
    FMA4(x0, wg0, aG, 0); FMA4(x0, wg1, aG, 4);
    FMA4(x1, wg0, aG, 8); FMA4(x1, wg1, aG, 12);
  }
#pragma unroll
  for (int r = 0; r < 2; r++) {
    int row = base + r0 + r;
    bool ok = row < NN;
    int o = r * 8;
    float hg[8];
    float sd = 0.f;
#pragma unroll
    for (int c = 0; c < 8; c++) {
      hg[c] = aG[o + c] + sB[128 + cg * 8 + c];
      sd = fmaf(hg[c], sAd[cg * 8 + c], sd);
    }
    sd += __shfl_xor(sd, 1);
    sd += __shfl_xor(sd, 2);
    sd += __shfl_xor(sd, 4);
    if (ok) {
      float4* kp = (float4*)(Kh + (size_t)cg * NN * 8 + (size_t)row * 8);
      kp[0] = make_float4(aK[o + 0] + sB[cg * 8 + 0], aK[o + 1] + sB[cg * 8 + 1],
                          aK[o + 2] + sB[cg * 8 + 2], aK[o + 3] + sB[cg * 8 + 3]);
      kp[1] = make_float4(aK[o + 4] + sB[cg * 8 + 4], aK[o + 5] + sB[cg * 8 + 5],
                          aK[o + 6] + sB[cg * 8 + 6], aK[o + 7] + sB[cg * 8 + 7]);
      float4* vp = (float4*)(Vh + (size_t)cg * NN * 8 + (size_t)row * 8);
      vp[0] = make_float4(aV[o + 0] + sB[64 + cg * 8 + 0], aV[o + 1] + sB[64 + cg * 8 + 1],
                          aV[o + 2] + sB[64 + cg * 8 + 2], aV[o + 3] + sB[64 + cg * 8 + 3]);
      vp[1] = make_float4(aV[o + 4] + sB[64 + cg * 8 + 4], aV[o + 5] + sB[64 + cg * 8 + 5],
                          aV[o + 6] + sB[64 + cg * 8 + 6], aV[o + 7] + sB[64 + cg * 8 + 7]);
      uint4 u;
      u.x = pack_bf2(hg[0], hg[1]);
      u.y = pack_bf2(hg[2], hg[3]);
      u.z = pack_bf2(hg[4], hg[5]);
      u.w = pack_bf2(hg[6], hg[7]);
      ((uint4*)(hGb + (size_t)row * 32))[cg] = u;
      if (cg == 0) s_dstv[row] = sd;
    }
  }
}

// ---------------- MHA main: atomic-free per-block partials ----------------
__launch_bounds__(256)
__global__ void k_mha(const float* __restrict__ Kh, const float* __restrict__ Vh,
                      const float* __restrict__ qh, float* __restrict__ part) {
  int h = blockIdx.x / BPH, b = blockIdx.x % BPH;
  __shared__ float sq[80];
  __shared__ float red[4][90];
  if (threadIdx.x < 80) {
    int l = threadIdx.x >> 3, j = threadIdx.x & 7;
    sq[threadIdx.x] = qh[l * 64 + h * 8 + j];
  }
  __syncthreads();
  const float4* Kp = (const float4*)(Kh + (size_t)h * NN * 8);
  const float4* Vp = (const float4*)(Vh + (size_t)h * NN * 8);
  const float4* sq4 = (const float4*)sq;
  float s[10], o[80];
#pragma unroll
  for (int l = 0; l < 10; l++) s[l] = 0.f;
#pragma unroll
  for (int t = 0; t < 80; t++) o[t] = 0.f;
  for (int n = b * 256 + threadIdx.x; n < NN; n += BPH * 256) {
    float4 k0 = Kp[n * 2], k1 = Kp[n * 2 + 1];
    float4 v0 = Vp[n * 2], v1 = Vp[n * 2 + 1];
#pragma unroll
    for (int l = 0; l < 10; l++) {
      float4 q0 = sq4[l * 2], q1 = sq4[l * 2 + 1];
      float z = q0.x * k0.x + q0.y * k0.y + q0.z * k0.z + q0.w * k0.w +
                q1.x * k1.x + q1.y * k1.y + q1.z * k1.z + q1.w * k1.w;
      float w = __expf(z);
      s[l] += w;
      o[l * 8 + 0] = fmaf(w, v0.x, o[l * 8 + 0]);
      o[l * 8 + 1] = fmaf(w, v0.y, o[l * 8 + 1]);
      o[l * 8 + 2] = fmaf(w, v0.z, o[l * 8 + 2]);
      o[l * 8 + 3] = fmaf(w, v0.w, o[l * 8 + 3]);
      o[l * 8 + 4] = fmaf(w, v1.x, o[l * 8 + 4]);
      o[l * 8 + 5] = fmaf(w, v1.y, o[l * 8 + 5]);
      o[l * 8 + 6] = fmaf(w, v1.z, o[l * 8 + 6]);
      o[l * 8 + 7] = fmaf(w, v1.w, o[l * 8 + 7]);
    }
  }
  int lane = threadIdx.x & 63, wave = threadIdx.x >> 6;
#pragma unroll
  for (int l = 0; l < 10; l++) {
    float v = s[l];
#pragma unroll
    for (int off = 32; off > 0; off >>= 1) v += __shfl_down(v, off);
    if (lane == 0) red[wave][l] = v;
  }
#pragma unroll
  for (int t = 0; t < 80; t++) {
    float v = o[t];
#pragma unroll
    for (int off = 32; off > 0; off >>= 1) v += __shfl_down(v, off);
    if (lane == 0) red[wave][10 + t] = v;
  }
  __syncthreads();
  if (threadIdx.x < 90) {
    float v = red[0][threadIdx.x] + red[1][threadIdx.x] +
              red[2][threadIdx.x] + red[3][threadIdx.x];
    part[(size_t)blockIdx.x * 90 + threadIdx.x] = v;
  }
}

// ---------------- reduce partials -> acc ----------------
__global__ void k_mred(const float* __restrict__ part, float* __restrict__ acc) {
  int t = blockIdx.x * 256 + threadIdx.x;
  if (t >= 720) return;
  int h = t / 90, j = t % 90;
  float v = 0.f;
  for (int b = 0; b < BPH; b++) v += part[(size_t)(h * BPH + b) * 90 + j];
  if (j < 10) acc[h * 10 + j] = v;
  else acc[80 + h * 80 + (j - 10)] = v;
}

// ---------------- softmax finalize -> cluster -> context -> a_eff ----------------
__global__ void k_context(const float* __restrict__ acc, const float* __restrict__ out_w,
                          const float* __restrict__ out_b, const float* __restrict__ a_src,
                          const float* __restrict__ gat_Wc, float* __restrict__ aeff) {
  __shared__ float po[640], cl[640], ctx[64];
  int t = threadIdx.x;  // blockDim = 640
  {
    int h = t / 80, r = t % 80, l = r >> 3, j = r & 7;
    po[l * 64 + h * 8 + j] = acc[80 + t] / acc[h * 10 + l];
  }
  __syncthreads();
  {
    int l = t >> 6, d = t & 63;
    float v = out_b[d];
    for (int c = 0; c < 64; c++) v = fmaf(po[l * 64 + c], out_w[d * 64 + c], v);
    cl[t] = v;
  }
  __syncthreads();
  if (t < 64) {
    float m = 0.f;
#pragma unroll
    for (int l = 0; l < 10; l++) m += cl[l * 64 + t];
    ctx[t] = m * 0.1f;
  }
  __syncthreads();
  if (t < 64) {
    float v = a_src[t];
    for (int i = 0; i < 64; i++) v = fmaf(ctx[i], gat_Wc[i * 64 + t], v);
    aeff[t] = v;
  }
}

// ---------------- s_src[n] = dot(hG[n], a_eff) ----------------
__launch_bounds__(256)
__global__ void k_ssrc(const unsigned* __restrict__ hGb, const float* __restrict__ aeff,
                       float* __restrict__ s_src) {
  int gid = blockIdx.x * 256 + threadIdx.x;
  int n = gid >> 6, lane = gid & 63;
  if (n >= NN) return;
  const __hip_bfloat16* hp = (const __hip_bfloat16*)hGb;
  float v = __bfloat162float(hp[(size_t)n * 64 + lane]) * aeff[lane];
#pragma unroll
  for (int off = 32; off > 0; off >>= 1) v += __shfl_xor(v, off);
  if (lane == 0) s_src[n] = v;
}

// ---------------- GAT: 8-lane-group gather ----------------
__launch_bounds__(256)
__global__ void k_gat(const int* __restrict__ offsets, const int* __restrict__ csr,
                      const float* __restrict__ s_src, const float* __restrict__ s_dstv,
                      const unsigned* __restrict__ hGb, const float* __restrict__ gat_b,
                      float* __restrict__ g) {
  int gid = blockIdx.x * 256 + threadIdx.x;
  int n = gid >> 6;
  if (n >= NN) return;
  int lane = gid & 63, q = lane & 7, grp = lane >> 3;
  int e0 = offsets[n], e1 = offsets[n + 1];
  float sd = s_dstv[n];
  float den = 0.f;
  float a[8];
#pragma unroll
  for (int i = 0; i < 8; i++) a[i] = 0.f;
  for (int base = e0; base < e1; base += 8) {
    int j = base + grp;
    if (j < e1) {
      int s = csr[j];
      float z = s_src[s] + sd;
      z = z > 0.f ? z : 0.2f * z;
      float ex = __expf(z);  // logits O(1): softmax shift-invariant, skip segment-max
      den += ex;
      uint4 u = ((const uint4*)(hGb + (size_t)s * 32))[q];
      unsigned uu[4] = {u.x, u.y, u.z, u.w};
#pragma unroll
      for (int p = 0; p < 4; p++) {
        __hip_bfloat162 v = *reinterpret_cast<__hip_bfloat162*>(&uu[p]);
        a[2 * p] = fmaf(ex, __bfloat162float(v.x), a[2 * p]);
        a[2 * p + 1] = fmaf(ex, __bfloat162float(v.y), a[2 * p + 1]);
      }
    }
  }
  den += __shfl_xor(den, 8);
  den += __shfl_xor(den, 16);
  den += __shfl_xor(den, 32);
#pragma unroll
  for (int i = 0; i < 8; i++) {
    a[i] += __shfl_xor(a[i], 8);
    a[i] += __shfl_xor(a[i], 16);
    a[i] += __shfl_xor(a[i], 32);
  }
  float inv = 1.f / (den + 1e-16f);
  if (lane < 8) {
    float4* op = (float4*)(g + (size_t)n * 64 + q * 8);
    op[0] = make_float4(a[0] * inv + gat_b[q * 8 + 0], a[1] * inv + gat_b[q * 8 + 1],
                        a[2] * inv + gat_b[q * 8 + 2], a[3] * inv + gat_b[q * 8 + 3]);
    op[1] = make_float4(a[4] * inv + gat_b[q * 8 + 4], a[5] * inv + gat_b[q * 8 + 5],
                        a[6] * inv + gat_b[q * 8 + 6], a[7] * inv + gat_b[q * 8 + 7]);
  }
}

// ---------------- MLP stage 1: h1 = relu(g@W1+b1) -> bf16 (2r x 8c / thread) ----------------
__launch_bounds__(256)
__global__ void k_mlp1(const float* __restrict__ g, const float* __restrict__ W1,
                       const float* __restrict__ b1, unsigned* __restrict__ h1b) {
  __shared__ float sX[32 * 65];
  __shared__ float sW[64 * 128];
  __shared__ float sb[128];
  int t = threadIdx.x;
  int base = blockIdx.x * 32;
  for (int i = t; i < 8192; i += 256) sW[i] = W1[i];
  if (t < 128) sb[t] = b1[t];
  for (int idx = t; idx < 32 * 16; idx += 256) {
    int rl = idx >> 4, k4 = idx & 15;
    int row = base + rl;
    float4 v = (row < NN) ? ((const float4*)g)[(size_t)row * 16 + k4]
                          : make_float4(0.f, 0.f, 0.f, 0.f);
    sX[rl * 65 + 4 * k4 + 0] = v.x;
    sX[rl * 65 + 4 * k4 + 1] = v.y;
    sX[rl * 65 + 4 * k4 + 2] = v.z;
    sX[rl * 65 + 4 * k4 + 3] = v.w;
  }
  __syncthreads();
  int cg = t & 15, rg = t >> 4;  // rows 2rg, 2rg+1; cols 8cg..8cg+7
  int r0 = rg * 2;
  float a0[8], a1[8];
#pragma unroll
  for (int i = 0; i < 8; i++) { a0[i] = 0.f; a1[i] = 0.f; }
  const float4* W4 = (const float4*)sW;
#pragma unroll 4
  for (int i = 0; i < 64; i++) {
    float x0 = sX[r0 * 65 + i];
    float x1 = sX[(r0 + 1) * 65 + i];
    float4 w0 = W4[i * 32 + cg * 2], w1 = W4[i * 32 + cg * 2 + 1];
    FMA4(x0, w0, a0, 0); FMA4(x0, w1, a0, 4);
    FMA4(x1, w0, a1, 0); FMA4(x1, w1, a1, 4);
  }
#pragma unroll
  for (int r = 0; r < 2; r++) {
    int row = base + r0 + r;
    if (row >= NN) continue;
    float* a = r ? a1 : a0;
    float h[8];
#pragma unroll
    for (int c = 0; c < 8; c++) h[c] = fmaxf(a[c] + sb[cg * 8 + c], 0.f);
    uint4 u;
    u.x = pack_bf2(h[0], h[1]);
    u.y = pack_bf2(h[2], h[3]);
    u.z = pack_bf2(h[4], h[5]);
    u.w = pack_bf2(h[6], h[7]);
    ((uint4*)(h1b + (size_t)row * 64))[cg] = u;
  }
}

// ---------------- MLP stage 2: out = relu(h1@W2+b2) (2r x 8c / thread) ----------------
__launch_bounds__(256)
__global__ void k_mlp2(const unsigned* __restrict__ h1b, const float* __restrict__ W2,
                       const float* __restrict__ b2, float* __restrict__ out) {
  __shared__ unsigned sH[64 * 65];  // bf16 pairs
  __shared__ float sW[128 * 64];
  __shared__ float sb[64];
  int t = threadIdx.x;
  int base = blockIdx.x * 64;
  for (int i = t; i < 8192; i += 256) sW[i] = W2[i];
  if (t < 64) sb[t] = b2[t];
  for (int idx = t; idx < 64 * 16; idx += 256) {
    int rl = idx >> 4, c4 = idx & 15;
    int row = base + rl;
    uint4 v = (row < NN) ? ((const uint4*)h1b)[(size_t)row * 16 + c4]
                         : make_uint4(0u, 0u, 0u, 0u);
    sH[rl * 65 + 4 * c4 + 0] = v.x;
    sH[rl * 65 + 4 * c4 + 1] = v.y;
    sH[rl * 65 + 4 * c4 + 2] = v.z;
    sH[rl * 65 + 4 * c4 + 3] = v.w;
  }
  __syncthreads();
  int cg = t & 7, rg = t >> 3;  // rows 2rg, 2rg+1; cols 8cg..8cg+7
  int r0 = rg * 2;
  float a0[8], a1[8];
#pragma unroll
  for (int i = 0; i < 8; i++) { a0[i] = 0.f; a1[i] = 0.f; }
  const float4* W4 = (const float4*)sW;
#pragma unroll 2
  for (int kp = 0; kp < 64; kp++) {
    unsigned u0 = sH[r0 * 65 + kp];
    unsigned u1 = sH[(r0 + 1) * 65 + kp];
    float x0a = __uint_as_float(u0 << 16), x0b = __uint_as_float(u0 & 0xffff0000u);
    float x1a = __uint_as_float(u1 << 16), x1b = __uint_as_float(u1 & 0xffff0000u);
    int k0 = 2 * kp, k1 = 2 * kp + 1;
    float4 wa0 = W4[k0 * 16 + cg * 2], wa1 = W4[k0 * 16 + cg * 2 + 1];
    float4 wb0 = W4[k1 * 16 + cg * 2], wb1 = W4[k1 * 16 + cg * 2 + 1];
    FMA4(x0a, wa0, a0, 0); FMA4(x0a, wa1, a0, 4);
    FMA4(x0b, wb0, a0, 0); FMA4(x0b, wb1, a0, 4);
    FMA4(x1a, wa0, a1, 0); FMA4(x1a, wa1, a1, 4);
    FMA4(x1b, wb0, a1, 0); FMA4(x1b, wb1, a1, 4);
  }
#pragma unroll
  for (int r = 0; r < 2; r++) {
    int row = base + r0 + r;
    if (row >= NN) continue;
    float* a = r ? a1 : a0;
    float4* op = (float4*)(out + (size_t)row * 64 + cg * 8);
    op[0] = make_float4(fmaxf(a[0] + sb[cg * 8 + 0], 0.f), fmaxf(a[1] + sb[cg * 8 + 1], 0.f),
                        fmaxf(a[2] + sb[cg * 8 + 2], 0.f), fmaxf(a[3] + sb[cg * 8 + 3], 0.f));
    op[1] = make_float4(fmaxf(a[4] + sb[cg * 8 + 4], 0.f), fmaxf(a[5] + sb[cg * 8 + 5], 0.f),
                        fmaxf(a[6] + sb[cg * 8 + 6], 0.f), fmaxf(a[7] + sb[cg * 8 + 7], 0.f));
  }
}

// ---------------- host ----------------
extern "C" void kernel_launch(void* const* d_in, const int* in_sizes, int n_in,
                              void* d_out, int out_size, void* d_ws, size_t ws_size,
                              hipStream_t stream) {
  (void)in_sizes; (void)n_in; (void)out_size; (void)ws_size;
  const float* x        = (const float*)d_in[0];
  const int*   ei       = (const int*)d_in[1];
  const float* gcnK_W   = (const float*)d_in[2];
  const float* gcnK_b   = (const float*)d_in[3];
  const float* gcnV_W   = (const float*)d_in[4];
  const float* gcnV_b   = (const float*)d_in[5];
  const float* super_Q  = (const float*)d_in[6];
  const float* mha_in_w = (const float*)d_in[7];
  const float* mha_in_b = (const float*)d_in[8];
  const float* mha_out_w= (const float*)d_in[9];
  const float* mha_out_b= (const float*)d_in[10];
  const float* gat_W    = (const float*)d_in[11];
  const float* gat_Wc   = (const float*)d_in[12];
  const float* gat_a_src= (const float*)d_in[13];
  const float* gat_a_dst= (const float*)d_in[14];
  const float* gat_b    = (const float*)d_in[15];
  const float* t1_W     = (const float*)d_in[16];
  const float* t1_b     = (const float*)d_in[17];
  const float* t2_W     = (const float*)d_in[18];
  const float* t2_b     = (const float*)d_in[19];

  char* ws = (char*)d_ws;
  size_t cur = 0;
  auto alloc = [&](size_t bytes) -> char* {
    char* p = ws + cur;
    cur = (cur + bytes + 255) & ~(size_t)255;
    return p;
  };
  // no zero-init needed: every buffer is fully written before first read
  int*      histmat = (int*)alloc((size_t)NBK * NCB * 4);
  int*      cbsum   = (int*)alloc((size_t)NCB * 4);
  int*      ppos    = (int*)alloc((size_t)NCB * NBK * 4);  // transposed [cb][blk]
  int*      bstart  = (int*)alloc((size_t)(NCB + 1) * 4);
  int*      offsets = (int*)alloc((size_t)(NN + 1) * 4);
  float*    dinv    = (float*)alloc((size_t)NN * 4);
  int*      csr     = (int*)alloc((size_t)EE * 4);
  unsigned* brec    = (unsigned*)alloc((size_t)EE * 4);
  float*    Wfk     = (float*)alloc(4096 * 4);
  float*    Wfv     = (float*)alloc(4096 * 4);
  float*    Wfg     = (float*)alloc(4096 * 4);
  float*    bfuse   = (float*)alloc(192 * 4);
  float*    qh      = (float*)alloc(640 * 4);
  float*    aeff    = (float*)alloc(64 * 4);
  float*    macc    = (float*)alloc(720 * 4);
  float*    part    = (float*)alloc((size_t)8 * BPH * 90 * 4);  // MHA partials
  float*    s_src   = (float*)alloc((size_t)NN * 4);
  float*    s_dstv  = (float*)alloc((size_t)NN * 4);
  unsigned* xbf     = (unsigned*)alloc((size_t)NN * 128);   // bf16 x*dinv
  float*    ax      = (float*)alloc((size_t)NN * 64 * 4);
  float*    Kh      = (float*)alloc((size_t)NN * 64 * 4);
  float*    Vh      = (float*)alloc((size_t)NN * 64 * 4);
  unsigned* hGb     = (unsigned*)alloc((size_t)NN * 128);   // bf16 GAT features
  unsigned* h1b     = (unsigned*)alloc((size_t)NN * 64 * 4); // bf16 MLP hidden (128/row)
  float*    g       = (float*)d_out;

  k_hist<<<NBK, 256, 0, stream>>>(ei, histmat);
  k_sumcb<<<NCB, 256, 0, stream>>>(histmat, cbsum);
  k_scancb<<<1, 128, 0, stream>>>(cbsum, bstart, offsets);
  k_ppos<<<NCB, 512, 0, stream>>>(histmat, bstart, ppos);
  k_fill_b<<<NBK, 256, 0, stream>>>(ei, ppos, brec);
  k_fill_c<<<NCB, 1024, 0, stream>>>(brec, bstart, csr, offsets, dinv);
  k_prep<<<(NN * 32 + 255) / 256, 256, 0, stream>>>(x, dinv, xbf);
  k_agg_x<<<NN / 4, 256, 0, stream>>>(xbf, offsets, csr, dinv, ax);
  k_fusew<<<49, 256, 0, stream>>>(gcnK_W, gcnK_b, gcnV_W, gcnV_b, mha_in_w, mha_in_b,
                                  gat_W, Wfk, Wfv, Wfg, bfuse);
  k_qh<<<3, 256, 0, stream>>>(super_Q, mha_in_w, mha_in_b, qh);
  k_proj<<<(NN + 63) / 64, 256, 0, stream>>>(ax, Wfk, Wfv, Wfg, bfuse, gat_a_dst,
                                             Kh, Vh, hGb, s_dstv);
  k_mha<<<8 * BPH, 256, 0, stream>>>(Kh, Vh, qh, part);
  k_mred<<<3, 256, 0, stream>>>(part, macc);
  k_context<<<1, 640, 0, stream>>>(macc, mha_out_w, mha_out_b, gat_a_src, gat_Wc, aeff);
  k_ssrc<<<NN / 4, 256, 0, stream>>>(hGb, aeff, s_src);
  k_gat<<<NN / 4, 256, 0, stream>>>(offsets, csr, s_src, s_dstv, hGb, gat_b, g);
  k_mlp1<<<(NN + 31) / 32, 256, 0, stream>>>(g, t1_W, t1_b, h1b);
  k_mlp2<<<(NN + 63) / 64, 256, 0, stream>>>(h1b, t2_W, t2_b, g);
}